// Round 8
// baseline (583.684 us; speedup 1.0000x reference)
//
#include <hip/hip_runtime.h>
#include <hip/hip_bf16.h>
#include <stdint.h>

typedef short s16x8 __attribute__((ext_vector_type(8)));
typedef unsigned short u16x8 __attribute__((ext_vector_type(8)));
typedef float f32x4 __attribute__((ext_vector_type(4)));

__device__ __forceinline__ unsigned short f2bf(float f) {
    union { float f; unsigned u; } v; v.f = f;
    unsigned u = v.u;
    unsigned r = u + 0x7fffu + ((u >> 16) & 1u);
    return (unsigned short)(r >> 16);
}
__device__ __forceinline__ float bf2f(unsigned short h) {
    union { unsigned u; float f; } v; v.u = ((unsigned)h) << 16;
    return v.f;
}
__device__ __forceinline__ unsigned pkbf(float a, float b) {
    __hip_bfloat162 h = __float22bfloat162_rn(float2{a, b});
    union { __hip_bfloat162 h; unsigned u; } c; c.h = h; return c.u;
}
__device__ __forceinline__ float lo2f(unsigned d) {
    union { unsigned u; float f; } v; v.u = d << 16; return v.f;
}
__device__ __forceinline__ float hi2f(unsigned d) {
    union { unsigned u; float f; } v; v.u = d & 0xffff0000u; return v.f;
}

// ---------------------------------------------------------------------------
// K0: weight repack (fp32 OIHW -> bf16 [kpos][oc][ic]), d5w -> bf16
// ---------------------------------------------------------------------------
__global__ void k0_prep(const float* __restrict__ c2w, const float* __restrict__ c3w,
                        const float* __restrict__ c4w, const float* __restrict__ d5w,
                        unsigned short* __restrict__ w2, unsigned short* __restrict__ w3,
                        unsigned short* __restrict__ w4, unsigned short* __restrict__ w5) {
    int t = blockIdx.x * 256 + threadIdx.x;
    if (t < 18432) {            // w2 [9][64][32] <- c2w [64][32][3][3]
        int kpos = t / 2048, rem = t % 2048, oc = rem / 32, ic = rem % 32;
        w2[t] = f2bf(c2w[(oc * 32 + ic) * 9 + kpos]);
        return;
    }
    t -= 18432;
    if (t < 36864) {            // w3 [9][64][64] <- c3w [64][64][3][3]
        int kpos = t / 4096, rem = t % 4096, oc = rem / 64, ic = rem % 64;
        w3[t] = f2bf(c3w[(oc * 64 + ic) * 9 + kpos]);
        return;
    }
    t -= 36864;
    if (t < 32768) {            // w4 [4][128][64] <- c4w [128][64][2][2]
        int kpos = t / 8192, rem = t % 8192, oc = rem / 64, ic = rem % 64;
        w4[t] = f2bf(c4w[(oc * 64 + ic) * 4 + kpos]);
        return;
    }
    t -= 32768;
    if (t < 294912) w5[t] = f2bf(d5w[t]);   // [256][1152] bf16
}

// ---------------------------------------------------------------------------
// K1 (unchanged from R7): conv1 + PReLU + maxpool -> p1 bf16 [n][23][23][32]
// ---------------------------------------------------------------------------
__global__ __launch_bounds__(256, 6)
void k1_conv1(const float* __restrict__ x, const float* __restrict__ c1w,
              const float* __restrict__ c1b, const float* __restrict__ a1,
              unsigned short* __restrict__ p1) {
    __shared__ unsigned xstrip[3 * 7 * 48];      // [ic][7 rows][48] h|l<<16  (4 KB)
    __shared__ unsigned short cbuf[230 * 40];    // [flat px][32 oc + 8 pad]  (18.4 KB)
    __shared__ unsigned short wlds[1024];        // [32 oc][32 k], k>=27 zero (2 KB)
    __shared__ float bls[32], als[32];

    const int n = blockIdx.x, tid = threadIdx.x;
    const int w = tid >> 6, lane = tid & 63, q = lane >> 4, l16 = lane & 15;

    for (int t = tid; t < 1024; t += 256) {
        int oc = t >> 5, k = t & 31;
        wlds[t] = (k < 27) ? f2bf(c1w[oc * 27 + k]) : (unsigned short)0;
    }
    if (tid < 32) { bls[tid] = c1b[tid]; als[tid] = a1[tid]; }
    __syncthreads();

    s16x8 Wf[2];
    #pragma unroll
    for (int nt = 0; nt < 2; ++nt)
        Wf[nt] = *(const s16x8*)(wlds + (nt * 16 + l16) * 32 + q * 8);

    float bq[2][4], aq[2][4];
    #pragma unroll
    for (int nt = 0; nt < 2; ++nt)
    #pragma unroll
    for (int r = 0; r < 4; ++r) {
        bq[nt][r] = bls[nt * 16 + q * 4 + r];
        aq[nt][r] = als[nt * 16 + q * 4 + r];
    }

    int off[8];
    #pragma unroll
    for (int j = 0; j < 8; ++j) {
        int k = q * 8 + j;
        int kk = k < 27 ? k : 26;
        int ic = kk / 9, r9 = kk - ic * 9, ky = r9 / 3, kx = r9 - ky * 3;
        off[j] = ic * 336 + ky * 48 + kx;
    }

    auto do_pool = [&](int sp, int nprows, int kymax) {
        int ntask = nprows * 92;
        int t = tid;
        if (t < ntask) {
            int ocg = t & 3; unsigned r2 = (unsigned)t >> 2;
            int px = (int)(r2 % 23u), py_l = (int)(r2 / 23u);
            int kxmax = (px == 22) ? 2 : 3;
            int base = (2 * py_l * 46 + 2 * px) * 40 + ocg * 8;
            float m0 = -3e38f, m1 = -3e38f, m2 = -3e38f, m3 = -3e38f;
            float m4 = -3e38f, m5 = -3e38f, m6 = -3e38f, m7 = -3e38f;
            #pragma unroll
            for (int ky = 0; ky < 3; ++ky) {
                if (ky < kymax) {
                    #pragma unroll
                    for (int kx = 0; kx < 3; ++kx) {
                        if (kx < kxmax) {
                            uint4 d = *(const uint4*)&cbuf[base + (ky * 46 + kx) * 40];
                            m0 = fmaxf(m0, lo2f(d.x)); m1 = fmaxf(m1, hi2f(d.x));
                            m2 = fmaxf(m2, lo2f(d.y)); m3 = fmaxf(m3, hi2f(d.y));
                            m4 = fmaxf(m4, lo2f(d.z)); m5 = fmaxf(m5, hi2f(d.z));
                            m6 = fmaxf(m6, lo2f(d.w)); m7 = fmaxf(m7, hi2f(d.w));
                        }
                    }
                }
            }
            uint4 ov;
            ov.x = pkbf(m0, m1); ov.y = pkbf(m2, m3);
            ov.z = pkbf(m4, m5); ov.w = pkbf(m6, m7);
            int py = 2 * sp + py_l;
            *(uint4*)&p1[n * 16928 + (py * 23 + px) * 32 + ocg * 8] = ov;
        }
    };

    for (int s = 0; s < 12; ++s) {
        const int nrows = (s == 11) ? 2 : 5;
        const int P = 46 * nrows;
        const int ntiles = (P + 15) >> 4;
        const int xr0 = 4 * s;

        for (int t = tid; t < 1008; t += 256) {
            int ic = t / 336, rem = t - ic * 336;
            int rr = rem / 48, col = rem - rr * 48;
            int row = xr0 + rr; if (row > 47) row = 47;
            float f = x[n * 6912 + ic * 2304 + row * 48 + col];
            unsigned short h = f2bf(f);
            unsigned short l = f2bf(f - bf2f(h));
            xstrip[t] = (unsigned)h | ((unsigned)l << 16);
        }
        if (s > 0) do_pool(s - 1, 2, 3);
        __syncthreads();

        for (int T = w; T < ntiles; T += 4) {
            int px = T * 16 + l16;
            int p = px < P ? px : P - 1;
            int ry = p / 46, cx = p - ry * 46;
            int basex = ry * 48 + cx;
            unsigned vv[8];
            #pragma unroll
            for (int j = 0; j < 8; ++j) vv[j] = xstrip[basex + off[j]];
            s16x8 Xh, Xl;
            #pragma unroll
            for (int j = 0; j < 8; ++j) {
                Xh[j] = (short)(vv[j] & 0xffffu);
                Xl[j] = (short)(vv[j] >> 16);
            }
            f32x4 acc[2] = {{0.f,0.f,0.f,0.f},{0.f,0.f,0.f,0.f}};
            #pragma unroll
            for (int nt = 0; nt < 2; ++nt) {
                acc[nt] = __builtin_amdgcn_mfma_f32_16x16x32_bf16(Wf[nt], Xh, acc[nt], 0, 0, 0);
                acc[nt] = __builtin_amdgcn_mfma_f32_16x16x32_bf16(Wf[nt], Xl, acc[nt], 0, 0, 0);
            }
            if (px < P) {
                #pragma unroll
                for (int nt = 0; nt < 2; ++nt) {
                    float v0 = acc[nt][0] + bq[nt][0];
                    float v1 = acc[nt][1] + bq[nt][1];
                    float v2 = acc[nt][2] + bq[nt][2];
                    float v3 = acc[nt][3] + bq[nt][3];
                    v0 = fmaxf(v0, 0.f) + aq[nt][0] * fminf(v0, 0.f);
                    v1 = fmaxf(v1, 0.f) + aq[nt][1] * fminf(v1, 0.f);
                    v2 = fmaxf(v2, 0.f) + aq[nt][2] * fminf(v2, 0.f);
                    v3 = fmaxf(v3, 0.f) + aq[nt][3] * fminf(v3, 0.f);
                    uint2 pk; pk.x = pkbf(v0, v1); pk.y = pkbf(v2, v3);
                    *(uint2*)&cbuf[px * 40 + nt * 16 + q * 4] = pk;
                }
            }
        }
        __syncthreads();
    }
    do_pool(11, 1, 2);
}

// ---------------------------------------------------------------------------
// K23 (R8): fused conv2+pool2+conv3+pool3+conv4 per image.
// vs R6: (a) conv2 restructured kp-outer with 16-VGPR double-buffered B
// (R6/R7's Bf[36]=144 VGPR "preload" was silently rematerialized per tile —
// serial global loads in the MFMA chain); (b) conv3/conv4 chunk-outer with
// 1-deep B prefetch, 18/16 B loads per lane instead of 72; (c) strips of
// 3 pool rows -> LDS 47.2 KB -> 3 blocks/CU (was 2).
// LDS: xs [9][23][32] @0 (13248) | c2s [147][72] @13248 (21168)
//      p2s [100][64] @34416 (12800) | c3buf/p3 alias dead xs.
// ---------------------------------------------------------------------------
__global__ __launch_bounds__(256, 3)
void k23_fused(const unsigned short* __restrict__ p1, const unsigned short* __restrict__ w2,
               const float* __restrict__ c2b, const float* __restrict__ a2,
               const unsigned short* __restrict__ w3, const float* __restrict__ c3b,
               const float* __restrict__ a3, const unsigned short* __restrict__ w4,
               const float* __restrict__ c4b, const float* __restrict__ a4,
               unsigned short* __restrict__ flat) {
    __shared__ __align__(16) char smem[47216];
    unsigned short* xs    = (unsigned short*)(smem);            // [9][23][32]
    unsigned short* c2s   = (unsigned short*)(smem + 13248);    // [147][72]
    unsigned short* p2s   = (unsigned short*)(smem + 34416);    // [100][64]
    unsigned short* c3buf = (unsigned short*)(smem);            // alias (8 KB)
    unsigned short* p3    = (unsigned short*)(smem + 8192);     // alias (2 KB)

    const int n = blockIdx.x, tid = threadIdx.x;
    const int w = tid >> 6, lane = tid & 63, q = lane >> 4, l16 = lane & 15;
    const unsigned short* p1n = p1 + n * 16928;

    float b2r[4], a2r[4];
    #pragma unroll
    for (int nt = 0; nt < 4; ++nt) { b2r[nt] = c2b[nt * 16 + l16]; a2r[nt] = a2[nt * 16 + l16]; }

    // stage 9 p1 rows starting at 6*s (clamped) into xs
    auto stage = [&](int s) {
        int pr0 = 6 * s;
        for (int t = tid; t < 828; t += 256) {
            int rr = t / 92, c = t - rr * 92;
            int row = pr0 + rr; if (row > 22) row = 22;
            ((uint4*)xs)[rr * 92 + c] = ((const uint4*)p1n)[row * 92 + c];
        }
    };

    // conv2 strip: conv rows 6s..6s+nr-1 (nr=7,7,7,3), P=21*nr px -> c2s
    auto conv2_strip = [&](int s) {
        const int nr = (s == 3) ? 3 : 7;
        const int P = 21 * nr;
        const int ntiles = (P + 15) >> 4;          // 10,10,10,4
        f32x4 acc[3][4];
        int abase[3];
        bool act[3];
        #pragma unroll
        for (int i = 0; i < 3; ++i) {
            int T = w + 4 * i;
            act[i] = (T < ntiles);
            int m = T * 16 + l16;
            int p = m < P ? m : P - 1;
            int ry = p / 21, ox = p - ry * 21;
            abase[i] = (ry * 23 + ox) * 32 + q * 8;
            #pragma unroll
            for (int nt = 0; nt < 4; ++nt) acc[i][nt] = f32x4{0.f, 0.f, 0.f, 0.f};
        }
        // B double-buffer: 4 fragments (16 VGPR) per kp, prefetch kp+1
        s16x8 Bc[4], Bn[4];
        #pragma unroll
        for (int nt = 0; nt < 4; ++nt)
            Bc[nt] = *(const s16x8*)(w2 + (nt * 16 + l16) * 32 + q * 8);
        for (int kp = 0; kp < 9; ++kp) {
            if (kp < 8) {
                #pragma unroll
                for (int nt = 0; nt < 4; ++nt)
                    Bn[nt] = *(const s16x8*)(w2 + ((kp + 1) * 64 + nt * 16 + l16) * 32 + q * 8);
            }
            int ky = kp / 3, kx = kp - ky * 3;
            int aoff = (ky * 23 + kx) * 32;
            #pragma unroll
            for (int i = 0; i < 3; ++i) {
                if (act[i]) {
                    s16x8 A = *(const s16x8*)(xs + abase[i] + aoff);
                    #pragma unroll
                    for (int nt = 0; nt < 4; ++nt)
                        acc[i][nt] = __builtin_amdgcn_mfma_f32_16x16x32_bf16(A, Bc[nt], acc[i][nt], 0, 0, 0);
                }
            }
            #pragma unroll
            for (int nt = 0; nt < 4; ++nt) Bc[nt] = Bn[nt];
        }
        #pragma unroll
        for (int i = 0; i < 3; ++i) {
            if (act[i]) {
                int T = w + 4 * i;
                #pragma unroll
                for (int nt = 0; nt < 4; ++nt) {
                    int oc = nt * 16 + l16;
                    #pragma unroll
                    for (int r = 0; r < 4; ++r) {
                        int row = T * 16 + q * 4 + r;
                        if (row < P) {
                            float val = acc[i][nt][r] + b2r[nt];
                            val = fmaxf(val, 0.f) + a2r[nt] * fminf(val, 0.f);
                            c2s[row * 72 + oc] = f2bf(val);
                        }
                    }
                }
            }
        }
    };

    // pool2 strip: pool rows 3s..3s+nprow-1 from c2s local rows
    auto pool_strip = [&](int s) {
        int nprow = (s == 3) ? 1 : 3;
        int ntask = nprow * 80;
        if (tid < ntask) {
            int ocg = tid & 7; int r2 = tid >> 3;
            int px = r2 % 10, pyl = r2 / 10;
            int base = (2 * pyl * 21 + 2 * px) * 72 + ocg * 8;
            float m0 = -3e38f, m1 = -3e38f, m2 = -3e38f, m3 = -3e38f;
            float m4 = -3e38f, m5 = -3e38f, m6 = -3e38f, m7 = -3e38f;
            #pragma unroll
            for (int ky = 0; ky < 3; ++ky)
            #pragma unroll
            for (int kx = 0; kx < 3; ++kx) {
                uint4 d = *(const uint4*)&c2s[base + (ky * 21 + kx) * 72];
                m0 = fmaxf(m0, lo2f(d.x)); m1 = fmaxf(m1, hi2f(d.x));
                m2 = fmaxf(m2, lo2f(d.y)); m3 = fmaxf(m3, hi2f(d.y));
                m4 = fmaxf(m4, lo2f(d.z)); m5 = fmaxf(m5, hi2f(d.z));
                m6 = fmaxf(m6, lo2f(d.w)); m7 = fmaxf(m7, hi2f(d.w));
            }
            uint4 ov;
            ov.x = pkbf(m0, m1); ov.y = pkbf(m2, m3);
            ov.z = pkbf(m4, m5); ov.w = pkbf(m6, m7);
            *(uint4*)&p2s[((3 * s + pyl) * 10 + px) * 64 + ocg * 8] = ov;
        }
    };

    stage(0);
    __syncthreads();
    for (int s = 0; s < 4; ++s) {
        conv2_strip(s);
        __syncthreads();
        pool_strip(s);
        if (s < 3) stage(s + 1);
        __syncthreads();
    }

    // conv3: wave w owns oc-tile w (oc=w*16+l16) x all 4 M-tiles; 18 chunks,
    // per chunk: 4 ds_read A + 1 global B (prefetched) + 4 MFMA
    {
        const int oc3 = w * 16 + l16;
        int mbase[4];
        #pragma unroll
        for (int j = 0; j < 4; ++j) {
            int px = j * 16 + l16;
            int oy = px >> 3, ox = px & 7;
            mbase[j] = (oy * 10 + ox) * 64 + q * 8;
        }
        f32x4 acc3[4];
        #pragma unroll
        for (int j = 0; j < 4; ++j) acc3[j] = f32x4{0.f, 0.f, 0.f, 0.f};
        s16x8 B3c = *(const s16x8*)(w3 + oc3 * 64 + q * 8);
        for (int c = 0; c < 18; ++c) {
            s16x8 B3n = B3c;
            if (c < 17) {
                int cn = c + 1;
                B3n = *(const s16x8*)(w3 + ((cn >> 1) * 64 + oc3) * 64 + (cn & 1) * 32 + q * 8);
            }
            int kp = c >> 1, ky = kp / 3, kx = kp - ky * 3;
            int aoff = (ky * 10 + kx) * 64 + (c & 1) * 32;
            #pragma unroll
            for (int j = 0; j < 4; ++j) {
                s16x8 A = *(const s16x8*)(p2s + mbase[j] + aoff);
                acc3[j] = __builtin_amdgcn_mfma_f32_16x16x32_bf16(A, B3c, acc3[j], 0, 0, 0);
            }
            B3c = B3n;
        }
        float bias = c3b[oc3], al = a3[oc3];
        #pragma unroll
        for (int j = 0; j < 4; ++j)
        #pragma unroll
        for (int r = 0; r < 4; ++r) {
            int row = j * 16 + q * 4 + r;
            float val = acc3[j][r] + bias;
            val = fmaxf(val, 0.f) + al * fminf(val, 0.f);
            c3buf[row * 64 + oc3] = f2bf(val);
        }
    }
    __syncthreads();

    // pool3 2x2 s2 (8->4) -> p3
    for (int t = tid; t < 1024; t += 256) {
        int oc = t & 63, r = t >> 6, py = r >> 2, pxo = r & 3;
        float m = -3e38f;
        #pragma unroll
        for (int ky = 0; ky < 2; ++ky)
        #pragma unroll
        for (int kx = 0; kx < 2; ++kx)
            m = fmaxf(m, bf2f(c3buf[((py * 2 + ky) * 8 + pxo * 2 + kx) * 64 + oc]));
        p3[t] = f2bf(m);
    }
    __syncthreads();

    // conv4: wave w owns oc-tiles 2w,2w+1; 8 chunks, 1 shared A ds_read +
    // 2 prefetched B + 2 MFMA per chunk -> permuted flat
    {
        int px = l16 < 9 ? l16 : 8;
        int oy = px / 3, ox = px - oy * 3;
        const int mb4 = (oy * 4 + ox) * 64 + q * 8;
        const int oc4a = (w * 2) * 16 + l16, oc4b = (w * 2 + 1) * 16 + l16;
        f32x4 acc4[2] = {{0.f,0.f,0.f,0.f},{0.f,0.f,0.f,0.f}};
        s16x8 B4c[2];
        B4c[0] = *(const s16x8*)(w4 + oc4a * 64 + q * 8);
        B4c[1] = *(const s16x8*)(w4 + oc4b * 64 + q * 8);
        for (int c = 0; c < 8; ++c) {
            s16x8 B4n[2] = {B4c[0], B4c[1]};
            if (c < 7) {
                int cn = c + 1;
                int boff = (cn >> 1) * 8192 + (cn & 1) * 32 + q * 8;
                B4n[0] = *(const s16x8*)(w4 + boff + oc4a * 64);
                B4n[1] = *(const s16x8*)(w4 + boff + oc4b * 64);
            }
            int kp = c >> 1, ky = kp >> 1, kx = kp & 1;
            s16x8 A = *(const s16x8*)(p3 + mb4 + (ky * 4 + kx) * 64 + (c & 1) * 32);
            acc4[0] = __builtin_amdgcn_mfma_f32_16x16x32_bf16(A, B4c[0], acc4[0], 0, 0, 0);
            acc4[1] = __builtin_amdgcn_mfma_f32_16x16x32_bf16(A, B4c[1], acc4[1], 0, 0, 0);
            B4c[0] = B4n[0]; B4c[1] = B4n[1];
        }
        #pragma unroll
        for (int h = 0; h < 2; ++h) {
            int oc = h ? oc4b : oc4a;
            float bias = c4b[oc], al = a4[oc];
            #pragma unroll
            for (int r = 0; r < 4; ++r) {
                int row = q * 4 + r;
                if (row < 9) {
                    int hy = row / 3, wx = row - hy * 3;
                    float val = acc4[h][r] + bias;
                    val = fmaxf(val, 0.f) + al * fminf(val, 0.f);
                    flat[(unsigned)n * 1152u + (wx * 3 + hy) * 128 + oc] = f2bf(val);
                }
            }
        }
    }
}

// ---------------------------------------------------------------------------
// K5a: d5 GEMM half — 256 blocks, block = 16 images x 128 oc.
// ---------------------------------------------------------------------------
__global__ __launch_bounds__(256, 2)
void k5a_gemm(const unsigned short* __restrict__ flat, const unsigned short* __restrict__ w5,
              const float* __restrict__ d5b, const float* __restrict__ a5,
              unsigned short* __restrict__ h) {
    __shared__ float hbuf[4 * 16 * 128];   // 32 KB
    const int blk = blockIdx.x, tid = threadIdx.x;
    const int w = tid >> 6, lane = tid & 63, q = lane >> 4, l16 = lane & 15;
    const int img0 = (blk >> 1) * 16, ocb = (blk & 1) * 128;
    const int img = img0 + l16;

    f32x4 acc[8];
    #pragma unroll
    for (int nt = 0; nt < 8; ++nt) acc[nt] = f32x4{0.f, 0.f, 0.f, 0.f};

    for (int cc = 0; cc < 9; ++cc) {
        int c = w * 9 + cc;
        int k0 = c * 32 + q * 8;
        s16x8 A = *(const s16x8*)(flat + (unsigned)img * 1152u + k0);
        #pragma unroll
        for (int nt = 0; nt < 8; ++nt) {
            int oc = ocb + nt * 16 + l16;
            s16x8 B = *(const s16x8*)(w5 + (unsigned)oc * 1152u + k0);
            acc[nt] = __builtin_amdgcn_mfma_f32_16x16x32_bf16(A, B, acc[nt], 0, 0, 0);
        }
    }
    #pragma unroll
    for (int nt = 0; nt < 8; ++nt)
    #pragma unroll
    for (int r = 0; r < 4; ++r) {
        int row = q * 4 + r;
        hbuf[(w * 16 + row) * 128 + nt * 16 + l16] = acc[nt][r];
    }
    __syncthreads();
    for (int t = tid; t < 1024; t += 256) {
        int im = t >> 6, oc2 = (t & 63) * 2;
        float s0 = hbuf[im * 128 + oc2]        + hbuf[(16 + im) * 128 + oc2]
                 + hbuf[(32 + im) * 128 + oc2] + hbuf[(48 + im) * 128 + oc2];
        float s1 = hbuf[im * 128 + oc2 + 1]        + hbuf[(16 + im) * 128 + oc2 + 1]
                 + hbuf[(32 + im) * 128 + oc2 + 1] + hbuf[(48 + im) * 128 + oc2 + 1];
        int oc = ocb + oc2;
        s0 += d5b[oc];     s0 = fmaxf(s0, 0.f) + a5[oc] * fminf(s0, 0.f);
        s1 += d5b[oc + 1]; s1 = fmaxf(s1, 0.f) + a5[oc + 1] * fminf(s1, 0.f);
        *(unsigned*)&h[(unsigned)(img0 + im) * 256u + oc] = pkbf(s0, s1);
    }
}

// ---------------------------------------------------------------------------
// K5b: heads from h — 128 blocks x 16 images; LDS-staged float4 dots.
// ---------------------------------------------------------------------------
__global__ __launch_bounds__(256, 2)
void k5b_head(const unsigned short* __restrict__ h,
              const float* __restrict__ d61w, const float* __restrict__ d61b,
              const float* __restrict__ d62w, const float* __restrict__ d62b,
              const float* __restrict__ d63w, const float* __restrict__ d63b,
              float* __restrict__ out) {
    __shared__ float hL[16 * 260];
    __shared__ float wl[16 * 260];
    __shared__ float lg[256];
    const int blk = blockIdx.x, tid = threadIdx.x;
    const int img0 = blk * 16;

    for (int t = tid; t < 512; t += 256) {
        int im = t >> 5, g = t & 31;
        uint4 d = *(const uint4*)&h[(unsigned)(img0 + im) * 256u + g * 8];
        float* dst = &hL[im * 260 + g * 8];
        dst[0] = lo2f(d.x); dst[1] = hi2f(d.x);
        dst[2] = lo2f(d.y); dst[3] = hi2f(d.y);
        dst[4] = lo2f(d.z); dst[5] = hi2f(d.z);
        dst[6] = lo2f(d.w); dst[7] = hi2f(d.w);
    }
    {
        int o = tid >> 4, seg = tid & 15;
        const float* wrow = (o < 2) ? d61w + o * 256
                          : (o < 6) ? d62w + (o - 2) * 256
                          :           d63w + (o - 6) * 256;
        #pragma unroll
        for (int j = 0; j < 4; ++j)
            *(float4*)&wl[o * 260 + seg * 16 + j * 4] = ((const float4*)wrow)[seg * 4 + j];
    }
    __syncthreads();

    const int im = tid >> 4, o = tid & 15;
    {
        float bias = (o < 2) ? d61b[o] : (o < 6) ? d62b[o - 2] : d63b[o - 6];
        float s = bias;
        const float4* ha = (const float4*)&hL[im * 260];
        const float4* wa = (const float4*)&wl[o * 260];
        #pragma unroll 8
        for (int k = 0; k < 64; ++k) {
            float4 a = ha[k], b = wa[k];
            s += a.x * b.x + a.y * b.y + a.z * b.z + a.w * b.w;
        }
        lg[im * 16 + o] = s;
    }
    __syncthreads();
    {
        int gimg = img0 + im;
        float v = lg[im * 16 + o];
        if (o >= 2 && o < 6) {
            out[gimg * 4 + (o - 2)] = v;
        } else if (o >= 6) {
            out[8192 + gimg * 10 + (o - 6)] = v;
        } else {
            float l0 = lg[im * 16 + 0], l1 = lg[im * 16 + 1];
            float mx = fmaxf(l0, l1);
            float e0 = __expf(l0 - mx), e1 = __expf(l1 - mx);
            out[28672 + gimg * 2 + o] = (o == 0 ? e0 : e1) / (e0 + e1);
        }
    }
}

// ---------------------------------------------------------------------------
extern "C" void kernel_launch(void* const* d_in, const int* in_sizes, int n_in,
                              void* d_out, int out_size, void* d_ws, size_t ws_size,
                              hipStream_t stream) {
    (void)in_sizes; (void)n_in; (void)out_size; (void)ws_size;
    const float* x    = (const float*)d_in[0];
    const float* c1w  = (const float*)d_in[1];
    const float* c1b  = (const float*)d_in[2];
    const float* a1   = (const float*)d_in[3];
    const float* c2w  = (const float*)d_in[4];
    const float* c2b  = (const float*)d_in[5];
    const float* a2   = (const float*)d_in[6];
    const float* c3w  = (const float*)d_in[7];
    const float* c3b  = (const float*)d_in[8];
    const float* a3   = (const float*)d_in[9];
    const float* c4w  = (const float*)d_in[10];
    const float* c4b  = (const float*)d_in[11];
    const float* a4   = (const float*)d_in[12];
    const float* d5w  = (const float*)d_in[13];
    const float* d5b  = (const float*)d_in[14];
    const float* a5   = (const float*)d_in[15];
    const float* d61w = (const float*)d_in[16];
    const float* d61b = (const float*)d_in[17];
    const float* d62w = (const float*)d_in[18];
    const float* d62b = (const float*)d_in[19];
    const float* d63w = (const float*)d_in[20];
    const float* d63b = (const float*)d_in[21];

    char* ws = (char*)d_ws;
    // region plan:
    //   p1    @ 0          : 69,337,088 B  (live through k23_fused)
    //   flat  @ 69,337,088 : 4,718,592 B
    //   h     @ 74,055,680 : 1,048,576 B
    //   weights @ 186,777,600 : ~766 KB
    unsigned short* p1    = (unsigned short*)(ws + 0);
    unsigned short* flat  = (unsigned short*)(ws + 69337088);
    unsigned short* h     = (unsigned short*)(ws + 74055680);
    unsigned short* w2    = (unsigned short*)(ws + 186777600);
    unsigned short* w3    = (unsigned short*)(ws + 186814464);
    unsigned short* w4    = (unsigned short*)(ws + 186888192);
    unsigned short* w5    = (unsigned short*)(ws + 186953728);

    k0_prep  <<<1496, 256, 0, stream>>>(c2w, c3w, c4w, d5w, w2, w3, w4, w5);
    k1_conv1 <<<2048, 256, 0, stream>>>(x, c1w, c1b, a1, p1);
    k23_fused<<<2048, 256, 0, stream>>>(p1, w2, c2b, a2, w3, c3b, a3, w4, c4b, a4, flat);
    k5a_gemm <<<256, 256, 0, stream>>>(flat, w5, d5b, a5, h);
    k5b_head <<<128, 256, 0, stream>>>(h, d61w, d61b, d62w, d62b, d63w, d63b,
                                       (float*)d_out);
}

// Round 9
// 350.809 us; speedup vs baseline: 1.6638x; 1.6638x over previous
//
#include <hip/hip_runtime.h>
#include <hip/hip_bf16.h>
#include <stdint.h>

typedef short s16x8 __attribute__((ext_vector_type(8)));
typedef unsigned short u16x8 __attribute__((ext_vector_type(8)));
typedef float f32x4 __attribute__((ext_vector_type(4)));

__device__ __forceinline__ unsigned short f2bf(float f) {
    union { float f; unsigned u; } v; v.f = f;
    unsigned u = v.u;
    unsigned r = u + 0x7fffu + ((u >> 16) & 1u);
    return (unsigned short)(r >> 16);
}
__device__ __forceinline__ float bf2f(unsigned short h) {
    union { unsigned u; float f; } v; v.u = ((unsigned)h) << 16;
    return v.f;
}
__device__ __forceinline__ unsigned pkbf(float a, float b) {
    __hip_bfloat162 h = __float22bfloat162_rn(float2{a, b});
    union { __hip_bfloat162 h; unsigned u; } c; c.h = h; return c.u;
}
__device__ __forceinline__ float lo2f(unsigned d) {
    union { unsigned u; float f; } v; v.u = d << 16; return v.f;
}
__device__ __forceinline__ float hi2f(unsigned d) {
    union { unsigned u; float f; } v; v.u = d & 0xffff0000u; return v.f;
}

// ---------------------------------------------------------------------------
// K0: weight repack (fp32 OIHW -> bf16 [kpos][oc][ic]), d5w -> bf16
// ---------------------------------------------------------------------------
__global__ void k0_prep(const float* __restrict__ c2w, const float* __restrict__ c3w,
                        const float* __restrict__ c4w, const float* __restrict__ d5w,
                        unsigned short* __restrict__ w2, unsigned short* __restrict__ w3,
                        unsigned short* __restrict__ w4, unsigned short* __restrict__ w5) {
    int t = blockIdx.x * 256 + threadIdx.x;
    if (t < 18432) {            // w2 [9][64][32] <- c2w [64][32][3][3]
        int kpos = t / 2048, rem = t % 2048, oc = rem / 32, ic = rem % 32;
        w2[t] = f2bf(c2w[(oc * 32 + ic) * 9 + kpos]);
        return;
    }
    t -= 18432;
    if (t < 36864) {            // w3 [9][64][64] <- c3w [64][64][3][3]
        int kpos = t / 4096, rem = t % 4096, oc = rem / 64, ic = rem % 64;
        w3[t] = f2bf(c3w[(oc * 64 + ic) * 9 + kpos]);
        return;
    }
    t -= 36864;
    if (t < 32768) {            // w4 [4][128][64] <- c4w [128][64][2][2]
        int kpos = t / 8192, rem = t % 8192, oc = rem / 64, ic = rem % 64;
        w4[t] = f2bf(c4w[(oc * 64 + ic) * 4 + kpos]);
        return;
    }
    t -= 32768;
    if (t < 294912) w5[t] = f2bf(d5w[t]);   // [256][1152] bf16
}

// ---------------------------------------------------------------------------
// K1 (unchanged): conv1 + PReLU + maxpool -> p1 bf16 [n][23][23][32]
// ---------------------------------------------------------------------------
__global__ __launch_bounds__(256, 6)
void k1_conv1(const float* __restrict__ x, const float* __restrict__ c1w,
              const float* __restrict__ c1b, const float* __restrict__ a1,
              unsigned short* __restrict__ p1) {
    __shared__ unsigned xstrip[3 * 7 * 48];      // [ic][7 rows][48] h|l<<16  (4 KB)
    __shared__ unsigned short cbuf[230 * 40];    // [flat px][32 oc + 8 pad]  (18.4 KB)
    __shared__ unsigned short wlds[1024];        // [32 oc][32 k], k>=27 zero (2 KB)
    __shared__ float bls[32], als[32];

    const int n = blockIdx.x, tid = threadIdx.x;
    const int w = tid >> 6, lane = tid & 63, q = lane >> 4, l16 = lane & 15;

    for (int t = tid; t < 1024; t += 256) {
        int oc = t >> 5, k = t & 31;
        wlds[t] = (k < 27) ? f2bf(c1w[oc * 27 + k]) : (unsigned short)0;
    }
    if (tid < 32) { bls[tid] = c1b[tid]; als[tid] = a1[tid]; }
    __syncthreads();

    s16x8 Wf[2];
    #pragma unroll
    for (int nt = 0; nt < 2; ++nt)
        Wf[nt] = *(const s16x8*)(wlds + (nt * 16 + l16) * 32 + q * 8);

    float bq[2][4], aq[2][4];
    #pragma unroll
    for (int nt = 0; nt < 2; ++nt)
    #pragma unroll
    for (int r = 0; r < 4; ++r) {
        bq[nt][r] = bls[nt * 16 + q * 4 + r];
        aq[nt][r] = als[nt * 16 + q * 4 + r];
    }

    int off[8];
    #pragma unroll
    for (int j = 0; j < 8; ++j) {
        int k = q * 8 + j;
        int kk = k < 27 ? k : 26;
        int ic = kk / 9, r9 = kk - ic * 9, ky = r9 / 3, kx = r9 - ky * 3;
        off[j] = ic * 336 + ky * 48 + kx;
    }

    auto do_pool = [&](int sp, int nprows, int kymax) {
        int ntask = nprows * 92;
        int t = tid;
        if (t < ntask) {
            int ocg = t & 3; unsigned r2 = (unsigned)t >> 2;
            int px = (int)(r2 % 23u), py_l = (int)(r2 / 23u);
            int kxmax = (px == 22) ? 2 : 3;
            int base = (2 * py_l * 46 + 2 * px) * 40 + ocg * 8;
            float m0 = -3e38f, m1 = -3e38f, m2 = -3e38f, m3 = -3e38f;
            float m4 = -3e38f, m5 = -3e38f, m6 = -3e38f, m7 = -3e38f;
            #pragma unroll
            for (int ky = 0; ky < 3; ++ky) {
                if (ky < kymax) {
                    #pragma unroll
                    for (int kx = 0; kx < 3; ++kx) {
                        if (kx < kxmax) {
                            uint4 d = *(const uint4*)&cbuf[base + (ky * 46 + kx) * 40];
                            m0 = fmaxf(m0, lo2f(d.x)); m1 = fmaxf(m1, hi2f(d.x));
                            m2 = fmaxf(m2, lo2f(d.y)); m3 = fmaxf(m3, hi2f(d.y));
                            m4 = fmaxf(m4, lo2f(d.z)); m5 = fmaxf(m5, hi2f(d.z));
                            m6 = fmaxf(m6, lo2f(d.w)); m7 = fmaxf(m7, hi2f(d.w));
                        }
                    }
                }
            }
            uint4 ov;
            ov.x = pkbf(m0, m1); ov.y = pkbf(m2, m3);
            ov.z = pkbf(m4, m5); ov.w = pkbf(m6, m7);
            int py = 2 * sp + py_l;
            *(uint4*)&p1[n * 16928 + (py * 23 + px) * 32 + ocg * 8] = ov;
        }
    };

    for (int s = 0; s < 12; ++s) {
        const int nrows = (s == 11) ? 2 : 5;
        const int P = 46 * nrows;
        const int ntiles = (P + 15) >> 4;
        const int xr0 = 4 * s;

        for (int t = tid; t < 1008; t += 256) {
            int ic = t / 336, rem = t - ic * 336;
            int rr = rem / 48, col = rem - rr * 48;
            int row = xr0 + rr; if (row > 47) row = 47;
            float f = x[n * 6912 + ic * 2304 + row * 48 + col];
            unsigned short h = f2bf(f);
            unsigned short l = f2bf(f - bf2f(h));
            xstrip[t] = (unsigned)h | ((unsigned)l << 16);
        }
        if (s > 0) do_pool(s - 1, 2, 3);
        __syncthreads();

        for (int T = w; T < ntiles; T += 4) {
            int px = T * 16 + l16;
            int p = px < P ? px : P - 1;
            int ry = p / 46, cx = p - ry * 46;
            int basex = ry * 48 + cx;
            unsigned vv[8];
            #pragma unroll
            for (int j = 0; j < 8; ++j) vv[j] = xstrip[basex + off[j]];
            s16x8 Xh, Xl;
            #pragma unroll
            for (int j = 0; j < 8; ++j) {
                Xh[j] = (short)(vv[j] & 0xffffu);
                Xl[j] = (short)(vv[j] >> 16);
            }
            f32x4 acc[2] = {{0.f,0.f,0.f,0.f},{0.f,0.f,0.f,0.f}};
            #pragma unroll
            for (int nt = 0; nt < 2; ++nt) {
                acc[nt] = __builtin_amdgcn_mfma_f32_16x16x32_bf16(Wf[nt], Xh, acc[nt], 0, 0, 0);
                acc[nt] = __builtin_amdgcn_mfma_f32_16x16x32_bf16(Wf[nt], Xl, acc[nt], 0, 0, 0);
            }
            if (px < P) {
                #pragma unroll
                for (int nt = 0; nt < 2; ++nt) {
                    float v0 = acc[nt][0] + bq[nt][0];
                    float v1 = acc[nt][1] + bq[nt][1];
                    float v2 = acc[nt][2] + bq[nt][2];
                    float v3 = acc[nt][3] + bq[nt][3];
                    v0 = fmaxf(v0, 0.f) + aq[nt][0] * fminf(v0, 0.f);
                    v1 = fmaxf(v1, 0.f) + aq[nt][1] * fminf(v1, 0.f);
                    v2 = fmaxf(v2, 0.f) + aq[nt][2] * fminf(v2, 0.f);
                    v3 = fmaxf(v3, 0.f) + aq[nt][3] * fminf(v3, 0.f);
                    uint2 pk; pk.x = pkbf(v0, v1); pk.y = pkbf(v2, v3);
                    *(uint2*)&cbuf[px * 40 + nt * 16 + q * 4] = pk;
                }
            }
        }
        __syncthreads();
    }
    do_pool(11, 1, 2);
}

// ---------------------------------------------------------------------------
// K23 (R9): fused conv2+pool2+conv3+pool3+conv4.
// REGISTER-BUDGET REDESIGN after R7/R8 spills (launch_bounds(256,3) capped
// combined VGPR+AGPR at ~170; conv2 wanted ~190 -> 150 MB scratch traffic).
// conv2: wave w owns oc-pair (w&1: 32 oc) x tile-half (w>>1). Full B set =
// B2[9][2] = 72 VGPR loaded ONCE for all 4 strips; per tile just acc[2]
// (8 AGPR) + 1 A read shared across the 2 oc tiles. Peak ~100 regs.
// launch_bounds(256,2): no forced cap; LDS 47.2 KB + ~110 VGPR -> 3 blocks/CU.
// LDS: xs [9][23][32] @0 (13248) | c2s [147][72] @13248 (21168)
//      p2s [100][64] @34416 (12800) | c3buf/p3 alias dead xs.
// ---------------------------------------------------------------------------
__global__ __launch_bounds__(256, 2)
void k23_fused(const unsigned short* __restrict__ p1, const unsigned short* __restrict__ w2,
               const float* __restrict__ c2b, const float* __restrict__ a2,
               const unsigned short* __restrict__ w3, const float* __restrict__ c3b,
               const float* __restrict__ a3, const unsigned short* __restrict__ w4,
               const float* __restrict__ c4b, const float* __restrict__ a4,
               unsigned short* __restrict__ flat) {
    __shared__ __align__(16) char smem[47216];
    unsigned short* xs    = (unsigned short*)(smem);            // [9][23][32]
    unsigned short* c2s   = (unsigned short*)(smem + 13248);    // [147][72]
    unsigned short* p2s   = (unsigned short*)(smem + 34416);    // [100][64]
    unsigned short* c3buf = (unsigned short*)(smem);            // alias (8 KB)
    unsigned short* p3    = (unsigned short*)(smem + 8192);     // alias (2 KB)

    const int n = blockIdx.x, tid = threadIdx.x;
    const int w = tid >> 6, lane = tid & 63, q = lane >> 4, l16 = lane & 15;
    const unsigned short* p1n = p1 + n * 16928;

    // conv2 ownership: oc-pair npair (oc = npair*32 + {0,16} + l16), tile-half tset
    const int npair = w & 1, tset = w >> 1;
    const int ocA = npair * 32 + l16, ocB = npair * 32 + 16 + l16;

    // persistent conv2 B: 9 kpos x 2 oc-tiles = 72 VGPR, loaded once
    s16x8 B2[9][2];
    #pragma unroll
    for (int kp = 0; kp < 9; ++kp) {
        B2[kp][0] = *(const s16x8*)(w2 + (kp * 64 + ocA) * 32 + q * 8);
        B2[kp][1] = *(const s16x8*)(w2 + (kp * 64 + ocB) * 32 + q * 8);
    }
    const float b2a = c2b[ocA], b2b = c2b[ocB];
    const float a2a = a2[ocA],  a2b = a2[ocB];

    // stage 9 p1 rows starting at 6*s (clamped) into xs
    auto stage = [&](int s) {
        int pr0 = 6 * s;
        for (int t = tid; t < 828; t += 256) {
            int rr = t / 92, c = t - rr * 92;
            int row = pr0 + rr; if (row > 22) row = 22;
            ((uint4*)xs)[rr * 92 + c] = ((const uint4*)p1n)[row * 92 + c];
        }
    };

    // conv2 strip: conv rows 6s..6s+nr-1 (nr=7,7,7,3), P=21*nr px -> c2s
    auto conv2_strip = [&](int s) {
        const int nr = (s == 3) ? 3 : 7;
        const int P = 21 * nr;
        const int ntiles = (P + 15) >> 4;          // 10 or 4
        const int half = (ntiles + 1) >> 1;        // 5 or 2
        const int T0 = tset * half;
        const int T1 = (T0 + half) < ntiles ? (T0 + half) : ntiles;
        for (int T = T0; T < T1; ++T) {
            int m = T * 16 + l16;
            int p = m < P ? m : P - 1;
            int ry = p / 21, ox = p - ry * 21;
            const unsigned short* ab = xs + (ry * 23 + ox) * 32 + q * 8;
            f32x4 acc0 = {0.f, 0.f, 0.f, 0.f}, acc1 = {0.f, 0.f, 0.f, 0.f};
            #pragma unroll
            for (int kp = 0; kp < 9; ++kp) {
                int ky = kp / 3, kx = kp - ky * 3;
                s16x8 A = *(const s16x8*)(ab + (ky * 23 + kx) * 32);
                acc0 = __builtin_amdgcn_mfma_f32_16x16x32_bf16(A, B2[kp][0], acc0, 0, 0, 0);
                acc1 = __builtin_amdgcn_mfma_f32_16x16x32_bf16(A, B2[kp][1], acc1, 0, 0, 0);
            }
            int rowb = T * 16 + q * 4;
            #pragma unroll
            for (int r = 0; r < 4; ++r) {
                int row = rowb + r;
                if (row < P) {
                    float v0 = acc0[r] + b2a;
                    v0 = fmaxf(v0, 0.f) + a2a * fminf(v0, 0.f);
                    c2s[row * 72 + npair * 32 + l16] = f2bf(v0);
                    float v1 = acc1[r] + b2b;
                    v1 = fmaxf(v1, 0.f) + a2b * fminf(v1, 0.f);
                    c2s[row * 72 + npair * 32 + 16 + l16] = f2bf(v1);
                }
            }
        }
    };

    // pool2 strip: pool rows 3s..3s+nprow-1 from c2s local rows
    auto pool_strip = [&](int s) {
        int nprow = (s == 3) ? 1 : 3;
        int ntask = nprow * 80;
        if (tid < ntask) {
            int ocg = tid & 7; int r2 = tid >> 3;
            int px = r2 % 10, pyl = r2 / 10;
            int base = (2 * pyl * 21 + 2 * px) * 72 + ocg * 8;
            float m0 = -3e38f, m1 = -3e38f, m2 = -3e38f, m3 = -3e38f;
            float m4 = -3e38f, m5 = -3e38f, m6 = -3e38f, m7 = -3e38f;
            #pragma unroll
            for (int ky = 0; ky < 3; ++ky)
            #pragma unroll
            for (int kx = 0; kx < 3; ++kx) {
                uint4 d = *(const uint4*)&c2s[base + (ky * 21 + kx) * 72];
                m0 = fmaxf(m0, lo2f(d.x)); m1 = fmaxf(m1, hi2f(d.x));
                m2 = fmaxf(m2, lo2f(d.y)); m3 = fmaxf(m3, hi2f(d.y));
                m4 = fmaxf(m4, lo2f(d.z)); m5 = fmaxf(m5, hi2f(d.z));
                m6 = fmaxf(m6, lo2f(d.w)); m7 = fmaxf(m7, hi2f(d.w));
            }
            uint4 ov;
            ov.x = pkbf(m0, m1); ov.y = pkbf(m2, m3);
            ov.z = pkbf(m4, m5); ov.w = pkbf(m6, m7);
            *(uint4*)&p2s[((3 * s + pyl) * 10 + px) * 64 + ocg * 8] = ov;
        }
    };

    stage(0);
    __syncthreads();
    for (int s = 0; s < 4; ++s) {
        conv2_strip(s);
        __syncthreads();
        pool_strip(s);
        if (s < 3) stage(s + 1);
        __syncthreads();
    }

    // conv3: wave w owns oc-tile w (oc=w*16+l16) x all 4 M-tiles; 18 chunks,
    // per chunk: 4 ds_read A + 1 global B (prefetched) + 4 MFMA
    {
        const int oc3 = w * 16 + l16;
        int mbase[4];
        #pragma unroll
        for (int j = 0; j < 4; ++j) {
            int px = j * 16 + l16;
            int oy = px >> 3, ox = px & 7;
            mbase[j] = (oy * 10 + ox) * 64 + q * 8;
        }
        f32x4 acc3[4];
        #pragma unroll
        for (int j = 0; j < 4; ++j) acc3[j] = f32x4{0.f, 0.f, 0.f, 0.f};
        s16x8 B3c = *(const s16x8*)(w3 + oc3 * 64 + q * 8);
        for (int c = 0; c < 18; ++c) {
            s16x8 B3n = B3c;
            if (c < 17) {
                int cn = c + 1;
                B3n = *(const s16x8*)(w3 + ((cn >> 1) * 64 + oc3) * 64 + (cn & 1) * 32 + q * 8);
            }
            int kp = c >> 1, ky = kp / 3, kx = kp - ky * 3;
            int aoff = (ky * 10 + kx) * 64 + (c & 1) * 32;
            #pragma unroll
            for (int j = 0; j < 4; ++j) {
                s16x8 A = *(const s16x8*)(p2s + mbase[j] + aoff);
                acc3[j] = __builtin_amdgcn_mfma_f32_16x16x32_bf16(A, B3c, acc3[j], 0, 0, 0);
            }
            B3c = B3n;
        }
        float bias = c3b[oc3], al = a3[oc3];
        #pragma unroll
        for (int j = 0; j < 4; ++j)
        #pragma unroll
        for (int r = 0; r < 4; ++r) {
            int row = j * 16 + q * 4 + r;
            float val = acc3[j][r] + bias;
            val = fmaxf(val, 0.f) + al * fminf(val, 0.f);
            c3buf[row * 64 + oc3] = f2bf(val);
        }
    }
    __syncthreads();

    // pool3 2x2 s2 (8->4) -> p3
    for (int t = tid; t < 1024; t += 256) {
        int oc = t & 63, r = t >> 6, py = r >> 2, pxo = r & 3;
        float m = -3e38f;
        #pragma unroll
        for (int ky = 0; ky < 2; ++ky)
        #pragma unroll
        for (int kx = 0; kx < 2; ++kx)
            m = fmaxf(m, bf2f(c3buf[((py * 2 + ky) * 8 + pxo * 2 + kx) * 64 + oc]));
        p3[t] = f2bf(m);
    }
    __syncthreads();

    // conv4: wave w owns oc-tiles 2w,2w+1; 8 chunks, 1 shared A ds_read +
    // 2 prefetched B + 2 MFMA per chunk -> permuted flat
    {
        int px = l16 < 9 ? l16 : 8;
        int oy = px / 3, ox = px - oy * 3;
        const int mb4 = (oy * 4 + ox) * 64 + q * 8;
        const int oc4a = (w * 2) * 16 + l16, oc4b = (w * 2 + 1) * 16 + l16;
        f32x4 acc4[2] = {{0.f,0.f,0.f,0.f},{0.f,0.f,0.f,0.f}};
        s16x8 B4c[2];
        B4c[0] = *(const s16x8*)(w4 + oc4a * 64 + q * 8);
        B4c[1] = *(const s16x8*)(w4 + oc4b * 64 + q * 8);
        for (int c = 0; c < 8; ++c) {
            s16x8 B4n[2] = {B4c[0], B4c[1]};
            if (c < 7) {
                int cn = c + 1;
                int boff = (cn >> 1) * 8192 + (cn & 1) * 32 + q * 8;
                B4n[0] = *(const s16x8*)(w4 + boff + oc4a * 64);
                B4n[1] = *(const s16x8*)(w4 + boff + oc4b * 64);
            }
            int kp = c >> 1, ky = kp >> 1, kx = kp & 1;
            s16x8 A = *(const s16x8*)(p3 + mb4 + (ky * 4 + kx) * 64 + (c & 1) * 32);
            acc4[0] = __builtin_amdgcn_mfma_f32_16x16x32_bf16(A, B4c[0], acc4[0], 0, 0, 0);
            acc4[1] = __builtin_amdgcn_mfma_f32_16x16x32_bf16(A, B4c[1], acc4[1], 0, 0, 0);
            B4c[0] = B4n[0]; B4c[1] = B4n[1];
        }
        #pragma unroll
        for (int h = 0; h < 2; ++h) {
            int oc = h ? oc4b : oc4a;
            float bias = c4b[oc], al = a4[oc];
            #pragma unroll
            for (int r = 0; r < 4; ++r) {
                int row = q * 4 + r;
                if (row < 9) {
                    int hy = row / 3, wx = row - hy * 3;
                    float val = acc4[h][r] + bias;
                    val = fmaxf(val, 0.f) + al * fminf(val, 0.f);
                    flat[(unsigned)n * 1152u + (wx * 3 + hy) * 128 + oc] = f2bf(val);
                }
            }
        }
    }
}

// ---------------------------------------------------------------------------
// K5a: d5 GEMM half — 256 blocks, block = 16 images x 128 oc.
// ---------------------------------------------------------------------------
__global__ __launch_bounds__(256, 2)
void k5a_gemm(const unsigned short* __restrict__ flat, const unsigned short* __restrict__ w5,
              const float* __restrict__ d5b, const float* __restrict__ a5,
              unsigned short* __restrict__ h) {
    __shared__ float hbuf[4 * 16 * 128];   // 32 KB
    const int blk = blockIdx.x, tid = threadIdx.x;
    const int w = tid >> 6, lane = tid & 63, q = lane >> 4, l16 = lane & 15;
    const int img0 = (blk >> 1) * 16, ocb = (blk & 1) * 128;
    const int img = img0 + l16;

    f32x4 acc[8];
    #pragma unroll
    for (int nt = 0; nt < 8; ++nt) acc[nt] = f32x4{0.f, 0.f, 0.f, 0.f};

    for (int cc = 0; cc < 9; ++cc) {
        int c = w * 9 + cc;
        int k0 = c * 32 + q * 8;
        s16x8 A = *(const s16x8*)(flat + (unsigned)img * 1152u + k0);
        #pragma unroll
        for (int nt = 0; nt < 8; ++nt) {
            int oc = ocb + nt * 16 + l16;
            s16x8 B = *(const s16x8*)(w5 + (unsigned)oc * 1152u + k0);
            acc[nt] = __builtin_amdgcn_mfma_f32_16x16x32_bf16(A, B, acc[nt], 0, 0, 0);
        }
    }
    #pragma unroll
    for (int nt = 0; nt < 8; ++nt)
    #pragma unroll
    for (int r = 0; r < 4; ++r) {
        int row = q * 4 + r;
        hbuf[(w * 16 + row) * 128 + nt * 16 + l16] = acc[nt][r];
    }
    __syncthreads();
    for (int t = tid; t < 1024; t += 256) {
        int im = t >> 6, oc2 = (t & 63) * 2;
        float s0 = hbuf[im * 128 + oc2]        + hbuf[(16 + im) * 128 + oc2]
                 + hbuf[(32 + im) * 128 + oc2] + hbuf[(48 + im) * 128 + oc2];
        float s1 = hbuf[im * 128 + oc2 + 1]        + hbuf[(16 + im) * 128 + oc2 + 1]
                 + hbuf[(32 + im) * 128 + oc2 + 1] + hbuf[(48 + im) * 128 + oc2 + 1];
        int oc = ocb + oc2;
        s0 += d5b[oc];     s0 = fmaxf(s0, 0.f) + a5[oc] * fminf(s0, 0.f);
        s1 += d5b[oc + 1]; s1 = fmaxf(s1, 0.f) + a5[oc + 1] * fminf(s1, 0.f);
        *(unsigned*)&h[(unsigned)(img0 + im) * 256u + oc] = pkbf(s0, s1);
    }
}

// ---------------------------------------------------------------------------
// K5b: heads from h — 128 blocks x 16 images; LDS-staged float4 dots.
// ---------------------------------------------------------------------------
__global__ __launch_bounds__(256, 2)
void k5b_head(const unsigned short* __restrict__ h,
              const float* __restrict__ d61w, const float* __restrict__ d61b,
              const float* __restrict__ d62w, const float* __restrict__ d62b,
              const float* __restrict__ d63w, const float* __restrict__ d63b,
              float* __restrict__ out) {
    __shared__ float hL[16 * 260];
    __shared__ float wl[16 * 260];
    __shared__ float lg[256];
    const int blk = blockIdx.x, tid = threadIdx.x;
    const int img0 = blk * 16;

    for (int t = tid; t < 512; t += 256) {
        int im = t >> 5, g = t & 31;
        uint4 d = *(const uint4*)&h[(unsigned)(img0 + im) * 256u + g * 8];
        float* dst = &hL[im * 260 + g * 8];
        dst[0] = lo2f(d.x); dst[1] = hi2f(d.x);
        dst[2] = lo2f(d.y); dst[3] = hi2f(d.y);
        dst[4] = lo2f(d.z); dst[5] = hi2f(d.z);
        dst[6] = lo2f(d.w); dst[7] = hi2f(d.w);
    }
    {
        int o = tid >> 4, seg = tid & 15;
        const float* wrow = (o < 2) ? d61w + o * 256
                          : (o < 6) ? d62w + (o - 2) * 256
                          :           d63w + (o - 6) * 256;
        #pragma unroll
        for (int j = 0; j < 4; ++j)
            *(float4*)&wl[o * 260 + seg * 16 + j * 4] = ((const float4*)wrow)[seg * 4 + j];
    }
    __syncthreads();

    const int im = tid >> 4, o = tid & 15;
    {
        float bias = (o < 2) ? d61b[o] : (o < 6) ? d62b[o - 2] : d63b[o - 6];
        float s = bias;
        const float4* ha = (const float4*)&hL[im * 260];
        const float4* wa = (const float4*)&wl[o * 260];
        #pragma unroll 8
        for (int k = 0; k < 64; ++k) {
            float4 a = ha[k], b = wa[k];
            s += a.x * b.x + a.y * b.y + a.z * b.z + a.w * b.w;
        }
        lg[im * 16 + o] = s;
    }
    __syncthreads();
    {
        int gimg = img0 + im;
        float v = lg[im * 16 + o];
        if (o >= 2 && o < 6) {
            out[gimg * 4 + (o - 2)] = v;
        } else if (o >= 6) {
            out[8192 + gimg * 10 + (o - 6)] = v;
        } else {
            float l0 = lg[im * 16 + 0], l1 = lg[im * 16 + 1];
            float mx = fmaxf(l0, l1);
            float e0 = __expf(l0 - mx), e1 = __expf(l1 - mx);
            out[28672 + gimg * 2 + o] = (o == 0 ? e0 : e1) / (e0 + e1);
        }
    }
}

// ---------------------------------------------------------------------------
extern "C" void kernel_launch(void* const* d_in, const int* in_sizes, int n_in,
                              void* d_out, int out_size, void* d_ws, size_t ws_size,
                              hipStream_t stream) {
    (void)in_sizes; (void)n_in; (void)out_size; (void)ws_size;
    const float* x    = (const float*)d_in[0];
    const float* c1w  = (const float*)d_in[1];
    const float* c1b  = (const float*)d_in[2];
    const float* a1   = (const float*)d_in[3];
    const float* c2w  = (const float*)d_in[4];
    const float* c2b  = (const float*)d_in[5];
    const float* a2   = (const float*)d_in[6];
    const float* c3w  = (const float*)d_in[7];
    const float* c3b  = (const float*)d_in[8];
    const float* a3   = (const float*)d_in[9];
    const float* c4w  = (const float*)d_in[10];
    const float* c4b  = (const float*)d_in[11];
    const float* a4   = (const float*)d_in[12];
    const float* d5w  = (const float*)d_in[13];
    const float* d5b  = (const float*)d_in[14];
    const float* a5   = (const float*)d_in[15];
    const float* d61w = (const float*)d_in[16];
    const float* d61b = (const float*)d_in[17];
    const float* d62w = (const float*)d_in[18];
    const float* d62b = (const float*)d_in[19];
    const float* d63w = (const float*)d_in[20];
    const float* d63b = (const float*)d_in[21];

    char* ws = (char*)d_ws;
    // region plan:
    //   p1    @ 0          : 69,337,088 B  (live through k23_fused)
    //   flat  @ 69,337,088 : 4,718,592 B
    //   h     @ 74,055,680 : 1,048,576 B
    //   weights @ 186,777,600 : ~766 KB
    unsigned short* p1    = (unsigned short*)(ws + 0);
    unsigned short* flat  = (unsigned short*)(ws + 69337088);
    unsigned short* h     = (unsigned short*)(ws + 74055680);
    unsigned short* w2    = (unsigned short*)(ws + 186777600);
    unsigned short* w3    = (unsigned short*)(ws + 186814464);
    unsigned short* w4    = (unsigned short*)(ws + 186888192);
    unsigned short* w5    = (unsigned short*)(ws + 186953728);

    k0_prep  <<<1496, 256, 0, stream>>>(c2w, c3w, c4w, d5w, w2, w3, w4, w5);
    k1_conv1 <<<2048, 256, 0, stream>>>(x, c1w, c1b, a1, p1);
    k23_fused<<<2048, 256, 0, stream>>>(p1, w2, c2b, a2, w3, c3b, a3, w4, c4b, a4, flat);
    k5a_gemm <<<256, 256, 0, stream>>>(flat, w5, d5b, a5, h);
    k5b_head <<<128, 256, 0, stream>>>(h, d61w, d61b, d62w, d62b, d63w, d63b,
                                       (float*)d_out);
}

// Round 10
// 320.050 us; speedup vs baseline: 1.8237x; 1.0961x over previous
//
#include <hip/hip_runtime.h>
#include <hip/hip_bf16.h>
#include <hip/hip_fp16.h>
#include <stdint.h>

typedef short s16x8 __attribute__((ext_vector_type(8)));
typedef unsigned short u16x8 __attribute__((ext_vector_type(8)));
typedef _Float16 f16x8 __attribute__((ext_vector_type(8)));
typedef float f32x4 __attribute__((ext_vector_type(4)));

__device__ __forceinline__ unsigned short f2bf(float f) {
    union { float f; unsigned u; } v; v.f = f;
    unsigned u = v.u;
    unsigned r = u + 0x7fffu + ((u >> 16) & 1u);
    return (unsigned short)(r >> 16);
}
__device__ __forceinline__ float bf2f(unsigned short h) {
    union { unsigned u; float f; } v; v.u = ((unsigned)h) << 16;
    return v.f;
}
__device__ __forceinline__ unsigned pkbf(float a, float b) {
    __hip_bfloat162 h = __float22bfloat162_rn(float2{a, b});
    union { __hip_bfloat162 h; unsigned u; } c; c.h = h; return c.u;
}
__device__ __forceinline__ float lo2f(unsigned d) {
    union { unsigned u; float f; } v; v.u = d << 16; return v.f;
}
__device__ __forceinline__ float hi2f(unsigned d) {
    union { unsigned u; float f; } v; v.u = d & 0xffff0000u; return v.f;
}
__device__ __forceinline__ unsigned short f2h(float f) {
    __half h = __float2half(f);
    union { __half h; unsigned short u; } c; c.h = h; return c.u;
}

// ---------------------------------------------------------------------------
// K0: weight repack (fp32 OIHW -> bf16 [kpos][oc][ic]), d5w -> bf16
// ---------------------------------------------------------------------------
__global__ void k0_prep(const float* __restrict__ c2w, const float* __restrict__ c3w,
                        const float* __restrict__ c4w, const float* __restrict__ d5w,
                        unsigned short* __restrict__ w2, unsigned short* __restrict__ w3,
                        unsigned short* __restrict__ w4, unsigned short* __restrict__ w5) {
    int t = blockIdx.x * 256 + threadIdx.x;
    if (t < 18432) {            // w2 [9][64][32] <- c2w [64][32][3][3]
        int kpos = t / 2048, rem = t % 2048, oc = rem / 32, ic = rem % 32;
        w2[t] = f2bf(c2w[(oc * 32 + ic) * 9 + kpos]);
        return;
    }
    t -= 18432;
    if (t < 36864) {            // w3 [9][64][64] <- c3w [64][64][3][3]
        int kpos = t / 4096, rem = t % 4096, oc = rem / 64, ic = rem % 64;
        w3[t] = f2bf(c3w[(oc * 64 + ic) * 9 + kpos]);
        return;
    }
    t -= 36864;
    if (t < 32768) {            // w4 [4][128][64] <- c4w [128][64][2][2]
        int kpos = t / 8192, rem = t % 8192, oc = rem / 64, ic = rem % 64;
        w4[t] = f2bf(c4w[(oc * 64 + ic) * 4 + kpos]);
        return;
    }
    t -= 32768;
    if (t < 294912) w5[t] = f2bf(d5w[t]);   // [256][1152] bf16
}

// ---------------------------------------------------------------------------
// K1 (R10): conv1 via SINGLE fp16 MFMA (was hi/lo bf16 dual-MFMA).
// fp16 is strictly better here: x~N(0,1), w~N(0,1/27) both fit fp16; weight
// precision improves 8x vs bf16; input path <=1e-3. Per tile: 8 ds_read_u16
// + 2 MFMA (was 8 b32 + 16 extract + 4 MFMA). Staging: 1 cvt/element (was
// ~12 ops for the hi/lo split). Everything downstream unchanged (bf16).
// ---------------------------------------------------------------------------
__global__ __launch_bounds__(256, 6)
void k1_conv1(const float* __restrict__ x, const float* __restrict__ c1w,
              const float* __restrict__ c1b, const float* __restrict__ a1,
              unsigned short* __restrict__ p1) {
    __shared__ unsigned short xstrip[1008];      // [ic][7 rows][48] fp16 bits (2 KB)
    __shared__ unsigned short cbuf[230 * 40];    // [flat px][32 oc + 8 pad] bf16 (18.4 KB)
    __shared__ unsigned short wlds[1024];        // [32 oc][32 k] fp16, k>=27 zero (2 KB)
    __shared__ float bls[32], als[32];

    const int n = blockIdx.x, tid = threadIdx.x;
    const int w = tid >> 6, lane = tid & 63, q = lane >> 4, l16 = lane & 15;

    for (int t = tid; t < 1024; t += 256) {
        int oc = t >> 5, k = t & 31;
        wlds[t] = (k < 27) ? f2h(c1w[oc * 27 + k]) : (unsigned short)0;
    }
    if (tid < 32) { bls[tid] = c1b[tid]; als[tid] = a1[tid]; }
    __syncthreads();

    // W fragments (fp16): m = nt*16 + l16, k = q*8..q*8+7 (one b128)
    f16x8 Wf[2];
    #pragma unroll
    for (int nt = 0; nt < 2; ++nt) {
        union { u16x8 u; f16x8 f; } cc;
        cc.u = *(const u16x8*)(wlds + (nt * 16 + l16) * 32 + q * 8);
        Wf[nt] = cc.f;
    }

    float bq[2][4], aq[2][4];
    #pragma unroll
    for (int nt = 0; nt < 2; ++nt)
    #pragma unroll
    for (int r = 0; r < 4; ++r) {
        bq[nt][r] = bls[nt * 16 + q * 4 + r];
        aq[nt][r] = als[nt * 16 + q * 4 + r];
    }

    int off[8];
    #pragma unroll
    for (int j = 0; j < 8; ++j) {
        int k = q * 8 + j;
        int kk = k < 27 ? k : 26;
        int ic = kk / 9, r9 = kk - ic * 9, ky = r9 / 3, kx = r9 - ky * 3;
        off[j] = ic * 336 + ky * 48 + kx;
    }

    auto do_pool = [&](int sp, int nprows, int kymax) {
        int ntask = nprows * 92;
        int t = tid;
        if (t < ntask) {
            int ocg = t & 3; unsigned r2 = (unsigned)t >> 2;
            int px = (int)(r2 % 23u), py_l = (int)(r2 / 23u);
            int kxmax = (px == 22) ? 2 : 3;
            int base = (2 * py_l * 46 + 2 * px) * 40 + ocg * 8;
            float m0 = -3e38f, m1 = -3e38f, m2 = -3e38f, m3 = -3e38f;
            float m4 = -3e38f, m5 = -3e38f, m6 = -3e38f, m7 = -3e38f;
            #pragma unroll
            for (int ky = 0; ky < 3; ++ky) {
                if (ky < kymax) {
                    #pragma unroll
                    for (int kx = 0; kx < 3; ++kx) {
                        if (kx < kxmax) {
                            uint4 d = *(const uint4*)&cbuf[base + (ky * 46 + kx) * 40];
                            m0 = fmaxf(m0, lo2f(d.x)); m1 = fmaxf(m1, hi2f(d.x));
                            m2 = fmaxf(m2, lo2f(d.y)); m3 = fmaxf(m3, hi2f(d.y));
                            m4 = fmaxf(m4, lo2f(d.z)); m5 = fmaxf(m5, hi2f(d.z));
                            m6 = fmaxf(m6, lo2f(d.w)); m7 = fmaxf(m7, hi2f(d.w));
                        }
                    }
                }
            }
            uint4 ov;
            ov.x = pkbf(m0, m1); ov.y = pkbf(m2, m3);
            ov.z = pkbf(m4, m5); ov.w = pkbf(m6, m7);
            int py = 2 * sp + py_l;
            *(uint4*)&p1[n * 16928 + (py * 23 + px) * 32 + ocg * 8] = ov;
        }
    };

    for (int s = 0; s < 12; ++s) {
        const int nrows = (s == 11) ? 2 : 5;
        const int P = 46 * nrows;
        const int ntiles = (P + 15) >> 4;
        const int xr0 = 4 * s;

        // stage x strip as fp16: 252 float4 reads -> ushort4 LDS writes
        {
            int t4 = tid;
            if (t4 < 252) {
                int ic = t4 / 84;
                int rem4 = t4 * 4 - ic * 336;
                int rr = rem4 / 48, col = rem4 - rr * 48;
                int row = xr0 + rr; if (row > 47) row = 47;
                float4 f = *(const float4*)(x + n * 6912 + ic * 2304 + row * 48 + col);
                ushort4 o;
                o.x = f2h(f.x); o.y = f2h(f.y); o.z = f2h(f.z); o.w = f2h(f.w);
                *(ushort4*)&xstrip[t4 * 4] = o;
            }
        }
        if (s > 0) do_pool(s - 1, 2, 3);
        __syncthreads();

        for (int T = w; T < ntiles; T += 4) {
            int px = T * 16 + l16;
            int p = px < P ? px : P - 1;
            int ry = p / 46, cx = p - ry * 46;
            int basex = ry * 48 + cx;
            union { u16x8 u; f16x8 f; } xcc;
            #pragma unroll
            for (int j = 0; j < 8; ++j) xcc.u[j] = xstrip[basex + off[j]];
            f16x8 Xf = xcc.f;
            f32x4 acc[2] = {{0.f,0.f,0.f,0.f},{0.f,0.f,0.f,0.f}};
            #pragma unroll
            for (int nt = 0; nt < 2; ++nt)
                acc[nt] = __builtin_amdgcn_mfma_f32_16x16x32_f16(Wf[nt], Xf, acc[nt], 0, 0, 0);
            if (px < P) {
                #pragma unroll
                for (int nt = 0; nt < 2; ++nt) {
                    float v0 = acc[nt][0] + bq[nt][0];
                    float v1 = acc[nt][1] + bq[nt][1];
                    float v2 = acc[nt][2] + bq[nt][2];
                    float v3 = acc[nt][3] + bq[nt][3];
                    v0 = fmaxf(v0, 0.f) + aq[nt][0] * fminf(v0, 0.f);
                    v1 = fmaxf(v1, 0.f) + aq[nt][1] * fminf(v1, 0.f);
                    v2 = fmaxf(v2, 0.f) + aq[nt][2] * fminf(v2, 0.f);
                    v3 = fmaxf(v3, 0.f) + aq[nt][3] * fminf(v3, 0.f);
                    uint2 pk; pk.x = pkbf(v0, v1); pk.y = pkbf(v2, v3);
                    *(uint2*)&cbuf[px * 40 + nt * 16 + q * 4] = pk;
                }
            }
        }
        __syncthreads();
    }
    do_pool(11, 1, 2);
}

// ---------------------------------------------------------------------------
// K23 (R9, unchanged): fused conv2+pool2+conv3+pool3+conv4.
// conv2: wave w owns oc-pair (w&1) x tile-half (w>>1); B2[9][2] = 72 VGPR
// persistent. Peak ~100 regs, no spill. LDS 47.2 KB -> 3 blocks/CU.
// ---------------------------------------------------------------------------
__global__ __launch_bounds__(256, 2)
void k23_fused(const unsigned short* __restrict__ p1, const unsigned short* __restrict__ w2,
               const float* __restrict__ c2b, const float* __restrict__ a2,
               const unsigned short* __restrict__ w3, const float* __restrict__ c3b,
               const float* __restrict__ a3, const unsigned short* __restrict__ w4,
               const float* __restrict__ c4b, const float* __restrict__ a4,
               unsigned short* __restrict__ flat) {
    __shared__ __align__(16) char smem[47216];
    unsigned short* xs    = (unsigned short*)(smem);            // [9][23][32]
    unsigned short* c2s   = (unsigned short*)(smem + 13248);    // [147][72]
    unsigned short* p2s   = (unsigned short*)(smem + 34416);    // [100][64]
    unsigned short* c3buf = (unsigned short*)(smem);            // alias (8 KB)
    unsigned short* p3    = (unsigned short*)(smem + 8192);     // alias (2 KB)

    const int n = blockIdx.x, tid = threadIdx.x;
    const int w = tid >> 6, lane = tid & 63, q = lane >> 4, l16 = lane & 15;
    const unsigned short* p1n = p1 + n * 16928;

    const int npair = w & 1, tset = w >> 1;
    const int ocA = npair * 32 + l16, ocB = npair * 32 + 16 + l16;

    s16x8 B2[9][2];
    #pragma unroll
    for (int kp = 0; kp < 9; ++kp) {
        B2[kp][0] = *(const s16x8*)(w2 + (kp * 64 + ocA) * 32 + q * 8);
        B2[kp][1] = *(const s16x8*)(w2 + (kp * 64 + ocB) * 32 + q * 8);
    }
    const float b2a = c2b[ocA], b2b = c2b[ocB];
    const float a2a = a2[ocA],  a2b = a2[ocB];

    auto stage = [&](int s) {
        int pr0 = 6 * s;
        for (int t = tid; t < 828; t += 256) {
            int rr = t / 92, c = t - rr * 92;
            int row = pr0 + rr; if (row > 22) row = 22;
            ((uint4*)xs)[rr * 92 + c] = ((const uint4*)p1n)[row * 92 + c];
        }
    };

    auto conv2_strip = [&](int s) {
        const int nr = (s == 3) ? 3 : 7;
        const int P = 21 * nr;
        const int ntiles = (P + 15) >> 4;
        const int half = (ntiles + 1) >> 1;
        const int T0 = tset * half;
        const int T1 = (T0 + half) < ntiles ? (T0 + half) : ntiles;
        for (int T = T0; T < T1; ++T) {
            int m = T * 16 + l16;
            int p = m < P ? m : P - 1;
            int ry = p / 21, ox = p - ry * 21;
            const unsigned short* ab = xs + (ry * 23 + ox) * 32 + q * 8;
            f32x4 acc0 = {0.f, 0.f, 0.f, 0.f}, acc1 = {0.f, 0.f, 0.f, 0.f};
            #pragma unroll
            for (int kp = 0; kp < 9; ++kp) {
                int ky = kp / 3, kx = kp - ky * 3;
                s16x8 A = *(const s16x8*)(ab + (ky * 23 + kx) * 32);
                acc0 = __builtin_amdgcn_mfma_f32_16x16x32_bf16(A, B2[kp][0], acc0, 0, 0, 0);
                acc1 = __builtin_amdgcn_mfma_f32_16x16x32_bf16(A, B2[kp][1], acc1, 0, 0, 0);
            }
            int rowb = T * 16 + q * 4;
            #pragma unroll
            for (int r = 0; r < 4; ++r) {
                int row = rowb + r;
                if (row < P) {
                    float v0 = acc0[r] + b2a;
                    v0 = fmaxf(v0, 0.f) + a2a * fminf(v0, 0.f);
                    c2s[row * 72 + npair * 32 + l16] = f2bf(v0);
                    float v1 = acc1[r] + b2b;
                    v1 = fmaxf(v1, 0.f) + a2b * fminf(v1, 0.f);
                    c2s[row * 72 + npair * 32 + 16 + l16] = f2bf(v1);
                }
            }
        }
    };

    auto pool_strip = [&](int s) {
        int nprow = (s == 3) ? 1 : 3;
        int ntask = nprow * 80;
        if (tid < ntask) {
            int ocg = tid & 7; int r2 = tid >> 3;
            int px = r2 % 10, pyl = r2 / 10;
            int base = (2 * pyl * 21 + 2 * px) * 72 + ocg * 8;
            float m0 = -3e38f, m1 = -3e38f, m2 = -3e38f, m3 = -3e38f;
            float m4 = -3e38f, m5 = -3e38f, m6 = -3e38f, m7 = -3e38f;
            #pragma unroll
            for (int ky = 0; ky < 3; ++ky)
            #pragma unroll
            for (int kx = 0; kx < 3; ++kx) {
                uint4 d = *(const uint4*)&c2s[base + (ky * 21 + kx) * 72];
                m0 = fmaxf(m0, lo2f(d.x)); m1 = fmaxf(m1, hi2f(d.x));
                m2 = fmaxf(m2, lo2f(d.y)); m3 = fmaxf(m3, hi2f(d.y));
                m4 = fmaxf(m4, lo2f(d.z)); m5 = fmaxf(m5, hi2f(d.z));
                m6 = fmaxf(m6, lo2f(d.w)); m7 = fmaxf(m7, hi2f(d.w));
            }
            uint4 ov;
            ov.x = pkbf(m0, m1); ov.y = pkbf(m2, m3);
            ov.z = pkbf(m4, m5); ov.w = pkbf(m6, m7);
            *(uint4*)&p2s[((3 * s + pyl) * 10 + px) * 64 + ocg * 8] = ov;
        }
    };

    stage(0);
    __syncthreads();
    for (int s = 0; s < 4; ++s) {
        conv2_strip(s);
        __syncthreads();
        pool_strip(s);
        if (s < 3) stage(s + 1);
        __syncthreads();
    }

    // conv3
    {
        const int oc3 = w * 16 + l16;
        int mbase[4];
        #pragma unroll
        for (int j = 0; j < 4; ++j) {
            int px = j * 16 + l16;
            int oy = px >> 3, ox = px & 7;
            mbase[j] = (oy * 10 + ox) * 64 + q * 8;
        }
        f32x4 acc3[4];
        #pragma unroll
        for (int j = 0; j < 4; ++j) acc3[j] = f32x4{0.f, 0.f, 0.f, 0.f};
        s16x8 B3c = *(const s16x8*)(w3 + oc3 * 64 + q * 8);
        for (int c = 0; c < 18; ++c) {
            s16x8 B3n = B3c;
            if (c < 17) {
                int cn = c + 1;
                B3n = *(const s16x8*)(w3 + ((cn >> 1) * 64 + oc3) * 64 + (cn & 1) * 32 + q * 8);
            }
            int kp = c >> 1, ky = kp / 3, kx = kp - ky * 3;
            int aoff = (ky * 10 + kx) * 64 + (c & 1) * 32;
            #pragma unroll
            for (int j = 0; j < 4; ++j) {
                s16x8 A = *(const s16x8*)(p2s + mbase[j] + aoff);
                acc3[j] = __builtin_amdgcn_mfma_f32_16x16x32_bf16(A, B3c, acc3[j], 0, 0, 0);
            }
            B3c = B3n;
        }
        float bias = c3b[oc3], al = a3[oc3];
        #pragma unroll
        for (int j = 0; j < 4; ++j)
        #pragma unroll
        for (int r = 0; r < 4; ++r) {
            int row = j * 16 + q * 4 + r;
            float val = acc3[j][r] + bias;
            val = fmaxf(val, 0.f) + al * fminf(val, 0.f);
            c3buf[row * 64 + oc3] = f2bf(val);
        }
    }
    __syncthreads();

    // pool3
    for (int t = tid; t < 1024; t += 256) {
        int oc = t & 63, r = t >> 6, py = r >> 2, pxo = r & 3;
        float m = -3e38f;
        #pragma unroll
        for (int ky = 0; ky < 2; ++ky)
        #pragma unroll
        for (int kx = 0; kx < 2; ++kx)
            m = fmaxf(m, bf2f(c3buf[((py * 2 + ky) * 8 + pxo * 2 + kx) * 64 + oc]));
        p3[t] = f2bf(m);
    }
    __syncthreads();

    // conv4
    {
        int px = l16 < 9 ? l16 : 8;
        int oy = px / 3, ox = px - oy * 3;
        const int mb4 = (oy * 4 + ox) * 64 + q * 8;
        const int oc4a = (w * 2) * 16 + l16, oc4b = (w * 2 + 1) * 16 + l16;
        f32x4 acc4[2] = {{0.f,0.f,0.f,0.f},{0.f,0.f,0.f,0.f}};
        s16x8 B4c[2];
        B4c[0] = *(const s16x8*)(w4 + oc4a * 64 + q * 8);
        B4c[1] = *(const s16x8*)(w4 + oc4b * 64 + q * 8);
        for (int c = 0; c < 8; ++c) {
            s16x8 B4n[2] = {B4c[0], B4c[1]};
            if (c < 7) {
                int cn = c + 1;
                int boff = (cn >> 1) * 8192 + (cn & 1) * 32 + q * 8;
                B4n[0] = *(const s16x8*)(w4 + boff + oc4a * 64);
                B4n[1] = *(const s16x8*)(w4 + boff + oc4b * 64);
            }
            int kp = c >> 1, ky = kp >> 1, kx = kp & 1;
            s16x8 A = *(const s16x8*)(p3 + mb4 + (ky * 4 + kx) * 64 + (c & 1) * 32);
            acc4[0] = __builtin_amdgcn_mfma_f32_16x16x32_bf16(A, B4c[0], acc4[0], 0, 0, 0);
            acc4[1] = __builtin_amdgcn_mfma_f32_16x16x32_bf16(A, B4c[1], acc4[1], 0, 0, 0);
            B4c[0] = B4n[0]; B4c[1] = B4n[1];
        }
        #pragma unroll
        for (int h = 0; h < 2; ++h) {
            int oc = h ? oc4b : oc4a;
            float bias = c4b[oc], al = a4[oc];
            #pragma unroll
            for (int r = 0; r < 4; ++r) {
                int row = q * 4 + r;
                if (row < 9) {
                    int hy = row / 3, wx = row - hy * 3;
                    float val = acc4[h][r] + bias;
                    val = fmaxf(val, 0.f) + al * fminf(val, 0.f);
                    flat[(unsigned)n * 1152u + (wx * 3 + hy) * 128 + oc] = f2bf(val);
                }
            }
        }
    }
}

// ---------------------------------------------------------------------------
// K5a (unchanged): d5 GEMM half — 256 blocks, block = 16 images x 128 oc.
// ---------------------------------------------------------------------------
__global__ __launch_bounds__(256, 2)
void k5a_gemm(const unsigned short* __restrict__ flat, const unsigned short* __restrict__ w5,
              const float* __restrict__ d5b, const float* __restrict__ a5,
              unsigned short* __restrict__ h) {
    __shared__ float hbuf[4 * 16 * 128];   // 32 KB
    const int blk = blockIdx.x, tid = threadIdx.x;
    const int w = tid >> 6, lane = tid & 63, q = lane >> 4, l16 = lane & 15;
    const int img0 = (blk >> 1) * 16, ocb = (blk & 1) * 128;
    const int img = img0 + l16;

    f32x4 acc[8];
    #pragma unroll
    for (int nt = 0; nt < 8; ++nt) acc[nt] = f32x4{0.f, 0.f, 0.f, 0.f};

    for (int cc = 0; cc < 9; ++cc) {
        int c = w * 9 + cc;
        int k0 = c * 32 + q * 8;
        s16x8 A = *(const s16x8*)(flat + (unsigned)img * 1152u + k0);
        #pragma unroll
        for (int nt = 0; nt < 8; ++nt) {
            int oc = ocb + nt * 16 + l16;
            s16x8 B = *(const s16x8*)(w5 + (unsigned)oc * 1152u + k0);
            acc[nt] = __builtin_amdgcn_mfma_f32_16x16x32_bf16(A, B, acc[nt], 0, 0, 0);
        }
    }
    #pragma unroll
    for (int nt = 0; nt < 8; ++nt)
    #pragma unroll
    for (int r = 0; r < 4; ++r) {
        int row = q * 4 + r;
        hbuf[(w * 16 + row) * 128 + nt * 16 + l16] = acc[nt][r];
    }
    __syncthreads();
    for (int t = tid; t < 1024; t += 256) {
        int im = t >> 6, oc2 = (t & 63) * 2;
        float s0 = hbuf[im * 128 + oc2]        + hbuf[(16 + im) * 128 + oc2]
                 + hbuf[(32 + im) * 128 + oc2] + hbuf[(48 + im) * 128 + oc2];
        float s1 = hbuf[im * 128 + oc2 + 1]        + hbuf[(16 + im) * 128 + oc2 + 1]
                 + hbuf[(32 + im) * 128 + oc2 + 1] + hbuf[(48 + im) * 128 + oc2 + 1];
        int oc = ocb + oc2;
        s0 += d5b[oc];     s0 = fmaxf(s0, 0.f) + a5[oc] * fminf(s0, 0.f);
        s1 += d5b[oc + 1]; s1 = fmaxf(s1, 0.f) + a5[oc + 1] * fminf(s1, 0.f);
        *(unsigned*)&h[(unsigned)(img0 + im) * 256u + oc] = pkbf(s0, s1);
    }
}

// ---------------------------------------------------------------------------
// K5b (unchanged): heads from h — 128 blocks x 16 images.
// ---------------------------------------------------------------------------
__global__ __launch_bounds__(256, 2)
void k5b_head(const unsigned short* __restrict__ h,
              const float* __restrict__ d61w, const float* __restrict__ d61b,
              const float* __restrict__ d62w, const float* __restrict__ d62b,
              const float* __restrict__ d63w, const float* __restrict__ d63b,
              float* __restrict__ out) {
    __shared__ float hL[16 * 260];
    __shared__ float wl[16 * 260];
    __shared__ float lg[256];
    const int blk = blockIdx.x, tid = threadIdx.x;
    const int img0 = blk * 16;

    for (int t = tid; t < 512; t += 256) {
        int im = t >> 5, g = t & 31;
        uint4 d = *(const uint4*)&h[(unsigned)(img0 + im) * 256u + g * 8];
        float* dst = &hL[im * 260 + g * 8];
        dst[0] = lo2f(d.x); dst[1] = hi2f(d.x);
        dst[2] = lo2f(d.y); dst[3] = hi2f(d.y);
        dst[4] = lo2f(d.z); dst[5] = hi2f(d.z);
        dst[6] = lo2f(d.w); dst[7] = hi2f(d.w);
    }
    {
        int o = tid >> 4, seg = tid & 15;
        const float* wrow = (o < 2) ? d61w + o * 256
                          : (o < 6) ? d62w + (o - 2) * 256
                          :           d63w + (o - 6) * 256;
        #pragma unroll
        for (int j = 0; j < 4; ++j)
            *(float4*)&wl[o * 260 + seg * 16 + j * 4] = ((const float4*)wrow)[seg * 4 + j];
    }
    __syncthreads();

    const int im = tid >> 4, o = tid & 15;
    {
        float bias = (o < 2) ? d61b[o] : (o < 6) ? d62b[o - 2] : d63b[o - 6];
        float s = bias;
        const float4* ha = (const float4*)&hL[im * 260];
        const float4* wa = (const float4*)&wl[o * 260];
        #pragma unroll 8
        for (int k = 0; k < 64; ++k) {
            float4 a = ha[k], b = wa[k];
            s += a.x * b.x + a.y * b.y + a.z * b.z + a.w * b.w;
        }
        lg[im * 16 + o] = s;
    }
    __syncthreads();
    {
        int gimg = img0 + im;
        float v = lg[im * 16 + o];
        if (o >= 2 && o < 6) {
            out[gimg * 4 + (o - 2)] = v;
        } else if (o >= 6) {
            out[8192 + gimg * 10 + (o - 6)] = v;
        } else {
            float l0 = lg[im * 16 + 0], l1 = lg[im * 16 + 1];
            float mx = fmaxf(l0, l1);
            float e0 = __expf(l0 - mx), e1 = __expf(l1 - mx);
            out[28672 + gimg * 2 + o] = (o == 0 ? e0 : e1) / (e0 + e1);
        }
    }
}

// ---------------------------------------------------------------------------
extern "C" void kernel_launch(void* const* d_in, const int* in_sizes, int n_in,
                              void* d_out, int out_size, void* d_ws, size_t ws_size,
                              hipStream_t stream) {
    (void)in_sizes; (void)n_in; (void)out_size; (void)ws_size;
    const float* x    = (const float*)d_in[0];
    const float* c1w  = (const float*)d_in[1];
    const float* c1b  = (const float*)d_in[2];
    const float* a1   = (const float*)d_in[3];
    const float* c2w  = (const float*)d_in[4];
    const float* c2b  = (const float*)d_in[5];
    const float* a2   = (const float*)d_in[6];
    const float* c3w  = (const float*)d_in[7];
    const float* c3b  = (const float*)d_in[8];
    const float* a3   = (const float*)d_in[9];
    const float* c4w  = (const float*)d_in[10];
    const float* c4b  = (const float*)d_in[11];
    const float* a4   = (const float*)d_in[12];
    const float* d5w  = (const float*)d_in[13];
    const float* d5b  = (const float*)d_in[14];
    const float* a5   = (const float*)d_in[15];
    const float* d61w = (const float*)d_in[16];
    const float* d61b = (const float*)d_in[17];
    const float* d62w = (const float*)d_in[18];
    const float* d62b = (const float*)d_in[19];
    const float* d63w = (const float*)d_in[20];
    const float* d63b = (const float*)d_in[21];

    char* ws = (char*)d_ws;
    // region plan:
    //   p1    @ 0          : 69,337,088 B  (live through k23_fused)
    //   flat  @ 69,337,088 : 4,718,592 B
    //   h     @ 74,055,680 : 1,048,576 B
    //   weights @ 186,777,600 : ~766 KB
    unsigned short* p1    = (unsigned short*)(ws + 0);
    unsigned short* flat  = (unsigned short*)(ws + 69337088);
    unsigned short* h     = (unsigned short*)(ws + 74055680);
    unsigned short* w2    = (unsigned short*)(ws + 186777600);
    unsigned short* w3    = (unsigned short*)(ws + 186814464);
    unsigned short* w4    = (unsigned short*)(ws + 186888192);
    unsigned short* w5    = (unsigned short*)(ws + 186953728);

    k0_prep  <<<1496, 256, 0, stream>>>(c2w, c3w, c4w, d5w, w2, w3, w4, w5);
    k1_conv1 <<<2048, 256, 0, stream>>>(x, c1w, c1b, a1, p1);
    k23_fused<<<2048, 256, 0, stream>>>(p1, w2, c2b, a2, w3, c3b, a3, w4, c4b, a4, flat);
    k5a_gemm <<<256, 256, 0, stream>>>(flat, w5, d5b, a5, h);
    k5b_head <<<128, 256, 0, stream>>>(h, d61w, d61b, d62w, d62b, d63w, d63b,
                                       (float*)d_out);
}

// Round 11
// 316.166 us; speedup vs baseline: 1.8461x; 1.0123x over previous
//
#include <hip/hip_runtime.h>
#include <hip/hip_bf16.h>
#include <hip/hip_fp16.h>
#include <stdint.h>

typedef short s16x8 __attribute__((ext_vector_type(8)));
typedef unsigned short u16x8 __attribute__((ext_vector_type(8)));
typedef _Float16 f16x8 __attribute__((ext_vector_type(8)));
typedef float f32x4 __attribute__((ext_vector_type(4)));

__device__ __forceinline__ unsigned short f2bf(float f) {
    union { float f; unsigned u; } v; v.f = f;
    unsigned u = v.u;
    unsigned r = u + 0x7fffu + ((u >> 16) & 1u);
    return (unsigned short)(r >> 16);
}
__device__ __forceinline__ float bf2f(unsigned short h) {
    union { unsigned u; float f; } v; v.u = ((unsigned)h) << 16;
    return v.f;
}
__device__ __forceinline__ unsigned pkbf(float a, float b) {
    __hip_bfloat162 h = __float22bfloat162_rn(float2{a, b});
    union { __hip_bfloat162 h; unsigned u; } c; c.h = h; return c.u;
}
__device__ __forceinline__ float lo2f(unsigned d) {
    union { unsigned u; float f; } v; v.u = d << 16; return v.f;
}
__device__ __forceinline__ float hi2f(unsigned d) {
    union { unsigned u; float f; } v; v.u = d & 0xffff0000u; return v.f;
}
__device__ __forceinline__ unsigned short f2h(float f) {
    __half h = __float2half(f);
    union { __half h; unsigned short u; } c; c.h = h; return c.u;
}

// ---------------------------------------------------------------------------
// K0: weight repack (fp32 OIHW -> bf16 [kpos][oc][ic]), d5w -> bf16
// ---------------------------------------------------------------------------
__global__ void k0_prep(const float* __restrict__ c2w, const float* __restrict__ c3w,
                        const float* __restrict__ c4w, const float* __restrict__ d5w,
                        unsigned short* __restrict__ w2, unsigned short* __restrict__ w3,
                        unsigned short* __restrict__ w4, unsigned short* __restrict__ w5) {
    int t = blockIdx.x * 256 + threadIdx.x;
    if (t < 18432) {            // w2 [9][64][32] <- c2w [64][32][3][3]
        int kpos = t / 2048, rem = t % 2048, oc = rem / 32, ic = rem % 32;
        w2[t] = f2bf(c2w[(oc * 32 + ic) * 9 + kpos]);
        return;
    }
    t -= 18432;
    if (t < 36864) {            // w3 [9][64][64] <- c3w [64][64][3][3]
        int kpos = t / 4096, rem = t % 4096, oc = rem / 64, ic = rem % 64;
        w3[t] = f2bf(c3w[(oc * 64 + ic) * 9 + kpos]);
        return;
    }
    t -= 36864;
    if (t < 32768) {            // w4 [4][128][64] <- c4w [128][64][2][2]
        int kpos = t / 8192, rem = t % 8192, oc = rem / 64, ic = rem % 64;
        w4[t] = f2bf(c4w[(oc * 64 + ic) * 4 + kpos]);
        return;
    }
    t -= 32768;
    if (t < 294912) w5[t] = f2bf(d5w[t]);   // [256][1152] bf16
}

// ---------------------------------------------------------------------------
// K1 (R10, unchanged): conv1 via single fp16 MFMA -> p1 bf16 [n][23][23][32]
// ---------------------------------------------------------------------------
__global__ __launch_bounds__(256, 6)
void k1_conv1(const float* __restrict__ x, const float* __restrict__ c1w,
              const float* __restrict__ c1b, const float* __restrict__ a1,
              unsigned short* __restrict__ p1) {
    __shared__ unsigned short xstrip[1008];      // [ic][7 rows][48] fp16 bits (2 KB)
    __shared__ unsigned short cbuf[230 * 40];    // [flat px][32 oc + 8 pad] bf16 (18.4 KB)
    __shared__ unsigned short wlds[1024];        // [32 oc][32 k] fp16, k>=27 zero (2 KB)
    __shared__ float bls[32], als[32];

    const int n = blockIdx.x, tid = threadIdx.x;
    const int w = tid >> 6, lane = tid & 63, q = lane >> 4, l16 = lane & 15;

    for (int t = tid; t < 1024; t += 256) {
        int oc = t >> 5, k = t & 31;
        wlds[t] = (k < 27) ? f2h(c1w[oc * 27 + k]) : (unsigned short)0;
    }
    if (tid < 32) { bls[tid] = c1b[tid]; als[tid] = a1[tid]; }
    __syncthreads();

    f16x8 Wf[2];
    #pragma unroll
    for (int nt = 0; nt < 2; ++nt) {
        union { u16x8 u; f16x8 f; } cc;
        cc.u = *(const u16x8*)(wlds + (nt * 16 + l16) * 32 + q * 8);
        Wf[nt] = cc.f;
    }

    float bq[2][4], aq[2][4];
    #pragma unroll
    for (int nt = 0; nt < 2; ++nt)
    #pragma unroll
    for (int r = 0; r < 4; ++r) {
        bq[nt][r] = bls[nt * 16 + q * 4 + r];
        aq[nt][r] = als[nt * 16 + q * 4 + r];
    }

    int off[8];
    #pragma unroll
    for (int j = 0; j < 8; ++j) {
        int k = q * 8 + j;
        int kk = k < 27 ? k : 26;
        int ic = kk / 9, r9 = kk - ic * 9, ky = r9 / 3, kx = r9 - ky * 3;
        off[j] = ic * 336 + ky * 48 + kx;
    }

    auto do_pool = [&](int sp, int nprows, int kymax) {
        int ntask = nprows * 92;
        int t = tid;
        if (t < ntask) {
            int ocg = t & 3; unsigned r2 = (unsigned)t >> 2;
            int px = (int)(r2 % 23u), py_l = (int)(r2 / 23u);
            int kxmax = (px == 22) ? 2 : 3;
            int base = (2 * py_l * 46 + 2 * px) * 40 + ocg * 8;
            float m0 = -3e38f, m1 = -3e38f, m2 = -3e38f, m3 = -3e38f;
            float m4 = -3e38f, m5 = -3e38f, m6 = -3e38f, m7 = -3e38f;
            #pragma unroll
            for (int ky = 0; ky < 3; ++ky) {
                if (ky < kymax) {
                    #pragma unroll
                    for (int kx = 0; kx < 3; ++kx) {
                        if (kx < kxmax) {
                            uint4 d = *(const uint4*)&cbuf[base + (ky * 46 + kx) * 40];
                            m0 = fmaxf(m0, lo2f(d.x)); m1 = fmaxf(m1, hi2f(d.x));
                            m2 = fmaxf(m2, lo2f(d.y)); m3 = fmaxf(m3, hi2f(d.y));
                            m4 = fmaxf(m4, lo2f(d.z)); m5 = fmaxf(m5, hi2f(d.z));
                            m6 = fmaxf(m6, lo2f(d.w)); m7 = fmaxf(m7, hi2f(d.w));
                        }
                    }
                }
            }
            uint4 ov;
            ov.x = pkbf(m0, m1); ov.y = pkbf(m2, m3);
            ov.z = pkbf(m4, m5); ov.w = pkbf(m6, m7);
            int py = 2 * sp + py_l;
            *(uint4*)&p1[n * 16928 + (py * 23 + px) * 32 + ocg * 8] = ov;
        }
    };

    for (int s = 0; s < 12; ++s) {
        const int nrows = (s == 11) ? 2 : 5;
        const int P = 46 * nrows;
        const int ntiles = (P + 15) >> 4;
        const int xr0 = 4 * s;

        {
            int t4 = tid;
            if (t4 < 252) {
                int ic = t4 / 84;
                int rem4 = t4 * 4 - ic * 336;
                int rr = rem4 / 48, col = rem4 - rr * 48;
                int row = xr0 + rr; if (row > 47) row = 47;
                float4 f = *(const float4*)(x + n * 6912 + ic * 2304 + row * 48 + col);
                ushort4 o;
                o.x = f2h(f.x); o.y = f2h(f.y); o.z = f2h(f.z); o.w = f2h(f.w);
                *(ushort4*)&xstrip[t4 * 4] = o;
            }
        }
        if (s > 0) do_pool(s - 1, 2, 3);
        __syncthreads();

        for (int T = w; T < ntiles; T += 4) {
            int px = T * 16 + l16;
            int p = px < P ? px : P - 1;
            int ry = p / 46, cx = p - ry * 46;
            int basex = ry * 48 + cx;
            union { u16x8 u; f16x8 f; } xcc;
            #pragma unroll
            for (int j = 0; j < 8; ++j) xcc.u[j] = xstrip[basex + off[j]];
            f16x8 Xf = xcc.f;
            f32x4 acc[2] = {{0.f,0.f,0.f,0.f},{0.f,0.f,0.f,0.f}};
            #pragma unroll
            for (int nt = 0; nt < 2; ++nt)
                acc[nt] = __builtin_amdgcn_mfma_f32_16x16x32_f16(Wf[nt], Xf, acc[nt], 0, 0, 0);
            if (px < P) {
                #pragma unroll
                for (int nt = 0; nt < 2; ++nt) {
                    float v0 = acc[nt][0] + bq[nt][0];
                    float v1 = acc[nt][1] + bq[nt][1];
                    float v2 = acc[nt][2] + bq[nt][2];
                    float v3 = acc[nt][3] + bq[nt][3];
                    v0 = fmaxf(v0, 0.f) + aq[nt][0] * fminf(v0, 0.f);
                    v1 = fmaxf(v1, 0.f) + aq[nt][1] * fminf(v1, 0.f);
                    v2 = fmaxf(v2, 0.f) + aq[nt][2] * fminf(v2, 0.f);
                    v3 = fmaxf(v3, 0.f) + aq[nt][3] * fminf(v3, 0.f);
                    uint2 pk; pk.x = pkbf(v0, v1); pk.y = pkbf(v2, v3);
                    *(uint2*)&cbuf[px * 40 + nt * 16 + q * 4] = pk;
                }
            }
        }
        __syncthreads();
    }
    do_pool(11, 1, 2);
}

// ---------------------------------------------------------------------------
// K23 (R11): fused conv2+pool2+conv3+pool3+conv4. Same structure as R9/R10;
// LDS BANK-CONFLICT FIX: pad the hot A-read arrays to 16B-aligned strides
// that are not 0 mod 32 dwords:
//   xs  px stride 32 -> 40 shorts (was 16 dw == 8-way for l16 lanes; now 2-way)
//   p2s px stride 64 -> 72 shorts (was 32 dw == 16-way; now 2-way)
//   p3  px stride 64 -> 72 shorts (same fix for conv4)
// R10 counters: SQ_LDS_BANK_CONFLICT 1.63e7 on a 108 us kernel; conv2's 180
// b128 reads/lane at 8-way and conv3's 72 at 16-way dominate LDS issue.
// LDS: xs [207][40] @0 (16560) | c2s [147][72] @16560 (21168)
//      p2s [100][72] @37728 (14400) | total 52128 -> 3 blocks/CU
//      c3buf [64][64] @0, p3 [16][72] @8192 (alias dead xs).
// ---------------------------------------------------------------------------
__global__ __launch_bounds__(256, 2)
void k23_fused(const unsigned short* __restrict__ p1, const unsigned short* __restrict__ w2,
               const float* __restrict__ c2b, const float* __restrict__ a2,
               const unsigned short* __restrict__ w3, const float* __restrict__ c3b,
               const float* __restrict__ a3, const unsigned short* __restrict__ w4,
               const float* __restrict__ c4b, const float* __restrict__ a4,
               unsigned short* __restrict__ flat) {
    __shared__ __align__(16) char smem[52128];
    unsigned short* xs    = (unsigned short*)(smem);            // [207 px][40]
    unsigned short* c2s   = (unsigned short*)(smem + 16560);    // [147][72]
    unsigned short* p2s   = (unsigned short*)(smem + 37728);    // [100][72]
    unsigned short* c3buf = (unsigned short*)(smem);            // alias (8 KB)
    unsigned short* p3    = (unsigned short*)(smem + 8192);     // alias [16][72]

    const int n = blockIdx.x, tid = threadIdx.x;
    const int w = tid >> 6, lane = tid & 63, q = lane >> 4, l16 = lane & 15;
    const unsigned short* p1n = p1 + n * 16928;

    const int npair = w & 1, tset = w >> 1;
    const int ocA = npair * 32 + l16, ocB = npair * 32 + 16 + l16;

    s16x8 B2[9][2];
    #pragma unroll
    for (int kp = 0; kp < 9; ++kp) {
        B2[kp][0] = *(const s16x8*)(w2 + (kp * 64 + ocA) * 32 + q * 8);
        B2[kp][1] = *(const s16x8*)(w2 + (kp * 64 + ocB) * 32 + q * 8);
    }
    const float b2a = c2b[ocA], b2b = c2b[ocB];
    const float a2a = a2[ocA],  a2b = a2[ocB];

    // stage 9 p1 rows (starting pr0=6s, clamped) into padded xs [px][40]
    auto stage = [&](int s) {
        int pr0 = 6 * s;
        for (int t = tid; t < 828; t += 256) {
            int pxl = t >> 2, c = t & 3;       // pxl 0..206, 4 uint4 of data per px
            int rr = pxl / 23, colpx = pxl - rr * 23;
            int prow = pr0 + rr; if (prow > 22) prow = 22;
            uint4 d = ((const uint4*)p1n)[(prow * 23 + colpx) * 4 + c];
            ((uint4*)xs)[pxl * 5 + c] = d;     // 40 shorts = 5 uint4 per px
        }
    };

    auto conv2_strip = [&](int s) {
        const int nr = (s == 3) ? 3 : 7;
        const int P = 21 * nr;
        const int ntiles = (P + 15) >> 4;
        const int half = (ntiles + 1) >> 1;
        const int T0 = tset * half;
        const int T1 = (T0 + half) < ntiles ? (T0 + half) : ntiles;
        for (int T = T0; T < T1; ++T) {
            int m = T * 16 + l16;
            int p = m < P ? m : P - 1;
            int ry = p / 21, ox = p - ry * 21;
            const unsigned short* ab = xs + (ry * 23 + ox) * 40 + q * 8;
            f32x4 acc0 = {0.f, 0.f, 0.f, 0.f}, acc1 = {0.f, 0.f, 0.f, 0.f};
            #pragma unroll
            for (int kp = 0; kp < 9; ++kp) {
                int ky = kp / 3, kx = kp - ky * 3;
                s16x8 A = *(const s16x8*)(ab + (ky * 23 + kx) * 40);
                acc0 = __builtin_amdgcn_mfma_f32_16x16x32_bf16(A, B2[kp][0], acc0, 0, 0, 0);
                acc1 = __builtin_amdgcn_mfma_f32_16x16x32_bf16(A, B2[kp][1], acc1, 0, 0, 0);
            }
            int rowb = T * 16 + q * 4;
            #pragma unroll
            for (int r = 0; r < 4; ++r) {
                int row = rowb + r;
                if (row < P) {
                    float v0 = acc0[r] + b2a;
                    v0 = fmaxf(v0, 0.f) + a2a * fminf(v0, 0.f);
                    c2s[row * 72 + npair * 32 + l16] = f2bf(v0);
                    float v1 = acc1[r] + b2b;
                    v1 = fmaxf(v1, 0.f) + a2b * fminf(v1, 0.f);
                    c2s[row * 72 + npair * 32 + 16 + l16] = f2bf(v1);
                }
            }
        }
    };

    auto pool_strip = [&](int s) {
        int nprow = (s == 3) ? 1 : 3;
        int ntask = nprow * 80;
        if (tid < ntask) {
            int ocg = tid & 7; int r2 = tid >> 3;
            int px = r2 % 10, pyl = r2 / 10;
            int base = (2 * pyl * 21 + 2 * px) * 72 + ocg * 8;
            float m0 = -3e38f, m1 = -3e38f, m2 = -3e38f, m3 = -3e38f;
            float m4 = -3e38f, m5 = -3e38f, m6 = -3e38f, m7 = -3e38f;
            #pragma unroll
            for (int ky = 0; ky < 3; ++ky)
            #pragma unroll
            for (int kx = 0; kx < 3; ++kx) {
                uint4 d = *(const uint4*)&c2s[base + (ky * 21 + kx) * 72];
                m0 = fmaxf(m0, lo2f(d.x)); m1 = fmaxf(m1, hi2f(d.x));
                m2 = fmaxf(m2, lo2f(d.y)); m3 = fmaxf(m3, hi2f(d.y));
                m4 = fmaxf(m4, lo2f(d.z)); m5 = fmaxf(m5, hi2f(d.z));
                m6 = fmaxf(m6, lo2f(d.w)); m7 = fmaxf(m7, hi2f(d.w));
            }
            uint4 ov;
            ov.x = pkbf(m0, m1); ov.y = pkbf(m2, m3);
            ov.z = pkbf(m4, m5); ov.w = pkbf(m6, m7);
            *(uint4*)&p2s[((3 * s + pyl) * 10 + px) * 72 + ocg * 8] = ov;
        }
    };

    stage(0);
    __syncthreads();
    for (int s = 0; s < 4; ++s) {
        conv2_strip(s);
        __syncthreads();
        pool_strip(s);
        if (s < 3) stage(s + 1);
        __syncthreads();
    }

    // conv3: wave w owns oc-tile w x all 4 M-tiles; 18 chunks, B prefetched
    {
        const int oc3 = w * 16 + l16;
        int mbase[4];
        #pragma unroll
        for (int j = 0; j < 4; ++j) {
            int px = j * 16 + l16;
            int oy = px >> 3, ox = px & 7;
            mbase[j] = (oy * 10 + ox) * 72 + q * 8;
        }
        f32x4 acc3[4];
        #pragma unroll
        for (int j = 0; j < 4; ++j) acc3[j] = f32x4{0.f, 0.f, 0.f, 0.f};
        s16x8 B3c = *(const s16x8*)(w3 + oc3 * 64 + q * 8);
        for (int c = 0; c < 18; ++c) {
            s16x8 B3n = B3c;
            if (c < 17) {
                int cn = c + 1;
                B3n = *(const s16x8*)(w3 + ((cn >> 1) * 64 + oc3) * 64 + (cn & 1) * 32 + q * 8);
            }
            int kp = c >> 1, ky = kp / 3, kx = kp - ky * 3;
            int aoff = (ky * 10 + kx) * 72 + (c & 1) * 32;
            #pragma unroll
            for (int j = 0; j < 4; ++j) {
                s16x8 A = *(const s16x8*)(p2s + mbase[j] + aoff);
                acc3[j] = __builtin_amdgcn_mfma_f32_16x16x32_bf16(A, B3c, acc3[j], 0, 0, 0);
            }
            B3c = B3n;
        }
        float bias = c3b[oc3], al = a3[oc3];
        #pragma unroll
        for (int j = 0; j < 4; ++j)
        #pragma unroll
        for (int r = 0; r < 4; ++r) {
            int row = j * 16 + q * 4 + r;
            float val = acc3[j][r] + bias;
            val = fmaxf(val, 0.f) + al * fminf(val, 0.f);
            c3buf[row * 64 + oc3] = f2bf(val);
        }
    }
    __syncthreads();

    // pool3 2x2 s2 (8->4) -> p3 [16][72]
    for (int t = tid; t < 1024; t += 256) {
        int oc = t & 63, r = t >> 6, py = r >> 2, pxo = r & 3;
        float m = -3e38f;
        #pragma unroll
        for (int ky = 0; ky < 2; ++ky)
        #pragma unroll
        for (int kx = 0; kx < 2; ++kx)
            m = fmaxf(m, bf2f(c3buf[((py * 2 + ky) * 8 + pxo * 2 + kx) * 64 + oc]));
        p3[r * 72 + oc] = f2bf(m);
    }
    __syncthreads();

    // conv4: wave w owns oc-tiles 2w,2w+1; 8 chunks, shared A + prefetched B
    {
        int px = l16 < 9 ? l16 : 8;
        int oy = px / 3, ox = px - oy * 3;
        const int mb4 = (oy * 4 + ox) * 72 + q * 8;
        const int oc4a = (w * 2) * 16 + l16, oc4b = (w * 2 + 1) * 16 + l16;
        f32x4 acc4[2] = {{0.f,0.f,0.f,0.f},{0.f,0.f,0.f,0.f}};
        s16x8 B4c[2];
        B4c[0] = *(const s16x8*)(w4 + oc4a * 64 + q * 8);
        B4c[1] = *(const s16x8*)(w4 + oc4b * 64 + q * 8);
        for (int c = 0; c < 8; ++c) {
            s16x8 B4n[2] = {B4c[0], B4c[1]};
            if (c < 7) {
                int cn = c + 1;
                int boff = (cn >> 1) * 8192 + (cn & 1) * 32 + q * 8;
                B4n[0] = *(const s16x8*)(w4 + boff + oc4a * 64);
                B4n[1] = *(const s16x8*)(w4 + boff + oc4b * 64);
            }
            int kp = c >> 1, ky = kp >> 1, kx = kp & 1;
            s16x8 A = *(const s16x8*)(p3 + mb4 + (ky * 4 + kx) * 72 + (c & 1) * 32);
            acc4[0] = __builtin_amdgcn_mfma_f32_16x16x32_bf16(A, B4c[0], acc4[0], 0, 0, 0);
            acc4[1] = __builtin_amdgcn_mfma_f32_16x16x32_bf16(A, B4c[1], acc4[1], 0, 0, 0);
            B4c[0] = B4n[0]; B4c[1] = B4n[1];
        }
        #pragma unroll
        for (int h = 0; h < 2; ++h) {
            int oc = h ? oc4b : oc4a;
            float bias = c4b[oc], al = a4[oc];
            #pragma unroll
            for (int r = 0; r < 4; ++r) {
                int row = q * 4 + r;
                if (row < 9) {
                    int hy = row / 3, wx = row - hy * 3;
                    float val = acc4[h][r] + bias;
                    val = fmaxf(val, 0.f) + al * fminf(val, 0.f);
                    flat[(unsigned)n * 1152u + (wx * 3 + hy) * 128 + oc] = f2bf(val);
                }
            }
        }
    }
}

// ---------------------------------------------------------------------------
// K5a (unchanged): d5 GEMM half — 256 blocks, block = 16 images x 128 oc.
// ---------------------------------------------------------------------------
__global__ __launch_bounds__(256, 2)
void k5a_gemm(const unsigned short* __restrict__ flat, const unsigned short* __restrict__ w5,
              const float* __restrict__ d5b, const float* __restrict__ a5,
              unsigned short* __restrict__ h) {
    __shared__ float hbuf[4 * 16 * 128];   // 32 KB
    const int blk = blockIdx.x, tid = threadIdx.x;
    const int w = tid >> 6, lane = tid & 63, q = lane >> 4, l16 = lane & 15;
    const int img0 = (blk >> 1) * 16, ocb = (blk & 1) * 128;
    const int img = img0 + l16;

    f32x4 acc[8];
    #pragma unroll
    for (int nt = 0; nt < 8; ++nt) acc[nt] = f32x4{0.f, 0.f, 0.f, 0.f};

    for (int cc = 0; cc < 9; ++cc) {
        int c = w * 9 + cc;
        int k0 = c * 32 + q * 8;
        s16x8 A = *(const s16x8*)(flat + (unsigned)img * 1152u + k0);
        #pragma unroll
        for (int nt = 0; nt < 8; ++nt) {
            int oc = ocb + nt * 16 + l16;
            s16x8 B = *(const s16x8*)(w5 + (unsigned)oc * 1152u + k0);
            acc[nt] = __builtin_amdgcn_mfma_f32_16x16x32_bf16(A, B, acc[nt], 0, 0, 0);
        }
    }
    #pragma unroll
    for (int nt = 0; nt < 8; ++nt)
    #pragma unroll
    for (int r = 0; r < 4; ++r) {
        int row = q * 4 + r;
        hbuf[(w * 16 + row) * 128 + nt * 16 + l16] = acc[nt][r];
    }
    __syncthreads();
    for (int t = tid; t < 1024; t += 256) {
        int im = t >> 6, oc2 = (t & 63) * 2;
        float s0 = hbuf[im * 128 + oc2]        + hbuf[(16 + im) * 128 + oc2]
                 + hbuf[(32 + im) * 128 + oc2] + hbuf[(48 + im) * 128 + oc2];
        float s1 = hbuf[im * 128 + oc2 + 1]        + hbuf[(16 + im) * 128 + oc2 + 1]
                 + hbuf[(32 + im) * 128 + oc2 + 1] + hbuf[(48 + im) * 128 + oc2 + 1];
        int oc = ocb + oc2;
        s0 += d5b[oc];     s0 = fmaxf(s0, 0.f) + a5[oc] * fminf(s0, 0.f);
        s1 += d5b[oc + 1]; s1 = fmaxf(s1, 0.f) + a5[oc + 1] * fminf(s1, 0.f);
        *(unsigned*)&h[(unsigned)(img0 + im) * 256u + oc] = pkbf(s0, s1);
    }
}

// ---------------------------------------------------------------------------
// K5b (unchanged): heads from h — 128 blocks x 16 images.
// ---------------------------------------------------------------------------
__global__ __launch_bounds__(256, 2)
void k5b_head(const unsigned short* __restrict__ h,
              const float* __restrict__ d61w, const float* __restrict__ d61b,
              const float* __restrict__ d62w, const float* __restrict__ d62b,
              const float* __restrict__ d63w, const float* __restrict__ d63b,
              float* __restrict__ out) {
    __shared__ float hL[16 * 260];
    __shared__ float wl[16 * 260];
    __shared__ float lg[256];
    const int blk = blockIdx.x, tid = threadIdx.x;
    const int img0 = blk * 16;

    for (int t = tid; t < 512; t += 256) {
        int im = t >> 5, g = t & 31;
        uint4 d = *(const uint4*)&h[(unsigned)(img0 + im) * 256u + g * 8];
        float* dst = &hL[im * 260 + g * 8];
        dst[0] = lo2f(d.x); dst[1] = hi2f(d.x);
        dst[2] = lo2f(d.y); dst[3] = hi2f(d.y);
        dst[4] = lo2f(d.z); dst[5] = hi2f(d.z);
        dst[6] = lo2f(d.w); dst[7] = hi2f(d.w);
    }
    {
        int o = tid >> 4, seg = tid & 15;
        const float* wrow = (o < 2) ? d61w + o * 256
                          : (o < 6) ? d62w + (o - 2) * 256
                          :           d63w + (o - 6) * 256;
        #pragma unroll
        for (int j = 0; j < 4; ++j)
            *(float4*)&wl[o * 260 + seg * 16 + j * 4] = ((const float4*)wrow)[seg * 4 + j];
    }
    __syncthreads();

    const int im = tid >> 4, o = tid & 15;
    {
        float bias = (o < 2) ? d61b[o] : (o < 6) ? d62b[o - 2] : d63b[o - 6];
        float s = bias;
        const float4* ha = (const float4*)&hL[im * 260];
        const float4* wa = (const float4*)&wl[o * 260];
        #pragma unroll 8
        for (int k = 0; k < 64; ++k) {
            float4 a = ha[k], b = wa[k];
            s += a.x * b.x + a.y * b.y + a.z * b.z + a.w * b.w;
        }
        lg[im * 16 + o] = s;
    }
    __syncthreads();
    {
        int gimg = img0 + im;
        float v = lg[im * 16 + o];
        if (o >= 2 && o < 6) {
            out[gimg * 4 + (o - 2)] = v;
        } else if (o >= 6) {
            out[8192 + gimg * 10 + (o - 6)] = v;
        } else {
            float l0 = lg[im * 16 + 0], l1 = lg[im * 16 + 1];
            float mx = fmaxf(l0, l1);
            float e0 = __expf(l0 - mx), e1 = __expf(l1 - mx);
            out[28672 + gimg * 2 + o] = (o == 0 ? e0 : e1) / (e0 + e1);
        }
    }
}

// ---------------------------------------------------------------------------
extern "C" void kernel_launch(void* const* d_in, const int* in_sizes, int n_in,
                              void* d_out, int out_size, void* d_ws, size_t ws_size,
                              hipStream_t stream) {
    (void)in_sizes; (void)n_in; (void)out_size; (void)ws_size;
    const float* x    = (const float*)d_in[0];
    const float* c1w  = (const float*)d_in[1];
    const float* c1b  = (const float*)d_in[2];
    const float* a1   = (const float*)d_in[3];
    const float* c2w  = (const float*)d_in[4];
    const float* c2b  = (const float*)d_in[5];
    const float* a2   = (const float*)d_in[6];
    const float* c3w  = (const float*)d_in[7];
    const float* c3b  = (const float*)d_in[8];
    const float* a3   = (const float*)d_in[9];
    const float* c4w  = (const float*)d_in[10];
    const float* c4b  = (const float*)d_in[11];
    const float* a4   = (const float*)d_in[12];
    const float* d5w  = (const float*)d_in[13];
    const float* d5b  = (const float*)d_in[14];
    const float* a5   = (const float*)d_in[15];
    const float* d61w = (const float*)d_in[16];
    const float* d61b = (const float*)d_in[17];
    const float* d62w = (const float*)d_in[18];
    const float* d62b = (const float*)d_in[19];
    const float* d63w = (const float*)d_in[20];
    const float* d63b = (const float*)d_in[21];

    char* ws = (char*)d_ws;
    // region plan:
    //   p1    @ 0          : 69,337,088 B  (live through k23_fused)
    //   flat  @ 69,337,088 : 4,718,592 B
    //   h     @ 74,055,680 : 1,048,576 B
    //   weights @ 186,777,600 : ~766 KB
    unsigned short* p1    = (unsigned short*)(ws + 0);
    unsigned short* flat  = (unsigned short*)(ws + 69337088);
    unsigned short* h     = (unsigned short*)(ws + 74055680);
    unsigned short* w2    = (unsigned short*)(ws + 186777600);
    unsigned short* w3    = (unsigned short*)(ws + 186814464);
    unsigned short* w4    = (unsigned short*)(ws + 186888192);
    unsigned short* w5    = (unsigned short*)(ws + 186953728);

    k0_prep  <<<1496, 256, 0, stream>>>(c2w, c3w, c4w, d5w, w2, w3, w4, w5);
    k1_conv1 <<<2048, 256, 0, stream>>>(x, c1w, c1b, a1, p1);
    k23_fused<<<2048, 256, 0, stream>>>(p1, w2, c2b, a2, w3, c3b, a3, w4, c4b, a4, flat);
    k5a_gemm <<<256, 256, 0, stream>>>(flat, w5, d5b, a5, h);
    k5b_head <<<128, 256, 0, stream>>>(h, d61w, d61b, d62w, d62b, d63w, d63b,
                                       (float*)d_out);
}

// Round 13
// 296.872 us; speedup vs baseline: 1.9661x; 1.0650x over previous
//
#include <hip/hip_runtime.h>
#include <hip/hip_bf16.h>
#include <hip/hip_fp16.h>
#include <stdint.h>

typedef short s16x8 __attribute__((ext_vector_type(8)));
typedef unsigned short u16x8 __attribute__((ext_vector_type(8)));
typedef _Float16 f16x8 __attribute__((ext_vector_type(8)));
typedef __fp16 h16x2 __attribute__((ext_vector_type(2)));   // builtin's return type
typedef float f32x4 __attribute__((ext_vector_type(4)));

__device__ __forceinline__ unsigned short f2h(float f) {
    __half h = __float2half(f);
    union { __half h; unsigned short u; } c; c.h = h; return c.u;
}
__device__ __forceinline__ float h2f(unsigned short u) {
    union { unsigned short u; __half h; } c; c.u = u; return __half2float(c.h);
}
// pack two f32 -> two f16 in one VALU op (v_cvt_pkrtz_f16_f32; RTZ, <=1ulp)
__device__ __forceinline__ unsigned pkh(float a, float b) {
    union { h16x2 h; unsigned u; } c;
    c.h = __builtin_amdgcn_cvt_pkrtz(a, b);
    return c.u;
}

// ---------------------------------------------------------------------------
// K0: weight repack (fp32 OIHW -> FP16 [kpos][oc][ic]), d5w -> fp16
// ---------------------------------------------------------------------------
__global__ void k0_prep(const float* __restrict__ c2w, const float* __restrict__ c3w,
                        const float* __restrict__ c4w, const float* __restrict__ d5w,
                        unsigned short* __restrict__ w2, unsigned short* __restrict__ w3,
                        unsigned short* __restrict__ w4, unsigned short* __restrict__ w5) {
    int t = blockIdx.x * 256 + threadIdx.x;
    if (t < 18432) {            // w2 [9][64][32] <- c2w [64][32][3][3]
        int kpos = t / 2048, rem = t % 2048, oc = rem / 32, ic = rem % 32;
        w2[t] = f2h(c2w[(oc * 32 + ic) * 9 + kpos]);
        return;
    }
    t -= 18432;
    if (t < 36864) {            // w3 [9][64][64] <- c3w [64][64][3][3]
        int kpos = t / 4096, rem = t % 4096, oc = rem / 64, ic = rem % 64;
        w3[t] = f2h(c3w[(oc * 64 + ic) * 9 + kpos]);
        return;
    }
    t -= 36864;
    if (t < 32768) {            // w4 [4][128][64] <- c4w [128][64][2][2]
        int kpos = t / 8192, rem = t % 8192, oc = rem / 64, ic = rem % 64;
        w4[t] = f2h(c4w[(oc * 64 + ic) * 4 + kpos]);
        return;
    }
    t -= 32768;
    if (t < 294912) w5[t] = f2h(d5w[t]);   // [256][1152] fp16
}

// ---------------------------------------------------------------------------
// K1 (R13 = R12 fixed): conv1 fp16 MFMA; cbuf/p1 FP16; pool via packed
// v_pk_max_f16 (4 packed max per uint4 vs 16 extract+fmax).
// -> p1 fp16 [n][23][23][32]
// ---------------------------------------------------------------------------
__global__ __launch_bounds__(256, 6)
void k1_conv1(const float* __restrict__ x, const float* __restrict__ c1w,
              const float* __restrict__ c1b, const float* __restrict__ a1,
              unsigned short* __restrict__ p1) {
    __shared__ unsigned short xstrip[1008];      // [ic][7 rows][48] fp16 (2 KB)
    __shared__ unsigned short cbuf[230 * 40];    // [flat px][32 oc + 8 pad] fp16 (18.4 KB)
    __shared__ unsigned short wlds[1024];        // [32 oc][32 k] fp16, k>=27 zero (2 KB)
    __shared__ float bls[32], als[32];

    const int n = blockIdx.x, tid = threadIdx.x;
    const int w = tid >> 6, lane = tid & 63, q = lane >> 4, l16 = lane & 15;

    for (int t = tid; t < 1024; t += 256) {
        int oc = t >> 5, k = t & 31;
        wlds[t] = (k < 27) ? f2h(c1w[oc * 27 + k]) : (unsigned short)0;
    }
    if (tid < 32) { bls[tid] = c1b[tid]; als[tid] = a1[tid]; }
    __syncthreads();

    f16x8 Wf[2];
    #pragma unroll
    for (int nt = 0; nt < 2; ++nt) {
        union { u16x8 u; f16x8 f; } cc;
        cc.u = *(const u16x8*)(wlds + (nt * 16 + l16) * 32 + q * 8);
        Wf[nt] = cc.f;
    }

    float bq[2][4], aq[2][4];
    #pragma unroll
    for (int nt = 0; nt < 2; ++nt)
    #pragma unroll
    for (int r = 0; r < 4; ++r) {
        bq[nt][r] = bls[nt * 16 + q * 4 + r];
        aq[nt][r] = als[nt * 16 + q * 4 + r];
    }

    int off[8];
    #pragma unroll
    for (int j = 0; j < 8; ++j) {
        int k = q * 8 + j;
        int kk = k < 27 ? k : 26;
        int ic = kk / 9, r9 = kk - ic * 9, ky = r9 / 3, kx = r9 - ky * 3;
        off[j] = ic * 336 + ky * 48 + kx;
    }

    auto do_pool = [&](int sp, int nprows, int kymax) {
        int ntask = nprows * 92;
        int t = tid;
        if (t < ntask) {
            int ocg = t & 3; unsigned r2 = (unsigned)t >> 2;
            int px = (int)(r2 % 23u), py_l = (int)(r2 / 23u);
            int kxmax = (px == 22) ? 2 : 3;
            int base = (2 * py_l * 46 + 2 * px) * 40 + ocg * 8;
            f16x8 mx;
            #pragma unroll
            for (int j = 0; j < 8; ++j) mx[j] = (_Float16)(-60000.f);
            #pragma unroll
            for (int ky = 0; ky < 3; ++ky) {
                if (ky < kymax) {
                    #pragma unroll
                    for (int kx = 0; kx < 3; ++kx) {
                        if (kx < kxmax) {
                            union { uint4 u; f16x8 f; } d;
                            d.u = *(const uint4*)&cbuf[base + (ky * 46 + kx) * 40];
                            mx = __builtin_elementwise_max(mx, d.f);
                        }
                    }
                }
            }
            union { f16x8 f; uint4 u; } o; o.f = mx;
            int py = 2 * sp + py_l;
            *(uint4*)&p1[n * 16928 + (py * 23 + px) * 32 + ocg * 8] = o.u;
        }
    };

    for (int s = 0; s < 12; ++s) {
        const int nrows = (s == 11) ? 2 : 5;
        const int P = 46 * nrows;
        const int ntiles = (P + 15) >> 4;
        const int xr0 = 4 * s;

        {
            int t4 = tid;
            if (t4 < 252) {
                int ic = t4 / 84;
                int rem4 = t4 * 4 - ic * 336;
                int rr = rem4 / 48, col = rem4 - rr * 48;
                int row = xr0 + rr; if (row > 47) row = 47;
                float4 f = *(const float4*)(x + n * 6912 + ic * 2304 + row * 48 + col);
                uint2 o; o.x = pkh(f.x, f.y); o.y = pkh(f.z, f.w);
                *(uint2*)&xstrip[t4 * 4] = o;
            }
        }
        if (s > 0) do_pool(s - 1, 2, 3);
        __syncthreads();

        for (int T = w; T < ntiles; T += 4) {
            int px = T * 16 + l16;
            int p = px < P ? px : P - 1;
            int ry = p / 46, cx = p - ry * 46;
            int basex = ry * 48 + cx;
            union { u16x8 u; f16x8 f; } xcc;
            #pragma unroll
            for (int j = 0; j < 8; ++j) xcc.u[j] = xstrip[basex + off[j]];
            f16x8 Xf = xcc.f;
            f32x4 acc[2] = {{0.f,0.f,0.f,0.f},{0.f,0.f,0.f,0.f}};
            #pragma unroll
            for (int nt = 0; nt < 2; ++nt)
                acc[nt] = __builtin_amdgcn_mfma_f32_16x16x32_f16(Wf[nt], Xf, acc[nt], 0, 0, 0);
            if (px < P) {
                #pragma unroll
                for (int nt = 0; nt < 2; ++nt) {
                    float v0 = acc[nt][0] + bq[nt][0];
                    float v1 = acc[nt][1] + bq[nt][1];
                    float v2 = acc[nt][2] + bq[nt][2];
                    float v3 = acc[nt][3] + bq[nt][3];
                    v0 = fmaxf(v0, 0.f) + aq[nt][0] * fminf(v0, 0.f);
                    v1 = fmaxf(v1, 0.f) + aq[nt][1] * fminf(v1, 0.f);
                    v2 = fmaxf(v2, 0.f) + aq[nt][2] * fminf(v2, 0.f);
                    v3 = fmaxf(v3, 0.f) + aq[nt][3] * fminf(v3, 0.f);
                    uint2 pk; pk.x = pkh(v0, v1); pk.y = pkh(v2, v3);
                    *(uint2*)&cbuf[px * 40 + nt * 16 + q * 4] = pk;
                }
            }
        }
        __syncthreads();
    }
    do_pool(11, 1, 2);
}

// ---------------------------------------------------------------------------
// K23 (R13 = R12 fixed): fused conv2+pool2+conv3+pool3+conv4, ALL-FP16.
// fp16 MFMA; packed pool max; f2h/pkh epilogues. Structure/reg-budget from R9.
// LDS: xs [207][40] @0 (16560) | c2s [147][72] @16560 (21168)
//      p2s [100][72] @37728 (14400) | c3buf [64][64] @0, p3 [16][72] @8192.
// ---------------------------------------------------------------------------
__global__ __launch_bounds__(256, 2)
void k23_fused(const unsigned short* __restrict__ p1, const unsigned short* __restrict__ w2,
               const float* __restrict__ c2b, const float* __restrict__ a2,
               const unsigned short* __restrict__ w3, const float* __restrict__ c3b,
               const float* __restrict__ a3, const unsigned short* __restrict__ w4,
               const float* __restrict__ c4b, const float* __restrict__ a4,
               unsigned short* __restrict__ flat) {
    __shared__ __align__(16) char smem[52128];
    unsigned short* xs    = (unsigned short*)(smem);            // [207 px][40]
    unsigned short* c2s   = (unsigned short*)(smem + 16560);    // [147][72]
    unsigned short* p2s   = (unsigned short*)(smem + 37728);    // [100][72]
    unsigned short* c3buf = (unsigned short*)(smem);            // alias (8 KB)
    unsigned short* p3    = (unsigned short*)(smem + 8192);     // alias [16][72]

    const int n = blockIdx.x, tid = threadIdx.x;
    const int w = tid >> 6, lane = tid & 63, q = lane >> 4, l16 = lane & 15;
    const unsigned short* p1n = p1 + n * 16928;

    const int npair = w & 1, tset = w >> 1;
    const int ocA = npair * 32 + l16, ocB = npair * 32 + 16 + l16;

    f16x8 B2[9][2];
    #pragma unroll
    for (int kp = 0; kp < 9; ++kp) {
        union { u16x8 u; f16x8 f; } c0, c1;
        c0.u = *(const u16x8*)(w2 + (kp * 64 + ocA) * 32 + q * 8);
        c1.u = *(const u16x8*)(w2 + (kp * 64 + ocB) * 32 + q * 8);
        B2[kp][0] = c0.f; B2[kp][1] = c1.f;
    }
    const float b2a = c2b[ocA], b2b = c2b[ocB];
    const float a2a = a2[ocA],  a2b = a2[ocB];

    auto stage = [&](int s) {
        int pr0 = 6 * s;
        for (int t = tid; t < 828; t += 256) {
            int pxl = t >> 2, c = t & 3;
            int rr = pxl / 23, colpx = pxl - rr * 23;
            int prow = pr0 + rr; if (prow > 22) prow = 22;
            uint4 d = ((const uint4*)p1n)[(prow * 23 + colpx) * 4 + c];
            ((uint4*)xs)[pxl * 5 + c] = d;
        }
    };

    auto conv2_strip = [&](int s) {
        const int nr = (s == 3) ? 3 : 7;
        const int P = 21 * nr;
        const int ntiles = (P + 15) >> 4;
        const int half = (ntiles + 1) >> 1;
        const int T0 = tset * half;
        const int T1 = (T0 + half) < ntiles ? (T0 + half) : ntiles;
        for (int T = T0; T < T1; ++T) {
            int m = T * 16 + l16;
            int p = m < P ? m : P - 1;
            int ry = p / 21, ox = p - ry * 21;
            const unsigned short* ab = xs + (ry * 23 + ox) * 40 + q * 8;
            f32x4 acc0 = {0.f, 0.f, 0.f, 0.f}, acc1 = {0.f, 0.f, 0.f, 0.f};
            #pragma unroll
            for (int kp = 0; kp < 9; ++kp) {
                int ky = kp / 3, kx = kp - ky * 3;
                union { u16x8 u; f16x8 f; } av;
                av.u = *(const u16x8*)(ab + (ky * 23 + kx) * 40);
                acc0 = __builtin_amdgcn_mfma_f32_16x16x32_f16(av.f, B2[kp][0], acc0, 0, 0, 0);
                acc1 = __builtin_amdgcn_mfma_f32_16x16x32_f16(av.f, B2[kp][1], acc1, 0, 0, 0);
            }
            int rowb = T * 16 + q * 4;
            #pragma unroll
            for (int r = 0; r < 4; ++r) {
                int row = rowb + r;
                if (row < P) {
                    float v0 = acc0[r] + b2a;
                    v0 = fmaxf(v0, 0.f) + a2a * fminf(v0, 0.f);
                    c2s[row * 72 + npair * 32 + l16] = f2h(v0);
                    float v1 = acc1[r] + b2b;
                    v1 = fmaxf(v1, 0.f) + a2b * fminf(v1, 0.f);
                    c2s[row * 72 + npair * 32 + 16 + l16] = f2h(v1);
                }
            }
        }
    };

    auto pool_strip = [&](int s) {
        int nprow = (s == 3) ? 1 : 3;
        int ntask = nprow * 80;
        if (tid < ntask) {
            int ocg = tid & 7; int r2 = tid >> 3;
            int px = r2 % 10, pyl = r2 / 10;
            int base = (2 * pyl * 21 + 2 * px) * 72 + ocg * 8;
            f16x8 mx;
            #pragma unroll
            for (int j = 0; j < 8; ++j) mx[j] = (_Float16)(-60000.f);
            #pragma unroll
            for (int ky = 0; ky < 3; ++ky)
            #pragma unroll
            for (int kx = 0; kx < 3; ++kx) {
                union { uint4 u; f16x8 f; } d;
                d.u = *(const uint4*)&c2s[base + (ky * 21 + kx) * 72];
                mx = __builtin_elementwise_max(mx, d.f);
            }
            union { f16x8 f; uint4 u; } o; o.f = mx;
            *(uint4*)&p2s[((3 * s + pyl) * 10 + px) * 72 + ocg * 8] = o.u;
        }
    };

    stage(0);
    __syncthreads();
    for (int s = 0; s < 4; ++s) {
        conv2_strip(s);
        __syncthreads();
        pool_strip(s);
        if (s < 3) stage(s + 1);
        __syncthreads();
    }

    // conv3: wave w owns oc-tile w x all 4 M-tiles; 18 chunks, B prefetched
    {
        const int oc3 = w * 16 + l16;
        int mbase[4];
        #pragma unroll
        for (int j = 0; j < 4; ++j) {
            int px = j * 16 + l16;
            int oy = px >> 3, ox = px & 7;
            mbase[j] = (oy * 10 + ox) * 72 + q * 8;
        }
        f32x4 acc3[4];
        #pragma unroll
        for (int j = 0; j < 4; ++j) acc3[j] = f32x4{0.f, 0.f, 0.f, 0.f};
        union { u16x8 u; f16x8 f; } bc;
        bc.u = *(const u16x8*)(w3 + oc3 * 64 + q * 8);
        f16x8 B3c = bc.f;
        for (int c = 0; c < 18; ++c) {
            f16x8 B3n = B3c;
            if (c < 17) {
                int cn = c + 1;
                union { u16x8 u; f16x8 f; } bn;
                bn.u = *(const u16x8*)(w3 + ((cn >> 1) * 64 + oc3) * 64 + (cn & 1) * 32 + q * 8);
                B3n = bn.f;
            }
            int kp = c >> 1, ky = kp / 3, kx = kp - ky * 3;
            int aoff = (ky * 10 + kx) * 72 + (c & 1) * 32;
            #pragma unroll
            for (int j = 0; j < 4; ++j) {
                union { u16x8 u; f16x8 f; } av;
                av.u = *(const u16x8*)(p2s + mbase[j] + aoff);
                acc3[j] = __builtin_amdgcn_mfma_f32_16x16x32_f16(av.f, B3c, acc3[j], 0, 0, 0);
            }
            B3c = B3n;
        }
        float bias = c3b[oc3], al = a3[oc3];
        #pragma unroll
        for (int j = 0; j < 4; ++j)
        #pragma unroll
        for (int r = 0; r < 4; ++r) {
            int row = j * 16 + q * 4 + r;
            float val = acc3[j][r] + bias;
            val = fmaxf(val, 0.f) + al * fminf(val, 0.f);
            c3buf[row * 64 + oc3] = f2h(val);
        }
    }
    __syncthreads();

    // pool3 2x2 s2 (8->4), packed max -> p3 [16][72]
    if (tid < 128) {
        int ocg = tid & 7, r = tid >> 3;   // r = output px 0..15
        int py = r >> 2, pxo = r & 3;
        f16x8 mx;
        #pragma unroll
        for (int j = 0; j < 8; ++j) mx[j] = (_Float16)(-60000.f);
        #pragma unroll
        for (int ky = 0; ky < 2; ++ky)
        #pragma unroll
        for (int kx = 0; kx < 2; ++kx) {
            union { uint4 u; f16x8 f; } d;
            d.u = *(const uint4*)&c3buf[((py * 2 + ky) * 8 + pxo * 2 + kx) * 64 + ocg * 8];
            mx = __builtin_elementwise_max(mx, d.f);
        }
        union { f16x8 f; uint4 u; } o; o.f = mx;
        *(uint4*)&p3[r * 72 + ocg * 8] = o.u;
    }
    __syncthreads();

    // conv4: wave w owns oc-tiles 2w,2w+1; 8 chunks, shared A + prefetched B
    {
        int px = l16 < 9 ? l16 : 8;
        int oy = px / 3, ox = px - oy * 3;
        const int mb4 = (oy * 4 + ox) * 72 + q * 8;
        const int oc4a = (w * 2) * 16 + l16, oc4b = (w * 2 + 1) * 16 + l16;
        f32x4 acc4[2] = {{0.f,0.f,0.f,0.f},{0.f,0.f,0.f,0.f}};
        f16x8 B4c[2];
        {
            union { u16x8 u; f16x8 f; } b0, b1;
            b0.u = *(const u16x8*)(w4 + oc4a * 64 + q * 8);
            b1.u = *(const u16x8*)(w4 + oc4b * 64 + q * 8);
            B4c[0] = b0.f; B4c[1] = b1.f;
        }
        for (int c = 0; c < 8; ++c) {
            f16x8 B4n[2] = {B4c[0], B4c[1]};
            if (c < 7) {
                int cn = c + 1;
                int boff = (cn >> 1) * 8192 + (cn & 1) * 32 + q * 8;
                union { u16x8 u; f16x8 f; } b0, b1;
                b0.u = *(const u16x8*)(w4 + boff + oc4a * 64);
                b1.u = *(const u16x8*)(w4 + boff + oc4b * 64);
                B4n[0] = b0.f; B4n[1] = b1.f;
            }
            int kp = c >> 1, ky = kp >> 1, kx = kp & 1;
            union { u16x8 u; f16x8 f; } av;
            av.u = *(const u16x8*)(p3 + mb4 + (ky * 4 + kx) * 72 + (c & 1) * 32);
            acc4[0] = __builtin_amdgcn_mfma_f32_16x16x32_f16(av.f, B4c[0], acc4[0], 0, 0, 0);
            acc4[1] = __builtin_amdgcn_mfma_f32_16x16x32_f16(av.f, B4c[1], acc4[1], 0, 0, 0);
            B4c[0] = B4n[0]; B4c[1] = B4n[1];
        }
        #pragma unroll
        for (int h = 0; h < 2; ++h) {
            int oc = h ? oc4b : oc4a;
            float bias = c4b[oc], al = a4[oc];
            #pragma unroll
            for (int r = 0; r < 4; ++r) {
                int row = q * 4 + r;
                if (row < 9) {
                    int hy = row / 3, wx = row - hy * 3;
                    float val = acc4[h][r] + bias;
                    val = fmaxf(val, 0.f) + al * fminf(val, 0.f);
                    flat[(unsigned)n * 1152u + (wx * 3 + hy) * 128 + oc] = f2h(val);
                }
            }
        }
    }
}

// ---------------------------------------------------------------------------
// K5a (R13): d5 GEMM half, fp16 MFMA — 256 blocks, 16 images x 128 oc.
// ---------------------------------------------------------------------------
__global__ __launch_bounds__(256, 2)
void k5a_gemm(const unsigned short* __restrict__ flat, const unsigned short* __restrict__ w5,
              const float* __restrict__ d5b, const float* __restrict__ a5,
              unsigned short* __restrict__ h) {
    __shared__ float hbuf[4 * 16 * 128];   // 32 KB
    const int blk = blockIdx.x, tid = threadIdx.x;
    const int w = tid >> 6, lane = tid & 63, q = lane >> 4, l16 = lane & 15;
    const int img0 = (blk >> 1) * 16, ocb = (blk & 1) * 128;
    const int img = img0 + l16;

    f32x4 acc[8];
    #pragma unroll
    for (int nt = 0; nt < 8; ++nt) acc[nt] = f32x4{0.f, 0.f, 0.f, 0.f};

    for (int cc = 0; cc < 9; ++cc) {
        int c = w * 9 + cc;
        int k0 = c * 32 + q * 8;
        union { u16x8 u; f16x8 f; } av;
        av.u = *(const u16x8*)(flat + (unsigned)img * 1152u + k0);
        #pragma unroll
        for (int nt = 0; nt < 8; ++nt) {
            int oc = ocb + nt * 16 + l16;
            union { u16x8 u; f16x8 f; } bv;
            bv.u = *(const u16x8*)(w5 + (unsigned)oc * 1152u + k0);
            acc[nt] = __builtin_amdgcn_mfma_f32_16x16x32_f16(av.f, bv.f, acc[nt], 0, 0, 0);
        }
    }
    #pragma unroll
    for (int nt = 0; nt < 8; ++nt)
    #pragma unroll
    for (int r = 0; r < 4; ++r) {
        int row = q * 4 + r;
        hbuf[(w * 16 + row) * 128 + nt * 16 + l16] = acc[nt][r];
    }
    __syncthreads();
    for (int t = tid; t < 1024; t += 256) {
        int im = t >> 6, oc2 = (t & 63) * 2;
        float s0 = hbuf[im * 128 + oc2]        + hbuf[(16 + im) * 128 + oc2]
                 + hbuf[(32 + im) * 128 + oc2] + hbuf[(48 + im) * 128 + oc2];
        float s1 = hbuf[im * 128 + oc2 + 1]        + hbuf[(16 + im) * 128 + oc2 + 1]
                 + hbuf[(32 + im) * 128 + oc2 + 1] + hbuf[(48 + im) * 128 + oc2 + 1];
        int oc = ocb + oc2;
        s0 += d5b[oc];     s0 = fmaxf(s0, 0.f) + a5[oc] * fminf(s0, 0.f);
        s1 += d5b[oc + 1]; s1 = fmaxf(s1, 0.f) + a5[oc + 1] * fminf(s1, 0.f);
        *(unsigned*)&h[(unsigned)(img0 + im) * 256u + oc] = pkh(s0, s1);
    }
}

// ---------------------------------------------------------------------------
// K5b (R13): heads from h (fp16) — 128 blocks x 16 images.
// ---------------------------------------------------------------------------
__global__ __launch_bounds__(256, 2)
void k5b_head(const unsigned short* __restrict__ h,
              const float* __restrict__ d61w, const float* __restrict__ d61b,
              const float* __restrict__ d62w, const float* __restrict__ d62b,
              const float* __restrict__ d63w, const float* __restrict__ d63b,
              float* __restrict__ out) {
    __shared__ float hL[16 * 260];
    __shared__ float wl[16 * 260];
    __shared__ float lg[256];
    const int blk = blockIdx.x, tid = threadIdx.x;
    const int img0 = blk * 16;

    for (int t = tid; t < 512; t += 256) {
        int im = t >> 5, g = t & 31;
        union { uint4 u; f16x8 f; } d;
        d.u = *(const uint4*)&h[(unsigned)(img0 + im) * 256u + g * 8];
        float* dst = &hL[im * 260 + g * 8];
        #pragma unroll
        for (int j = 0; j < 8; ++j) dst[j] = (float)d.f[j];
    }
    {
        int o = tid >> 4, seg = tid & 15;
        const float* wrow = (o < 2) ? d61w + o * 256
                          : (o < 6) ? d62w + (o - 2) * 256
                          :           d63w + (o - 6) * 256;
        #pragma unroll
        for (int j = 0; j < 4; ++j)
            *(float4*)&wl[o * 260 + seg * 16 + j * 4] = ((const float4*)wrow)[seg * 4 + j];
    }
    __syncthreads();

    const int im = tid >> 4, o = tid & 15;
    {
        float bias = (o < 2) ? d61b[o] : (o < 6) ? d62b[o - 2] : d63b[o - 6];
        float s = bias;
        const float4* ha = (const float4*)&hL[im * 260];
        const float4* wa = (const float4*)&wl[o * 260];
        #pragma unroll 8
        for (int k = 0; k < 64; ++k) {
            float4 a = ha[k], b = wa[k];
            s += a.x * b.x + a.y * b.y + a.z * b.z + a.w * b.w;
        }
        lg[im * 16 + o] = s;
    }
    __syncthreads();
    {
        int gimg = img0 + im;
        float v = lg[im * 16 + o];
        if (o >= 2 && o < 6) {
            out[gimg * 4 + (o - 2)] = v;
        } else if (o >= 6) {
            out[8192 + gimg * 10 + (o - 6)] = v;
        } else {
            float l0 = lg[im * 16 + 0], l1 = lg[im * 16 + 1];
            float mx = fmaxf(l0, l1);
            float e0 = __expf(l0 - mx), e1 = __expf(l1 - mx);
            out[28672 + gimg * 2 + o] = (o == 0 ? e0 : e1) / (e0 + e1);
        }
    }
}

// ---------------------------------------------------------------------------
extern "C" void kernel_launch(void* const* d_in, const int* in_sizes, int n_in,
                              void* d_out, int out_size, void* d_ws, size_t ws_size,
                              hipStream_t stream) {
    (void)in_sizes; (void)n_in; (void)out_size; (void)ws_size;
    const float* x    = (const float*)d_in[0];
    const float* c1w  = (const float*)d_in[1];
    const float* c1b  = (const float*)d_in[2];
    const float* a1   = (const float*)d_in[3];
    const float* c2w  = (const float*)d_in[4];
    const float* c2b  = (const float*)d_in[5];
    const float* a2   = (const float*)d_in[6];
    const float* c3w  = (const float*)d_in[7];
    const float* c3b  = (const float*)d_in[8];
    const float* a3   = (const float*)d_in[9];
    const float* c4w  = (const float*)d_in[10];
    const float* c4b  = (const float*)d_in[11];
    const float* a4   = (const float*)d_in[12];
    const float* d5w  = (const float*)d_in[13];
    const float* d5b  = (const float*)d_in[14];
    const float* a5   = (const float*)d_in[15];
    const float* d61w = (const float*)d_in[16];
    const float* d61b = (const float*)d_in[17];
    const float* d62w = (const float*)d_in[18];
    const float* d62b = (const float*)d_in[19];
    const float* d63w = (const float*)d_in[20];
    const float* d63b = (const float*)d_in[21];

    char* ws = (char*)d_ws;
    // region plan:
    //   p1    @ 0          : 69,337,088 B  (live through k23_fused)
    //   flat  @ 69,337,088 : 4,718,592 B
    //   h     @ 74,055,680 : 1,048,576 B
    //   weights @ 186,777,600 : ~766 KB
    unsigned short* p1    = (unsigned short*)(ws + 0);
    unsigned short* flat  = (unsigned short*)(ws + 69337088);
    unsigned short* h     = (unsigned short*)(ws + 74055680);
    unsigned short* w2    = (unsigned short*)(ws + 186777600);
    unsigned short* w3    = (unsigned short*)(ws + 186814464);
    unsigned short* w4    = (unsigned short*)(ws + 186888192);
    unsigned short* w5    = (unsigned short*)(ws + 186953728);

    k0_prep  <<<1496, 256, 0, stream>>>(c2w, c3w, c4w, d5w, w2, w3, w4, w5);
    k1_conv1 <<<2048, 256, 0, stream>>>(x, c1w, c1b, a1, p1);
    k23_fused<<<2048, 256, 0, stream>>>(p1, w2, c2b, a2, w3, c3b, a3, w4, c4b, a4, flat);
    k5a_gemm <<<256, 256, 0, stream>>>(flat, w5, d5b, a5, h);
    k5b_head <<<128, 256, 0, stream>>>(h, d61w, d61b, d62w, d62b, d63w, d63b,
                                       (float*)d_out);
}

// Round 14
// 294.459 us; speedup vs baseline: 1.9822x; 1.0082x over previous
//
#include <hip/hip_runtime.h>
#include <hip/hip_bf16.h>
#include <hip/hip_fp16.h>
#include <stdint.h>

typedef short s16x8 __attribute__((ext_vector_type(8)));
typedef unsigned short u16x8 __attribute__((ext_vector_type(8)));
typedef _Float16 f16x8 __attribute__((ext_vector_type(8)));
typedef __fp16 h16x2 __attribute__((ext_vector_type(2)));   // builtin's return type
typedef float f32x4 __attribute__((ext_vector_type(4)));

__device__ __forceinline__ unsigned short f2h(float f) {
    __half h = __float2half(f);
    union { __half h; unsigned short u; } c; c.h = h; return c.u;
}
// pack two f32 -> two f16 in one VALU op (v_cvt_pkrtz_f16_f32; RTZ, <=1ulp)
__device__ __forceinline__ unsigned pkh(float a, float b) {
    union { h16x2 h; unsigned u; } c;
    c.h = __builtin_amdgcn_cvt_pkrtz(a, b);
    return c.u;
}

// ---------------------------------------------------------------------------
// K0: weight repack (fp32 OIHW -> FP16 [kpos][oc][ic]), d5w -> fp16
// ---------------------------------------------------------------------------
__global__ void k0_prep(const float* __restrict__ c2w, const float* __restrict__ c3w,
                        const float* __restrict__ c4w, const float* __restrict__ d5w,
                        unsigned short* __restrict__ w2, unsigned short* __restrict__ w3,
                        unsigned short* __restrict__ w4, unsigned short* __restrict__ w5) {
    int t = blockIdx.x * 256 + threadIdx.x;
    if (t < 18432) {            // w2 [9][64][32] <- c2w [64][32][3][3]
        int kpos = t / 2048, rem = t % 2048, oc = rem / 32, ic = rem % 32;
        w2[t] = f2h(c2w[(oc * 32 + ic) * 9 + kpos]);
        return;
    }
    t -= 18432;
    if (t < 36864) {            // w3 [9][64][64] <- c3w [64][64][3][3]
        int kpos = t / 4096, rem = t % 4096, oc = rem / 64, ic = rem % 64;
        w3[t] = f2h(c3w[(oc * 64 + ic) * 9 + kpos]);
        return;
    }
    t -= 36864;
    if (t < 32768) {            // w4 [4][128][64] <- c4w [128][64][2][2]
        int kpos = t / 8192, rem = t % 8192, oc = rem / 64, ic = rem % 64;
        w4[t] = f2h(c4w[(oc * 64 + ic) * 4 + kpos]);
        return;
    }
    t -= 32768;
    if (t < 294912) w5[t] = f2h(d5w[t]);   // [256][1152] fp16
}

// ---------------------------------------------------------------------------
// K1 (R13, unchanged): conv1 fp16 MFMA; packed-max pool -> p1 fp16 [n][23][23][32]
// ---------------------------------------------------------------------------
__global__ __launch_bounds__(256, 6)
void k1_conv1(const float* __restrict__ x, const float* __restrict__ c1w,
              const float* __restrict__ c1b, const float* __restrict__ a1,
              unsigned short* __restrict__ p1) {
    __shared__ unsigned short xstrip[1008];      // [ic][7 rows][48] fp16 (2 KB)
    __shared__ unsigned short cbuf[230 * 40];    // [flat px][32 oc + 8 pad] fp16 (18.4 KB)
    __shared__ unsigned short wlds[1024];        // [32 oc][32 k] fp16, k>=27 zero (2 KB)
    __shared__ float bls[32], als[32];

    const int n = blockIdx.x, tid = threadIdx.x;
    const int w = tid >> 6, lane = tid & 63, q = lane >> 4, l16 = lane & 15;

    for (int t = tid; t < 1024; t += 256) {
        int oc = t >> 5, k = t & 31;
        wlds[t] = (k < 27) ? f2h(c1w[oc * 27 + k]) : (unsigned short)0;
    }
    if (tid < 32) { bls[tid] = c1b[tid]; als[tid] = a1[tid]; }
    __syncthreads();

    f16x8 Wf[2];
    #pragma unroll
    for (int nt = 0; nt < 2; ++nt) {
        union { u16x8 u; f16x8 f; } cc;
        cc.u = *(const u16x8*)(wlds + (nt * 16 + l16) * 32 + q * 8);
        Wf[nt] = cc.f;
    }

    float bq[2][4], aq[2][4];
    #pragma unroll
    for (int nt = 0; nt < 2; ++nt)
    #pragma unroll
    for (int r = 0; r < 4; ++r) {
        bq[nt][r] = bls[nt * 16 + q * 4 + r];
        aq[nt][r] = als[nt * 16 + q * 4 + r];
    }

    int off[8];
    #pragma unroll
    for (int j = 0; j < 8; ++j) {
        int k = q * 8 + j;
        int kk = k < 27 ? k : 26;
        int ic = kk / 9, r9 = kk - ic * 9, ky = r9 / 3, kx = r9 - ky * 3;
        off[j] = ic * 336 + ky * 48 + kx;
    }

    auto do_pool = [&](int sp, int nprows, int kymax) {
        int ntask = nprows * 92;
        int t = tid;
        if (t < ntask) {
            int ocg = t & 3; unsigned r2 = (unsigned)t >> 2;
            int px = (int)(r2 % 23u), py_l = (int)(r2 / 23u);
            int kxmax = (px == 22) ? 2 : 3;
            int base = (2 * py_l * 46 + 2 * px) * 40 + ocg * 8;
            f16x8 mx;
            #pragma unroll
            for (int j = 0; j < 8; ++j) mx[j] = (_Float16)(-60000.f);
            #pragma unroll
            for (int ky = 0; ky < 3; ++ky) {
                if (ky < kymax) {
                    #pragma unroll
                    for (int kx = 0; kx < 3; ++kx) {
                        if (kx < kxmax) {
                            union { uint4 u; f16x8 f; } d;
                            d.u = *(const uint4*)&cbuf[base + (ky * 46 + kx) * 40];
                            mx = __builtin_elementwise_max(mx, d.f);
                        }
                    }
                }
            }
            union { f16x8 f; uint4 u; } o; o.f = mx;
            int py = 2 * sp + py_l;
            *(uint4*)&p1[n * 16928 + (py * 23 + px) * 32 + ocg * 8] = o.u;
        }
    };

    for (int s = 0; s < 12; ++s) {
        const int nrows = (s == 11) ? 2 : 5;
        const int P = 46 * nrows;
        const int ntiles = (P + 15) >> 4;
        const int xr0 = 4 * s;

        {
            int t4 = tid;
            if (t4 < 252) {
                int ic = t4 / 84;
                int rem4 = t4 * 4 - ic * 336;
                int rr = rem4 / 48, col = rem4 - rr * 48;
                int row = xr0 + rr; if (row > 47) row = 47;
                float4 f = *(const float4*)(x + n * 6912 + ic * 2304 + row * 48 + col);
                uint2 o; o.x = pkh(f.x, f.y); o.y = pkh(f.z, f.w);
                *(uint2*)&xstrip[t4 * 4] = o;
            }
        }
        if (s > 0) do_pool(s - 1, 2, 3);
        __syncthreads();

        for (int T = w; T < ntiles; T += 4) {
            int px = T * 16 + l16;
            int p = px < P ? px : P - 1;
            int ry = p / 46, cx = p - ry * 46;
            int basex = ry * 48 + cx;
            union { u16x8 u; f16x8 f; } xcc;
            #pragma unroll
            for (int j = 0; j < 8; ++j) xcc.u[j] = xstrip[basex + off[j]];
            f16x8 Xf = xcc.f;
            f32x4 acc[2] = {{0.f,0.f,0.f,0.f},{0.f,0.f,0.f,0.f}};
            #pragma unroll
            for (int nt = 0; nt < 2; ++nt)
                acc[nt] = __builtin_amdgcn_mfma_f32_16x16x32_f16(Wf[nt], Xf, acc[nt], 0, 0, 0);
            if (px < P) {
                #pragma unroll
                for (int nt = 0; nt < 2; ++nt) {
                    float v0 = acc[nt][0] + bq[nt][0];
                    float v1 = acc[nt][1] + bq[nt][1];
                    float v2 = acc[nt][2] + bq[nt][2];
                    float v3 = acc[nt][3] + bq[nt][3];
                    v0 = fmaxf(v0, 0.f) + aq[nt][0] * fminf(v0, 0.f);
                    v1 = fmaxf(v1, 0.f) + aq[nt][1] * fminf(v1, 0.f);
                    v2 = fmaxf(v2, 0.f) + aq[nt][2] * fminf(v2, 0.f);
                    v3 = fmaxf(v3, 0.f) + aq[nt][3] * fminf(v3, 0.f);
                    uint2 pk; pk.x = pkh(v0, v1); pk.y = pkh(v2, v3);
                    *(uint2*)&cbuf[px * 40 + nt * 16 + q * 4] = pk;
                }
            }
        }
        __syncthreads();
    }
    do_pool(11, 1, 2);
}

// ---------------------------------------------------------------------------
// K23 (R14): fused conv2+pool2+conv3+pool3+conv4, fp16.
// OCCUPANCY 3->4 blocks/CU: padding reverted (R11 measured it ~neutral:
// conflicts 1.63e7->1.42e7, dur +4us) and strips shrunk to 2 pool rows
// (5 conv rows; 5 strips, exact fit, no tails). LDS 36.5 KB (was 52.2):
//   xs  [161 px][32] @0      (10304)  <- p1 rows 4s..4s+6, linear copy
//   c2s [105][64]    @10304  (13440)
//   p2s [100][64]    @23744  (12800)
//   c3buf [64][64] @0, p3 [16][64] @8192 (alias dead xs)
// VGPR 80 -> 16 waves/CU cap; 4 blocks x 4 waves = 16 exactly.
// ---------------------------------------------------------------------------
__global__ __launch_bounds__(256, 2)
void k23_fused(const unsigned short* __restrict__ p1, const unsigned short* __restrict__ w2,
               const float* __restrict__ c2b, const float* __restrict__ a2,
               const unsigned short* __restrict__ w3, const float* __restrict__ c3b,
               const float* __restrict__ a3, const unsigned short* __restrict__ w4,
               const float* __restrict__ c4b, const float* __restrict__ a4,
               unsigned short* __restrict__ flat) {
    __shared__ __align__(16) char smem[36544];
    unsigned short* xs    = (unsigned short*)(smem);            // [161 px][32]
    unsigned short* c2s   = (unsigned short*)(smem + 10304);    // [105][64]
    unsigned short* p2s   = (unsigned short*)(smem + 23744);    // [100][64]
    unsigned short* c3buf = (unsigned short*)(smem);            // alias (8 KB)
    unsigned short* p3    = (unsigned short*)(smem + 8192);     // alias [16][64]

    const int n = blockIdx.x, tid = threadIdx.x;
    const int w = tid >> 6, lane = tid & 63, q = lane >> 4, l16 = lane & 15;
    const unsigned short* p1n = p1 + n * 16928;

    const int npair = w & 1, tset = w >> 1;
    const int ocA = npair * 32 + l16, ocB = npair * 32 + 16 + l16;

    f16x8 B2[9][2];
    #pragma unroll
    for (int kp = 0; kp < 9; ++kp) {
        union { u16x8 u; f16x8 f; } c0, c1;
        c0.u = *(const u16x8*)(w2 + (kp * 64 + ocA) * 32 + q * 8);
        c1.u = *(const u16x8*)(w2 + (kp * 64 + ocB) * 32 + q * 8);
        B2[kp][0] = c0.f; B2[kp][1] = c1.f;
    }
    const float b2a = c2b[ocA], b2b = c2b[ocB];
    const float a2a = a2[ocA],  a2b = a2[ocB];

    // stage p1 rows 4s..4s+6 into xs (pure linear uint4 copy, 644 per strip)
    auto stage = [&](int s) {
        const uint4* src = ((const uint4*)p1n) + 368 * s;
        for (int t = tid; t < 644; t += 256) ((uint4*)xs)[t] = src[t];
    };

    // conv2 strip s: conv rows 4s..4s+4 (P=105 px) -> c2s local rows 0..104
    auto conv2_strip = [&]() {
        const int P = 105, ntiles = 7, half = 4;
        const int T0 = tset * half;
        const int T1 = (T0 + half) < ntiles ? (T0 + half) : ntiles;
        for (int T = T0; T < T1; ++T) {
            int m = T * 16 + l16;
            int p = m < P ? m : P - 1;
            int ry = p / 21, ox = p - ry * 21;
            const unsigned short* ab = xs + (ry * 23 + ox) * 32 + q * 8;
            f32x4 acc0 = {0.f, 0.f, 0.f, 0.f}, acc1 = {0.f, 0.f, 0.f, 0.f};
            #pragma unroll
            for (int kp = 0; kp < 9; ++kp) {
                int ky = kp / 3, kx = kp - ky * 3;
                union { u16x8 u; f16x8 f; } av;
                av.u = *(const u16x8*)(ab + (ky * 23 + kx) * 32);
                acc0 = __builtin_amdgcn_mfma_f32_16x16x32_f16(av.f, B2[kp][0], acc0, 0, 0, 0);
                acc1 = __builtin_amdgcn_mfma_f32_16x16x32_f16(av.f, B2[kp][1], acc1, 0, 0, 0);
            }
            int rowb = T * 16 + q * 4;
            #pragma unroll
            for (int r = 0; r < 4; ++r) {
                int row = rowb + r;
                if (row < P) {
                    float v0 = acc0[r] + b2a;
                    v0 = fmaxf(v0, 0.f) + a2a * fminf(v0, 0.f);
                    c2s[row * 64 + npair * 32 + l16] = f2h(v0);
                    float v1 = acc1[r] + b2b;
                    v1 = fmaxf(v1, 0.f) + a2b * fminf(v1, 0.f);
                    c2s[row * 64 + npair * 32 + 16 + l16] = f2h(v1);
                }
            }
        }
    };

    // pool2 strip s: pool rows 2s, 2s+1 from c2s local rows 0..4
    auto pool_strip = [&](int s) {
        if (tid < 160) {
            int ocg = tid & 7; int r2 = tid >> 3;
            int px = r2 % 10, pyl = r2 / 10;
            int base = (2 * pyl * 21 + 2 * px) * 64 + ocg * 8;
            f16x8 mx;
            #pragma unroll
            for (int j = 0; j < 8; ++j) mx[j] = (_Float16)(-60000.f);
            #pragma unroll
            for (int ky = 0; ky < 3; ++ky)
            #pragma unroll
            for (int kx = 0; kx < 3; ++kx) {
                union { uint4 u; f16x8 f; } d;
                d.u = *(const uint4*)&c2s[base + (ky * 21 + kx) * 64];
                mx = __builtin_elementwise_max(mx, d.f);
            }
            union { f16x8 f; uint4 u; } o; o.f = mx;
            *(uint4*)&p2s[((2 * s + pyl) * 10 + px) * 64 + ocg * 8] = o.u;
        }
    };

    stage(0);
    __syncthreads();
    for (int s = 0; s < 5; ++s) {
        conv2_strip();
        __syncthreads();
        pool_strip(s);
        if (s < 4) stage(s + 1);
        __syncthreads();
    }

    // conv3: wave w owns oc-tile w x all 4 M-tiles; 18 chunks, B prefetched
    {
        const int oc3 = w * 16 + l16;
        int mbase[4];
        #pragma unroll
        for (int j = 0; j < 4; ++j) {
            int px = j * 16 + l16;
            int oy = px >> 3, ox = px & 7;
            mbase[j] = (oy * 10 + ox) * 64 + q * 8;
        }
        f32x4 acc3[4];
        #pragma unroll
        for (int j = 0; j < 4; ++j) acc3[j] = f32x4{0.f, 0.f, 0.f, 0.f};
        union { u16x8 u; f16x8 f; } bc;
        bc.u = *(const u16x8*)(w3 + oc3 * 64 + q * 8);
        f16x8 B3c = bc.f;
        for (int c = 0; c < 18; ++c) {
            f16x8 B3n = B3c;
            if (c < 17) {
                int cn = c + 1;
                union { u16x8 u; f16x8 f; } bn;
                bn.u = *(const u16x8*)(w3 + ((cn >> 1) * 64 + oc3) * 64 + (cn & 1) * 32 + q * 8);
                B3n = bn.f;
            }
            int kp = c >> 1, ky = kp / 3, kx = kp - ky * 3;
            int aoff = (ky * 10 + kx) * 64 + (c & 1) * 32;
            #pragma unroll
            for (int j = 0; j < 4; ++j) {
                union { u16x8 u; f16x8 f; } av;
                av.u = *(const u16x8*)(p2s + mbase[j] + aoff);
                acc3[j] = __builtin_amdgcn_mfma_f32_16x16x32_f16(av.f, B3c, acc3[j], 0, 0, 0);
            }
            B3c = B3n;
        }
        float bias = c3b[oc3], al = a3[oc3];
        #pragma unroll
        for (int j = 0; j < 4; ++j)
        #pragma unroll
        for (int r = 0; r < 4; ++r) {
            int row = j * 16 + q * 4 + r;
            float val = acc3[j][r] + bias;
            val = fmaxf(val, 0.f) + al * fminf(val, 0.f);
            c3buf[row * 64 + oc3] = f2h(val);
        }
    }
    __syncthreads();

    // pool3 2x2 s2 (8->4), packed max -> p3 [16][64]
    if (tid < 128) {
        int ocg = tid & 7, r = tid >> 3;   // r = output px 0..15
        int py = r >> 2, pxo = r & 3;
        f16x8 mx;
        #pragma unroll
        for (int j = 0; j < 8; ++j) mx[j] = (_Float16)(-60000.f);
        #pragma unroll
        for (int ky = 0; ky < 2; ++ky)
        #pragma unroll
        for (int kx = 0; kx < 2; ++kx) {
            union { uint4 u; f16x8 f; } d;
            d.u = *(const uint4*)&c3buf[((py * 2 + ky) * 8 + pxo * 2 + kx) * 64 + ocg * 8];
            mx = __builtin_elementwise_max(mx, d.f);
        }
        union { f16x8 f; uint4 u; } o; o.f = mx;
        *(uint4*)&p3[r * 64 + ocg * 8] = o.u;
    }
    __syncthreads();

    // conv4: wave w owns oc-tiles 2w,2w+1; 8 chunks, shared A + prefetched B
    {
        int px = l16 < 9 ? l16 : 8;
        int oy = px / 3, ox = px - oy * 3;
        const int mb4 = (oy * 4 + ox) * 64 + q * 8;
        const int oc4a = (w * 2) * 16 + l16, oc4b = (w * 2 + 1) * 16 + l16;
        f32x4 acc4[2] = {{0.f,0.f,0.f,0.f},{0.f,0.f,0.f,0.f}};
        f16x8 B4c[2];
        {
            union { u16x8 u; f16x8 f; } b0, b1;
            b0.u = *(const u16x8*)(w4 + oc4a * 64 + q * 8);
            b1.u = *(const u16x8*)(w4 + oc4b * 64 + q * 8);
            B4c[0] = b0.f; B4c[1] = b1.f;
        }
        for (int c = 0; c < 8; ++c) {
            f16x8 B4n[2] = {B4c[0], B4c[1]};
            if (c < 7) {
                int cn = c + 1;
                int boff = (cn >> 1) * 8192 + (cn & 1) * 32 + q * 8;
                union { u16x8 u; f16x8 f; } b0, b1;
                b0.u = *(const u16x8*)(w4 + boff + oc4a * 64);
                b1.u = *(const u16x8*)(w4 + boff + oc4b * 64);
                B4n[0] = b0.f; B4n[1] = b1.f;
            }
            int kp = c >> 1, ky = kp >> 1, kx = kp & 1;
            union { u16x8 u; f16x8 f; } av;
            av.u = *(const u16x8*)(p3 + mb4 + (ky * 4 + kx) * 64 + (c & 1) * 32);
            acc4[0] = __builtin_amdgcn_mfma_f32_16x16x32_f16(av.f, B4c[0], acc4[0], 0, 0, 0);
            acc4[1] = __builtin_amdgcn_mfma_f32_16x16x32_f16(av.f, B4c[1], acc4[1], 0, 0, 0);
            B4c[0] = B4n[0]; B4c[1] = B4n[1];
        }
        #pragma unroll
        for (int h = 0; h < 2; ++h) {
            int oc = h ? oc4b : oc4a;
            float bias = c4b[oc], al = a4[oc];
            #pragma unroll
            for (int r = 0; r < 4; ++r) {
                int row = q * 4 + r;
                if (row < 9) {
                    int hy = row / 3, wx = row - hy * 3;
                    float val = acc4[h][r] + bias;
                    val = fmaxf(val, 0.f) + al * fminf(val, 0.f);
                    flat[(unsigned)n * 1152u + (wx * 3 + hy) * 128 + oc] = f2h(val);
                }
            }
        }
    }
}

// ---------------------------------------------------------------------------
// K5 (R14): MERGED d5 GEMM + heads. 128 blocks x 16 images. Wave w owns
// oc 64w..64w+63 over full K=1152 (36 chunks x 4 MFMA, acc=16 AGPR) — no
// K-split, no hbuf reduce, no h round-trip, one launch fewer. Heads phase
// from validated k5b. LDS: hL 16x260 f32 + wl 16x260 f32 + lg (34.3 KB).
// ---------------------------------------------------------------------------
__global__ __launch_bounds__(256, 2)
void k5_fused(const unsigned short* __restrict__ flat, const unsigned short* __restrict__ w5,
              const float* __restrict__ d5b, const float* __restrict__ a5,
              const float* __restrict__ d61w, const float* __restrict__ d61b,
              const float* __restrict__ d62w, const float* __restrict__ d62b,
              const float* __restrict__ d63w, const float* __restrict__ d63b,
              float* __restrict__ out) {
    __shared__ float hL[16 * 260];
    __shared__ float wl[16 * 260];
    __shared__ float lg[256];
    const int blk = blockIdx.x, tid = threadIdx.x;
    const int w = tid >> 6, lane = tid & 63, q = lane >> 4, l16 = lane & 15;
    const int img0 = blk * 16;
    const int img = img0 + l16;

    f32x4 acc[4];
    #pragma unroll
    for (int nt = 0; nt < 4; ++nt) acc[nt] = f32x4{0.f, 0.f, 0.f, 0.f};

    for (int c = 0; c < 36; ++c) {
        int k0 = c * 32 + q * 8;
        union { u16x8 u; f16x8 f; } av;
        av.u = *(const u16x8*)(flat + (unsigned)img * 1152u + k0);
        #pragma unroll
        for (int nt = 0; nt < 4; ++nt) {
            int oc = w * 64 + nt * 16 + l16;
            union { u16x8 u; f16x8 f; } bv;
            bv.u = *(const u16x8*)(w5 + (unsigned)oc * 1152u + k0);
            acc[nt] = __builtin_amdgcn_mfma_f32_16x16x32_f16(av.f, bv.f, acc[nt], 0, 0, 0);
        }
    }
    // epilogue: bias + PReLU -> hL (fp32); C row=q*4+r=image, col=l16
    #pragma unroll
    for (int nt = 0; nt < 4; ++nt) {
        int oc = w * 64 + nt * 16 + l16;
        float bias = d5b[oc], al = a5[oc];
        #pragma unroll
        for (int r = 0; r < 4; ++r) {
            int im = q * 4 + r;
            float v = acc[nt][r] + bias;
            v = fmaxf(v, 0.f) + al * fminf(v, 0.f);
            hL[im * 260 + oc] = v;
        }
    }
    // stage 16 head weight rows (fp32)
    {
        int o = tid >> 4, seg = tid & 15;
        const float* wrow = (o < 2) ? d61w + o * 256
                          : (o < 6) ? d62w + (o - 2) * 256
                          :           d63w + (o - 6) * 256;
        #pragma unroll
        for (int j = 0; j < 4; ++j)
            *(float4*)&wl[o * 260 + seg * 16 + j * 4] = ((const float4*)wrow)[seg * 4 + j];
    }
    __syncthreads();

    const int im = tid >> 4, o = tid & 15;
    {
        float bias = (o < 2) ? d61b[o] : (o < 6) ? d62b[o - 2] : d63b[o - 6];
        float s = bias;
        const float4* ha = (const float4*)&hL[im * 260];
        const float4* wa = (const float4*)&wl[o * 260];
        #pragma unroll 8
        for (int k = 0; k < 64; ++k) {
            float4 a = ha[k], b = wa[k];
            s += a.x * b.x + a.y * b.y + a.z * b.z + a.w * b.w;
        }
        lg[im * 16 + o] = s;
    }
    __syncthreads();
    {
        int gimg = img0 + im;
        float v = lg[im * 16 + o];
        if (o >= 2 && o < 6) {
            out[gimg * 4 + (o - 2)] = v;                       // b [N,4]
        } else if (o >= 6) {
            out[8192 + gimg * 10 + (o - 6)] = v;               // c [N,10]
        } else {
            float l0 = lg[im * 16 + 0], l1 = lg[im * 16 + 1];
            float mx = fmaxf(l0, l1);
            float e0 = __expf(l0 - mx), e1 = __expf(l1 - mx);
            out[28672 + gimg * 2 + o] = (o == 0 ? e0 : e1) / (e0 + e1);   // a [N,2]
        }
    }
}

// ---------------------------------------------------------------------------
extern "C" void kernel_launch(void* const* d_in, const int* in_sizes, int n_in,
                              void* d_out, int out_size, void* d_ws, size_t ws_size,
                              hipStream_t stream) {
    (void)in_sizes; (void)n_in; (void)out_size; (void)ws_size;
    const float* x    = (const float*)d_in[0];
    const float* c1w  = (const float*)d_in[1];
    const float* c1b  = (const float*)d_in[2];
    const float* a1   = (const float*)d_in[3];
    const float* c2w  = (const float*)d_in[4];
    const float* c2b  = (const float*)d_in[5];
    const float* a2   = (const float*)d_in[6];
    const float* c3w  = (const float*)d_in[7];
    const float* c3b  = (const float*)d_in[8];
    const float* a3   = (const float*)d_in[9];
    const float* c4w  = (const float*)d_in[10];
    const float* c4b  = (const float*)d_in[11];
    const float* a4   = (const float*)d_in[12];
    const float* d5w  = (const float*)d_in[13];
    const float* d5b  = (const float*)d_in[14];
    const float* a5   = (const float*)d_in[15];
    const float* d61w = (const float*)d_in[16];
    const float* d61b = (const float*)d_in[17];
    const float* d62w = (const float*)d_in[18];
    const float* d62b = (const float*)d_in[19];
    const float* d63w = (const float*)d_in[20];
    const float* d63b = (const float*)d_in[21];

    char* ws = (char*)d_ws;
    // region plan:
    //   p1    @ 0          : 69,337,088 B  (live through k23_fused)
    //   flat  @ 69,337,088 : 4,718,592 B
    //   weights @ 186,777,600 : ~766 KB
    unsigned short* p1    = (unsigned short*)(ws + 0);
    unsigned short* flat  = (unsigned short*)(ws + 69337088);
    unsigned short* w2    = (unsigned short*)(ws + 186777600);
    unsigned short* w3    = (unsigned short*)(ws + 186814464);
    unsigned short* w4    = (unsigned short*)(ws + 186888192);
    unsigned short* w5    = (unsigned short*)(ws + 186953728);

    k0_prep  <<<1496, 256, 0, stream>>>(c2w, c3w, c4w, d5w, w2, w3, w4, w5);
    k1_conv1 <<<2048, 256, 0, stream>>>(x, c1w, c1b, a1, p1);
    k23_fused<<<2048, 256, 0, stream>>>(p1, w2, c2b, a2, w3, c3b, a3, w4, c4b, a4, flat);
    k5_fused <<<128, 256, 0, stream>>>(flat, w5, d5b, a5, d61w, d61b, d62w, d62b,
                                       d63w, d63b, (float*)d_out);
}

// Round 15
// 279.716 us; speedup vs baseline: 2.0867x; 1.0527x over previous
//
#include <hip/hip_runtime.h>
#include <hip/hip_bf16.h>
#include <hip/hip_fp16.h>
#include <stdint.h>

typedef short s16x8 __attribute__((ext_vector_type(8)));
typedef unsigned short u16x8 __attribute__((ext_vector_type(8)));
typedef _Float16 f16x8 __attribute__((ext_vector_type(8)));
typedef __fp16 h16x2 __attribute__((ext_vector_type(2)));   // builtin's return type
typedef float f32x4 __attribute__((ext_vector_type(4)));

__device__ __forceinline__ unsigned short f2h(float f) {
    __half h = __float2half(f);
    union { __half h; unsigned short u; } c; c.h = h; return c.u;
}
// pack two f32 -> two f16 in one VALU op (v_cvt_pkrtz_f16_f32; RTZ, <=1ulp)
__device__ __forceinline__ unsigned pkh(float a, float b) {
    union { h16x2 h; unsigned u; } c;
    c.h = __builtin_amdgcn_cvt_pkrtz(a, b);
    return c.u;
}
// packed PReLU on 8 fp16 lanes: max(v,0) + a*min(v,0)  (v_pk_max/min/fma)
__device__ __forceinline__ f16x8 prelu8(f16x8 v, f16x8 a) {
    f16x8 z = {};
    f16x8 pos = __builtin_elementwise_max(v, z);
    f16x8 neg = __builtin_elementwise_min(v, z);
    return pos + a * neg;
}

// ---------------------------------------------------------------------------
// K1 (R15): conv1 fp16 MFMA + fused WEIGHT REPACK (blocks >= 2048 do the old
// k0 grid-stride; saves one dispatch). Bias folded into MFMA acc-init;
// PReLU deferred to pool (monotone, alpha>0) and applied as packed fp16.
// -> p1 fp16 [n][23][23][32], post-PReLU.
// ---------------------------------------------------------------------------
__global__ __launch_bounds__(256, 6)
void k1_conv1(const float* __restrict__ x, const float* __restrict__ c1w,
              const float* __restrict__ c1b, const float* __restrict__ a1,
              unsigned short* __restrict__ p1,
              const float* __restrict__ c2w, const float* __restrict__ c3w,
              const float* __restrict__ c4w, const float* __restrict__ d5w,
              unsigned short* __restrict__ w2, unsigned short* __restrict__ w3,
              unsigned short* __restrict__ w4, unsigned short* __restrict__ w5) {
    const int n = blockIdx.x, tid = threadIdx.x;

    if (n >= 2048) {            // ---- repack path (old k0), 74 blocks ----
        for (int t0 = (n - 2048) * 256 + tid; t0 < 382976; t0 += 18944) {
            int t = t0;
            if (t < 18432) {    // w2 [9][64][32] <- c2w [64][32][3][3]
                int kpos = t / 2048, rem = t % 2048, oc = rem / 32, ic = rem % 32;
                w2[t] = f2h(c2w[(oc * 32 + ic) * 9 + kpos]);
                continue;
            }
            t -= 18432;
            if (t < 36864) {    // w3 [9][64][64] <- c3w [64][64][3][3]
                int kpos = t / 4096, rem = t % 4096, oc = rem / 64, ic = rem % 64;
                w3[t] = f2h(c3w[(oc * 64 + ic) * 9 + kpos]);
                continue;
            }
            t -= 36864;
            if (t < 32768) {    // w4 [4][128][64] <- c4w [128][64][2][2]
                int kpos = t / 8192, rem = t % 8192, oc = rem / 64, ic = rem % 64;
                w4[t] = f2h(c4w[(oc * 64 + ic) * 4 + kpos]);
                continue;
            }
            t -= 32768;
            w5[t] = f2h(d5w[t]);    // [256][1152] fp16
        }
        return;
    }

    __shared__ unsigned short xstrip[1008];      // [ic][7 rows][48] fp16 (2 KB)
    __shared__ unsigned short cbuf[230 * 40];    // [flat px][32 oc + 8 pad] fp16 (18.4 KB)
    __shared__ unsigned short wlds[1024];        // [32 oc][32 k] fp16, k>=27 zero (2 KB)
    __shared__ unsigned short a1h[32];           // alpha fp16 packed source
    __shared__ float bls[32];

    const int w = tid >> 6, lane = tid & 63, q = lane >> 4, l16 = lane & 15;

    for (int t = tid; t < 1024; t += 256) {
        int oc = t >> 5, k = t & 31;
        wlds[t] = (k < 27) ? f2h(c1w[oc * 27 + k]) : (unsigned short)0;
    }
    if (tid < 32) { bls[tid] = c1b[tid]; a1h[tid] = f2h(a1[tid]); }
    __syncthreads();

    f16x8 Wf[2];
    #pragma unroll
    for (int nt = 0; nt < 2; ++nt) {
        union { u16x8 u; f16x8 f; } cc;
        cc.u = *(const u16x8*)(wlds + (nt * 16 + l16) * 32 + q * 8);
        Wf[nt] = cc.f;
    }

    // bias for acc-init: C row = oc = nt*16 + q*4 + r
    f32x4 binit[2];
    #pragma unroll
    for (int nt = 0; nt < 2; ++nt)
    #pragma unroll
    for (int r = 0; r < 4; ++r) binit[nt][r] = bls[nt * 16 + q * 4 + r];

    int off[8];
    #pragma unroll
    for (int j = 0; j < 8; ++j) {
        int k = q * 8 + j;
        int kk = k < 27 ? k : 26;
        int ic = kk / 9, r9 = kk - ic * 9, ky = r9 / 3, kx = r9 - ky * 3;
        off[j] = ic * 336 + ky * 48 + kx;
    }

    auto do_pool = [&](int sp, int nprows, int kymax) {
        int ntask = nprows * 92;
        int t = tid;
        if (t < ntask) {
            int ocg = t & 3; unsigned r2 = (unsigned)t >> 2;
            int px = (int)(r2 % 23u), py_l = (int)(r2 / 23u);
            int kxmax = (px == 22) ? 2 : 3;
            int base = (2 * py_l * 46 + 2 * px) * 40 + ocg * 8;
            f16x8 mx;
            #pragma unroll
            for (int j = 0; j < 8; ++j) mx[j] = (_Float16)(-60000.f);
            #pragma unroll
            for (int ky = 0; ky < 3; ++ky) {
                if (ky < kymax) {
                    #pragma unroll
                    for (int kx = 0; kx < 3; ++kx) {
                        if (kx < kxmax) {
                            union { uint4 u; f16x8 f; } d;
                            d.u = *(const uint4*)&cbuf[base + (ky * 46 + kx) * 40];
                            mx = __builtin_elementwise_max(mx, d.f);
                        }
                    }
                }
            }
            union { uint4 u; f16x8 f; } aal;
            aal.u = *(const uint4*)&a1h[ocg * 8];
            union { f16x8 f; uint4 u; } o; o.f = prelu8(mx, aal.f);
            int py = 2 * sp + py_l;
            *(uint4*)&p1[n * 16928 + (py * 23 + px) * 32 + ocg * 8] = o.u;
        }
    };

    for (int s = 0; s < 12; ++s) {
        const int nrows = (s == 11) ? 2 : 5;
        const int P = 46 * nrows;
        const int ntiles = (P + 15) >> 4;
        const int xr0 = 4 * s;

        {
            int t4 = tid;
            if (t4 < 252) {
                int ic = t4 / 84;
                int rem4 = t4 * 4 - ic * 336;
                int rr = rem4 / 48, col = rem4 - rr * 48;
                int row = xr0 + rr; if (row > 47) row = 47;
                float4 f = *(const float4*)(x + n * 6912 + ic * 2304 + row * 48 + col);
                uint2 o; o.x = pkh(f.x, f.y); o.y = pkh(f.z, f.w);
                *(uint2*)&xstrip[t4 * 4] = o;
            }
        }
        if (s > 0) do_pool(s - 1, 2, 3);
        __syncthreads();

        for (int T = w; T < ntiles; T += 4) {
            int px = T * 16 + l16;
            int p = px < P ? px : P - 1;
            int ry = p / 46, cx = p - ry * 46;
            int basex = ry * 48 + cx;
            union { u16x8 u; f16x8 f; } xcc;
            #pragma unroll
            for (int j = 0; j < 8; ++j) xcc.u[j] = xstrip[basex + off[j]];
            f16x8 Xf = xcc.f;
            f32x4 acc[2] = {binit[0], binit[1]};
            #pragma unroll
            for (int nt = 0; nt < 2; ++nt)
                acc[nt] = __builtin_amdgcn_mfma_f32_16x16x32_f16(Wf[nt], Xf, acc[nt], 0, 0, 0);
            if (px < P) {
                #pragma unroll
                for (int nt = 0; nt < 2; ++nt) {
                    uint2 pk; pk.x = pkh(acc[nt][0], acc[nt][1]);
                    pk.y = pkh(acc[nt][2], acc[nt][3]);
                    *(uint2*)&cbuf[px * 40 + nt * 16 + q * 4] = pk;
                }
            }
        }
        __syncthreads();
    }
    do_pool(11, 1, 2);
}

// ---------------------------------------------------------------------------
// K23 (R15): fused conv2+pool2+conv3+pool3+conv4, fp16. Same structure as
// R14 (4 blocks/CU); bias folded into acc-init; conv2/conv3 PReLU deferred
// to pool2/pool3 (packed fp16); conv4 keeps scalar PReLU (no pool after).
// LDS 36.8 KB: xs [161][32] @0 | c2s [105][64] @10304 | p2s [100][64] @23744
//   c3buf [64][64] @0, p3 [16][64] @8192 (alias) + a2h/a3h (256 B)
// ---------------------------------------------------------------------------
__global__ __launch_bounds__(256, 2)
void k23_fused(const unsigned short* __restrict__ p1, const unsigned short* __restrict__ w2,
               const float* __restrict__ c2b, const float* __restrict__ a2,
               const unsigned short* __restrict__ w3, const float* __restrict__ c3b,
               const float* __restrict__ a3, const unsigned short* __restrict__ w4,
               const float* __restrict__ c4b, const float* __restrict__ a4,
               unsigned short* __restrict__ flat) {
    __shared__ __align__(16) char smem[36544];
    __shared__ unsigned short a2h[64], a3h[64];
    unsigned short* xs    = (unsigned short*)(smem);            // [161 px][32]
    unsigned short* c2s   = (unsigned short*)(smem + 10304);    // [105][64]
    unsigned short* p2s   = (unsigned short*)(smem + 23744);    // [100][64]
    unsigned short* c3buf = (unsigned short*)(smem);            // alias (8 KB)
    unsigned short* p3    = (unsigned short*)(smem + 8192);     // alias [16][64]

    const int n = blockIdx.x, tid = threadIdx.x;
    const int w = tid >> 6, lane = tid & 63, q = lane >> 4, l16 = lane & 15;
    const unsigned short* p1n = p1 + n * 16928;

    const int npair = w & 1, tset = w >> 1;
    const int ocA = npair * 32 + l16, ocB = npair * 32 + 16 + l16;

    if (tid < 64) { a2h[tid] = f2h(a2[tid]); a3h[tid] = f2h(a3[tid]); }

    f16x8 B2[9][2];
    #pragma unroll
    for (int kp = 0; kp < 9; ++kp) {
        union { u16x8 u; f16x8 f; } c0, c1;
        c0.u = *(const u16x8*)(w2 + (kp * 64 + ocA) * 32 + q * 8);
        c1.u = *(const u16x8*)(w2 + (kp * 64 + ocB) * 32 + q * 8);
        B2[kp][0] = c0.f; B2[kp][1] = c1.f;
    }
    const float b2a = c2b[ocA], b2b = c2b[ocB];

    // stage p1 rows 4s..4s+6 into xs (pure linear uint4 copy, 644 per strip)
    auto stage = [&](int s) {
        const uint4* src = ((const uint4*)p1n) + 368 * s;
        for (int t = tid; t < 644; t += 256) ((uint4*)xs)[t] = src[t];
    };

    // conv2 strip: conv rows 4s..4s+4 (P=105 px) -> c2s (pre-PReLU, bias in)
    auto conv2_strip = [&]() {
        const int P = 105, ntiles = 7, half = 4;
        const int T0 = tset * half;
        const int T1 = (T0 + half) < ntiles ? (T0 + half) : ntiles;
        for (int T = T0; T < T1; ++T) {
            int m = T * 16 + l16;
            int p = m < P ? m : P - 1;
            int ry = p / 21, ox = p - ry * 21;
            const unsigned short* ab = xs + (ry * 23 + ox) * 32 + q * 8;
            f32x4 acc0 = {b2a, b2a, b2a, b2a}, acc1 = {b2b, b2b, b2b, b2b};
            #pragma unroll
            for (int kp = 0; kp < 9; ++kp) {
                int ky = kp / 3, kx = kp - ky * 3;
                union { u16x8 u; f16x8 f; } av;
                av.u = *(const u16x8*)(ab + (ky * 23 + kx) * 32);
                acc0 = __builtin_amdgcn_mfma_f32_16x16x32_f16(av.f, B2[kp][0], acc0, 0, 0, 0);
                acc1 = __builtin_amdgcn_mfma_f32_16x16x32_f16(av.f, B2[kp][1], acc1, 0, 0, 0);
            }
            int rowb = T * 16 + q * 4;
            #pragma unroll
            for (int r = 0; r < 4; ++r) {
                int row = rowb + r;
                if (row < P) {
                    c2s[row * 64 + npair * 32 + l16]      = f2h(acc0[r]);
                    c2s[row * 64 + npair * 32 + 16 + l16] = f2h(acc1[r]);
                }
            }
        }
    };

    // pool2 strip s: packed max + packed PReLU -> p2s (post-PReLU)
    auto pool_strip = [&](int s) {
        if (tid < 160) {
            int ocg = tid & 7; int r2 = tid >> 3;
            int px = r2 % 10, pyl = r2 / 10;
            int base = (2 * pyl * 21 + 2 * px) * 64 + ocg * 8;
            f16x8 mx;
            #pragma unroll
            for (int j = 0; j < 8; ++j) mx[j] = (_Float16)(-60000.f);
            #pragma unroll
            for (int ky = 0; ky < 3; ++ky)
            #pragma unroll
            for (int kx = 0; kx < 3; ++kx) {
                union { uint4 u; f16x8 f; } d;
                d.u = *(const uint4*)&c2s[base + (ky * 21 + kx) * 64];
                mx = __builtin_elementwise_max(mx, d.f);
            }
            union { uint4 u; f16x8 f; } aal;
            aal.u = *(const uint4*)&a2h[ocg * 8];
            union { f16x8 f; uint4 u; } o; o.f = prelu8(mx, aal.f);
            *(uint4*)&p2s[((2 * s + pyl) * 10 + px) * 64 + ocg * 8] = o.u;
        }
    };

    stage(0);
    __syncthreads();
    for (int s = 0; s < 5; ++s) {
        conv2_strip();
        __syncthreads();
        pool_strip(s);
        if (s < 4) stage(s + 1);
        __syncthreads();
    }

    // conv3: wave w owns oc-tile w x all 4 M-tiles; 18 chunks, B prefetched
    {
        const int oc3 = w * 16 + l16;
        int mbase[4];
        #pragma unroll
        for (int j = 0; j < 4; ++j) {
            int px = j * 16 + l16;
            int oy = px >> 3, ox = px & 7;
            mbase[j] = (oy * 10 + ox) * 64 + q * 8;
        }
        const float bias3 = c3b[oc3];
        f32x4 acc3[4];
        #pragma unroll
        for (int j = 0; j < 4; ++j) acc3[j] = f32x4{bias3, bias3, bias3, bias3};
        union { u16x8 u; f16x8 f; } bc;
        bc.u = *(const u16x8*)(w3 + oc3 * 64 + q * 8);
        f16x8 B3c = bc.f;
        for (int c = 0; c < 18; ++c) {
            f16x8 B3n = B3c;
            if (c < 17) {
                int cn = c + 1;
                union { u16x8 u; f16x8 f; } bn;
                bn.u = *(const u16x8*)(w3 + ((cn >> 1) * 64 + oc3) * 64 + (cn & 1) * 32 + q * 8);
                B3n = bn.f;
            }
            int kp = c >> 1, ky = kp / 3, kx = kp - ky * 3;
            int aoff = (ky * 10 + kx) * 64 + (c & 1) * 32;
            #pragma unroll
            for (int j = 0; j < 4; ++j) {
                union { u16x8 u; f16x8 f; } av;
                av.u = *(const u16x8*)(p2s + mbase[j] + aoff);
                acc3[j] = __builtin_amdgcn_mfma_f32_16x16x32_f16(av.f, B3c, acc3[j], 0, 0, 0);
            }
            B3c = B3n;
        }
        #pragma unroll
        for (int j = 0; j < 4; ++j)
        #pragma unroll
        for (int r = 0; r < 4; ++r) {
            int row = j * 16 + q * 4 + r;
            c3buf[row * 64 + oc3] = f2h(acc3[j][r]);   // pre-PReLU
        }
    }
    __syncthreads();

    // pool3 2x2 s2 (8->4), packed max + packed PReLU -> p3 [16][64]
    if (tid < 128) {
        int ocg = tid & 7, r = tid >> 3;   // r = output px 0..15
        int py = r >> 2, pxo = r & 3;
        f16x8 mx;
        #pragma unroll
        for (int j = 0; j < 8; ++j) mx[j] = (_Float16)(-60000.f);
        #pragma unroll
        for (int ky = 0; ky < 2; ++ky)
        #pragma unroll
        for (int kx = 0; kx < 2; ++kx) {
            union { uint4 u; f16x8 f; } d;
            d.u = *(const uint4*)&c3buf[((py * 2 + ky) * 8 + pxo * 2 + kx) * 64 + ocg * 8];
            mx = __builtin_elementwise_max(mx, d.f);
        }
        union { uint4 u; f16x8 f; } aal;
        aal.u = *(const uint4*)&a3h[ocg * 8];
        union { f16x8 f; uint4 u; } o; o.f = prelu8(mx, aal.f);
        *(uint4*)&p3[r * 64 + ocg * 8] = o.u;
    }
    __syncthreads();

    // conv4: wave w owns oc-tiles 2w,2w+1; 8 chunks; bias in init, scalar PReLU
    {
        int px = l16 < 9 ? l16 : 8;
        int oy = px / 3, ox = px - oy * 3;
        const int mb4 = (oy * 4 + ox) * 64 + q * 8;
        const int oc4a = (w * 2) * 16 + l16, oc4b = (w * 2 + 1) * 16 + l16;
        const float b4a = c4b[oc4a], b4b = c4b[oc4b];
        f32x4 acc4[2] = {{b4a, b4a, b4a, b4a}, {b4b, b4b, b4b, b4b}};
        f16x8 B4c[2];
        {
            union { u16x8 u; f16x8 f; } b0, b1;
            b0.u = *(const u16x8*)(w4 + oc4a * 64 + q * 8);
            b1.u = *(const u16x8*)(w4 + oc4b * 64 + q * 8);
            B4c[0] = b0.f; B4c[1] = b1.f;
        }
        for (int c = 0; c < 8; ++c) {
            f16x8 B4n[2] = {B4c[0], B4c[1]};
            if (c < 7) {
                int cn = c + 1;
                int boff = (cn >> 1) * 8192 + (cn & 1) * 32 + q * 8;
                union { u16x8 u; f16x8 f; } b0, b1;
                b0.u = *(const u16x8*)(w4 + boff + oc4a * 64);
                b1.u = *(const u16x8*)(w4 + boff + oc4b * 64);
                B4n[0] = b0.f; B4n[1] = b1.f;
            }
            int kp = c >> 1, ky = kp >> 1, kx = kp & 1;
            union { u16x8 u; f16x8 f; } av;
            av.u = *(const u16x8*)(p3 + mb4 + (ky * 4 + kx) * 64 + (c & 1) * 32);
            acc4[0] = __builtin_amdgcn_mfma_f32_16x16x32_f16(av.f, B4c[0], acc4[0], 0, 0, 0);
            acc4[1] = __builtin_amdgcn_mfma_f32_16x16x32_f16(av.f, B4c[1], acc4[1], 0, 0, 0);
            B4c[0] = B4n[0]; B4c[1] = B4n[1];
        }
        #pragma unroll
        for (int h = 0; h < 2; ++h) {
            int oc = h ? oc4b : oc4a;
            float al = a4[oc];
            #pragma unroll
            for (int r = 0; r < 4; ++r) {
                int row = q * 4 + r;
                if (row < 9) {
                    int hy = row / 3, wx = row - hy * 3;
                    float val = acc4[h][r];
                    val = fmaxf(val, 0.f) + al * fminf(val, 0.f);
                    flat[(unsigned)n * 1152u + (wx * 3 + hy) * 128 + oc] = f2h(val);
                }
            }
        }
    }
}

// ---------------------------------------------------------------------------
// K5 (R15): merged d5 GEMM + heads; bias in acc-init. 128 blocks x 16 images.
// ---------------------------------------------------------------------------
__global__ __launch_bounds__(256, 2)
void k5_fused(const unsigned short* __restrict__ flat, const unsigned short* __restrict__ w5,
              const float* __restrict__ d5b, const float* __restrict__ a5,
              const float* __restrict__ d61w, const float* __restrict__ d61b,
              const float* __restrict__ d62w, const float* __restrict__ d62b,
              const float* __restrict__ d63w, const float* __restrict__ d63b,
              float* __restrict__ out) {
    __shared__ float hL[16 * 260];
    __shared__ float wl[16 * 260];
    __shared__ float lg[256];
    const int blk = blockIdx.x, tid = threadIdx.x;
    const int w = tid >> 6, lane = tid & 63, q = lane >> 4, l16 = lane & 15;
    const int img0 = blk * 16;
    const int img = img0 + l16;

    f32x4 acc[4];
    #pragma unroll
    for (int nt = 0; nt < 4; ++nt) {
        float b = d5b[w * 64 + nt * 16 + l16];
        acc[nt] = f32x4{b, b, b, b};
    }

    for (int c = 0; c < 36; ++c) {
        int k0 = c * 32 + q * 8;
        union { u16x8 u; f16x8 f; } av;
        av.u = *(const u16x8*)(flat + (unsigned)img * 1152u + k0);
        #pragma unroll
        for (int nt = 0; nt < 4; ++nt) {
            int oc = w * 64 + nt * 16 + l16;
            union { u16x8 u; f16x8 f; } bv;
            bv.u = *(const u16x8*)(w5 + (unsigned)oc * 1152u + k0);
            acc[nt] = __builtin_amdgcn_mfma_f32_16x16x32_f16(av.f, bv.f, acc[nt], 0, 0, 0);
        }
    }
    // epilogue: PReLU -> hL (fp32); C row=q*4+r=image, col=l16
    #pragma unroll
    for (int nt = 0; nt < 4; ++nt) {
        int oc = w * 64 + nt * 16 + l16;
        float al = a5[oc];
        #pragma unroll
        for (int r = 0; r < 4; ++r) {
            int im = q * 4 + r;
            float v = acc[nt][r];
            v = fmaxf(v, 0.f) + al * fminf(v, 0.f);
            hL[im * 260 + oc] = v;
        }
    }
    // stage 16 head weight rows (fp32)
    {
        int o = tid >> 4, seg = tid & 15;
        const float* wrow = (o < 2) ? d61w + o * 256
                          : (o < 6) ? d62w + (o - 2) * 256
                          :           d63w + (o - 6) * 256;
        #pragma unroll
        for (int j = 0; j < 4; ++j)
            *(float4*)&wl[o * 260 + seg * 16 + j * 4] = ((const float4*)wrow)[seg * 4 + j];
    }
    __syncthreads();

    const int im = tid >> 4, o = tid & 15;
    {
        float bias = (o < 2) ? d61b[o] : (o < 6) ? d62b[o - 2] : d63b[o - 6];
        float s = bias;
        const float4* ha = (const float4*)&hL[im * 260];
        const float4* wa = (const float4*)&wl[o * 260];
        #pragma unroll 8
        for (int k = 0; k < 64; ++k) {
            float4 a = ha[k], b = wa[k];
            s += a.x * b.x + a.y * b.y + a.z * b.z + a.w * b.w;
        }
        lg[im * 16 + o] = s;
    }
    __syncthreads();
    {
        int gimg = img0 + im;
        float v = lg[im * 16 + o];
        if (o >= 2 && o < 6) {
            out[gimg * 4 + (o - 2)] = v;                       // b [N,4]
        } else if (o >= 6) {
            out[8192 + gimg * 10 + (o - 6)] = v;               // c [N,10]
        } else {
            float l0 = lg[im * 16 + 0], l1 = lg[im * 16 + 1];
            float mx = fmaxf(l0, l1);
            float e0 = __expf(l0 - mx), e1 = __expf(l1 - mx);
            out[28672 + gimg * 2 + o] = (o == 0 ? e0 : e1) / (e0 + e1);   // a [N,2]
        }
    }
}

// ---------------------------------------------------------------------------
extern "C" void kernel_launch(void* const* d_in, const int* in_sizes, int n_in,
                              void* d_out, int out_size, void* d_ws, size_t ws_size,
                              hipStream_t stream) {
    (void)in_sizes; (void)n_in; (void)out_size; (void)ws_size;
    const float* x    = (const float*)d_in[0];
    const float* c1w  = (const float*)d_in[1];
    const float* c1b  = (const float*)d_in[2];
    const float* a1   = (const float*)d_in[3];
    const float* c2w  = (const float*)d_in[4];
    const float* c2b  = (const float*)d_in[5];
    const float* a2   = (const float*)d_in[6];
    const float* c3w  = (const float*)d_in[7];
    const float* c3b  = (const float*)d_in[8];
    const float* a3   = (const float*)d_in[9];
    const float* c4w  = (const float*)d_in[10];
    const float* c4b  = (const float*)d_in[11];
    const float* a4   = (const float*)d_in[12];
    const float* d5w  = (const float*)d_in[13];
    const float* d5b  = (const float*)d_in[14];
    const float* a5   = (const float*)d_in[15];
    const float* d61w = (const float*)d_in[16];
    const float* d61b = (const float*)d_in[17];
    const float* d62w = (const float*)d_in[18];
    const float* d62b = (const float*)d_in[19];
    const float* d63w = (const float*)d_in[20];
    const float* d63b = (const float*)d_in[21];

    char* ws = (char*)d_ws;
    // region plan:
    //   p1    @ 0          : 69,337,088 B  (live through k23_fused)
    //   flat  @ 69,337,088 : 4,718,592 B
    //   weights @ 186,777,600 : ~766 KB
    unsigned short* p1    = (unsigned short*)(ws + 0);
    unsigned short* flat  = (unsigned short*)(ws + 69337088);
    unsigned short* w2    = (unsigned short*)(ws + 186777600);
    unsigned short* w3    = (unsigned short*)(ws + 186814464);
    unsigned short* w4    = (unsigned short*)(ws + 186888192);
    unsigned short* w5    = (unsigned short*)(ws + 186953728);

    k1_conv1 <<<2122, 256, 0, stream>>>(x, c1w, c1b, a1, p1,
                                        c2w, c3w, c4w, d5w, w2, w3, w4, w5);
    k23_fused<<<2048, 256, 0, stream>>>(p1, w2, c2b, a2, w3, c3b, a3, w4, c4b, a4, flat);
    k5_fused <<<128, 256, 0, stream>>>(flat, w5, d5b, a5, d61w, d61b, d62w, d62b,
                                       d63w, d63b, (float*)d_out);
}